// Round 1
// baseline (3259.879 us; speedup 1.0000x reference)
//
#include <hip/hip_runtime.h>

// ---------------------------------------------------------------------------
// Branch_62989990363328: TimesBlock conv ensemble -> TTT-MLP -> out proj
// B=2 T=400 C=64 OUT=2048 NH=8 HD=256 INNER=1024 MB=10 NC=40
// ---------------------------------------------------------------------------

typedef __bf16 bf16x8 __attribute__((ext_vector_type(8)));
typedef float  f32x4  __attribute__((ext_vector_type(4)));

__device__ __forceinline__ unsigned short f2bf(float f){
  unsigned int u = __builtin_bit_cast(unsigned int, f);
  u += 0x7fffu + ((u >> 16) & 1u);
  return (unsigned short)(u >> 16);
}
__device__ __forceinline__ float bf2f(unsigned short b){
  unsigned int u = ((unsigned int)b) << 16;
  return __builtin_bit_cast(float, u);
}
__device__ __forceinline__ float gelu_f(float x){
  return 0.5f * x * (1.0f + erff(x * 0.70710678118654752f));
}
__device__ __forceinline__ float gelu_bwd_f(float x){
  return 0.5f * (1.0f + erff(x * 0.70710678118654752f))
       + x * __expf(-0.5f * x * x) * 0.3989422804014327f;
}

union Frag { bf16x8 v; unsigned short u[8]; };

// ---------------------------------------------------------------------------
// Prep kernels
// ---------------------------------------------------------------------------

// Combine 6 SAME convs (k=1,3,5,7,9,11) into one 11x11 kernel, bf16.
// weff[o][c*121 + di*11 + dj]
__global__ __launch_bounds__(256) void k_weff(
    const float* __restrict__ w0, const float* __restrict__ w1,
    const float* __restrict__ w2, const float* __restrict__ w3,
    const float* __restrict__ w4, const float* __restrict__ w5,
    unsigned short* __restrict__ weff)
{
  int idx = blockIdx.x * 256 + threadIdx.x;
  if (idx >= 2048 * 7744) return;
  int o = idx / 7744, k = idx % 7744;
  int c = k / 121, dd = k % 121, di = dd / 11, dj = dd % 11;
  const float* ws6[6] = {w0, w1, w2, w3, w4, w5};
  float s = 0.f;
#pragma unroll
  for (int i = 0; i < 6; i++){
    int kk = 2 * i + 1;
    int a = di - 5 + i, b = dj - 5 + i;
    if (a >= 0 && a < kk && b >= 0 && b < kk)
      s += ws6[i][(((size_t)o * 64 + c) * kk + a) * kk + b];
  }
  weff[idx] = f2bf(s);
}

// im2col patches, bf16: P[n = b*400 + i*20 + j][c*121 + di*11 + dj]
__global__ __launch_bounds__(256) void k_im2col(
    const float* __restrict__ x, unsigned short* __restrict__ P)
{
  int idx = blockIdx.x * 256 + threadIdx.x;
  if (idx >= 800 * 7744) return;
  int n = idx / 7744, k = idx % 7744;
  int c = k / 121, dd = k % 121, di = dd / 11, dj = dd % 11;
  int b = n / 400, pos = n % 400, i = pos / 20, j = pos % 20;
  int ii = i + di - 5, jj = j + dj - 5;
  float v = 0.f;
  if (ii >= 0 && ii < 20 && jj >= 0 && jj < 20)
    v = x[((size_t)b * 400 + ii * 20 + jj) * 64 + c];
  P[idx] = f2bf(v);
}

// Concatenate wq|wk|wv -> bf16 [6144][2048]
__global__ __launch_bounds__(256) void k_wqkv(
    const float* __restrict__ wq, const float* __restrict__ wk,
    const float* __restrict__ wv, unsigned short* __restrict__ dst)
{
  int idx = blockIdx.x * 256 + threadIdx.x;
  if (idx >= 6144 * 2048) return;
  int m = idx >> 11, kk = idx & 2047;
  const float* src = (m < 2048) ? wq : ((m < 4096) ? wk : wv);
  dst[idx] = f2bf(src[(size_t)(m & 2047) * 2048 + kk]);
}

__global__ __launch_bounds__(256) void k_f2bf_copy(
    const float* __restrict__ src, unsigned short* __restrict__ dst, int n)
{
  int idx = blockIdx.x * 256 + threadIdx.x;
  if (idx < n) dst[idx] = f2bf(src[idx]);
}

__global__ __launch_bounds__(256) void k_bsum(
    const float* __restrict__ b0, const float* __restrict__ b1,
    const float* __restrict__ b2, const float* __restrict__ b3,
    const float* __restrict__ b4, const float* __restrict__ b5,
    float* __restrict__ bsum)
{
  int idx = blockIdx.x * 256 + threadIdx.x;
  if (idx < 2048)
    bsum[idx] = b0[idx] + b1[idx] + b2[idx] + b3[idx] + b4[idx] + b5[idx];
}

// ---------------------------------------------------------------------------
// Generic bf16 MFMA GEMM: C[M][N] = A[M][K] * B[N][K]^T  (both row-major in K)
// 128x128 tile, 256 threads (4 waves, each 64x64), BK=32, 16x16x32 MFMA.
// MODE 0: conv epilogue  -> xb bf16 [800][2048]   (silu((acc+bsum)/6))
// MODE 1: qkv epilogue   -> q/k/v fp32 [16][400][256]
// MODE 2: final epilogue -> d_out fp32 [800][2048]
// ---------------------------------------------------------------------------
template<int MODE>
__global__ __launch_bounds__(256, 1) void k_gemm(
    const unsigned short* __restrict__ A, const unsigned short* __restrict__ B,
    int M, int N, int K,
    const float* __restrict__ bsum, unsigned short* __restrict__ out_bf,
    float* __restrict__ qb, float* __restrict__ kb, float* __restrict__ vb,
    float* __restrict__ outf)
{
  __shared__ unsigned short As[128 * 32];
  __shared__ unsigned short Bs[128 * 32];
  int tid = threadIdx.x, w = tid >> 6, l = tid & 63, qd = l >> 4, lm = l & 15;
  int m0 = blockIdx.x * 128, n0 = blockIdx.y * 128;

  f32x4 acc[4][4];
#pragma unroll
  for (int i = 0; i < 4; i++)
#pragma unroll
    for (int j = 0; j < 4; j++){ acc[i][j][0]=0.f; acc[i][j][1]=0.f; acc[i][j][2]=0.f; acc[i][j][3]=0.f; }

  int nk = K >> 5;
  for (int kt = 0; kt < nk; kt++){
    int k0 = kt << 5;
#pragma unroll
    for (int i = 0; i < 2; i++){
      int cidx = tid + i * 256;              // 512 chunks of 16B
      int row = cidx >> 2, kc = (cidx & 3) << 3;
      *(uint4*)&As[row * 32 + kc] = *(const uint4*)&A[(size_t)(m0 + row) * K + k0 + kc];
      int br = n0 + row; if (br >= N) br = N - 1;
      *(uint4*)&Bs[row * 32 + kc] = *(const uint4*)&B[(size_t)br * K + k0 + kc];
    }
    __syncthreads();
    bf16x8 af[4], bfv[4];
#pragma unroll
    for (int i = 0; i < 4; i++)
      af[i] = *(const bf16x8*)&As[((w >> 1) * 64 + i * 16 + lm) * 32 + qd * 8];
#pragma unroll
    for (int j = 0; j < 4; j++)
      bfv[j] = *(const bf16x8*)&Bs[((w & 1) * 64 + j * 16 + lm) * 32 + qd * 8];
#pragma unroll
    for (int i = 0; i < 4; i++)
#pragma unroll
      for (int j = 0; j < 4; j++)
        acc[i][j] = __builtin_amdgcn_mfma_f32_16x16x32_bf16(af[i], bfv[j], acc[i][j], 0, 0, 0);
    __syncthreads();
  }

#pragma unroll
  for (int i = 0; i < 4; i++){
    int mBase = m0 + (w >> 1) * 64 + i * 16 + qd * 4;
#pragma unroll
    for (int j = 0; j < 4; j++){
      int n = n0 + (w & 1) * 64 + j * 16 + lm;
      if (n < N){
#pragma unroll
        for (int rr = 0; rr < 4; rr++){
          float val = acc[i][j][rr];
          int mm = mBase + rr;
          if (MODE == 0){
            float t = (val + bsum[mm]) * (1.0f / 6.0f);
            float sv = t / (1.0f + __expf(-t));
            out_bf[(size_t)n * 2048 + mm] = f2bf(sv);
          } else if (MODE == 1){
            int proj = mm >> 11, o = mm & 2047, hh = o >> 8, d = o & 255;
            int bh = (n / 400) * 8 + hh, tt = n % 400;
            float* dst = (proj == 0) ? qb : ((proj == 1) ? kb : vb);
            dst[((size_t)bh * 400 + tt) * 256 + d] = val;
          } else {
            outf[(size_t)n * 2048 + mm] = val;
          }
        }
      }
    }
  }
}

// ---------------------------------------------------------------------------
// TTT persistent kernel. 256 WGs: 16 heads x 16 INNER-slices (64 wide).
// W1 slice [256][64] + W2 slice [64][256] fp32 in REGISTERS (64+64/thread),
// bf16 operand copies in LDS. One per-head global barrier per chunk.
// ---------------------------------------------------------------------------
#define O_W1BT 0          // [64][264]  W1^T bf16  (n=inner, k=hd)
#define O_W2K  16896      // [64][264]  W2 bf16    (inner, hd)  (B for gZ1)
#define O_W2N  33792      // [256][72]  W2^T bf16  (hd, inner)  (B for Z2)
#define O_XKQ  52224      // [16][264]  xk / xq bf16 (rows 10..15 zero)
#define O_TGT  56448      // [10][256]  (xv-xk) bf16
#define O_A1   59008      // [16][72]   A1 bf16 (row-major)
#define O_A1T  60160      // [64][40]   A1^T bf16 (cols 10..39 zero)
#define O_GZ2  62720      // [16][264]  gZ2 bf16 (rows 10..15 zero)
#define O_ZPAD 66944      // [16][264]  zeros (overread guard for GZ2 k=16..31)
#define O_GZ1  71168      // [64][40]   gZ1^T-ish [inner][row] (cols 10..39 zero)
#define US_TOTAL 73728
#define O_F32  73728      // float region (ushort offset): b1s[64] b2[256] gw[256] gb[256]
#define TTT_LDS_BYTES (73728 * 2 + 832 * 4)   // 150784 <= 163840

#define ETA 0.01f

__global__ __launch_bounds__(256, 1) void k_ttt(
    const float* __restrict__ qg, const float* __restrict__ kg, const float* __restrict__ vg,
    const float* __restrict__ W1g, const float* __restrict__ b1g,
    const float* __restrict__ W2g, const float* __restrict__ b2g,
    const float* __restrict__ gwg, const float* __restrict__ gbg,
    float* __restrict__ pz2f, float* __restrict__ pqf,
    float* __restrict__ z2qs, unsigned int* __restrict__ bar)
{
  extern __shared__ unsigned short lds[];
  float* ldsf = (float*)&lds[O_F32];

  int tid = threadIdx.x, w = tid >> 6, l = tid & 63, qd = l >> 4, lm = l & 15;
  int bid = blockIdx.x;
  // XCD-locality swizzle (perf heuristic only): 16 WGs of a head share bid%8
  int jj = bid >> 3, xx = bid & 7;
  int h  = xx + 8 * (jj >> 4);   // bh = b*8 + head  (0..15)
  int sl = jj & 15;              // INNER slice (0..15)
  int hh = h & 7;                // weight index (shared across batch)

  // zero whole LDS (pads / zero-guard regions rely on this)
  for (int i = tid; i < US_TOTAL; i += 256) lds[i] = 0;
  for (int i = tid; i < 832; i += 256) ldsf[i] = 0.f;
  __syncthreads();

  // ---- load fp32 masters into registers (C-layout of their update MFMAs) ----
  float w1r[4][4][4];   // [a: m-tile 4w+a][nt][reg] : W1[(4w+a)*16+qd*4+reg][sl*64+nt*16+lm]
#pragma unroll
  for (int a = 0; a < 4; a++)
#pragma unroll
    for (int nt = 0; nt < 4; nt++)
#pragma unroll
      for (int rr = 0; rr < 4; rr++)
        w1r[a][nt][rr] = W1g[((size_t)hh * 256 + (4 * w + a) * 16 + qd * 4 + rr) * 1024
                             + sl * 64 + nt * 16 + lm];
  float w2r[16][4];     // [nt][reg] : W2[sl*64 + w*16 + qd*4 + reg][nt*16 + lm]
#pragma unroll
  for (int nt = 0; nt < 16; nt++)
#pragma unroll
    for (int rr = 0; rr < 4; rr++)
      w2r[nt][rr] = W2g[((size_t)hh * 1024 + sl * 64 + w * 16 + qd * 4 + rr) * 256
                        + nt * 16 + lm];
  if (tid < 64)  ldsf[tid] = b1g[hh * 1024 + sl * 64 + tid];
  if (tid < 256){
    ldsf[64 + tid]  = b2g[hh * 256 + tid];
    ldsf[320 + tid] = gwg[hh * 256 + tid];
    ldsf[576 + tid] = gbg[hh * 256 + tid];
  }

  // ---- write bf16 operand copies ----
#define WRITE_W1BF() do { \
  _Pragma("unroll") for (int a = 0; a < 4; a++){ \
    int m0i = (4 * w + a) * 16 + qd * 4; \
    _Pragma("unroll") for (int nt = 0; nt < 4; nt++){ \
      int n = nt * 16 + lm; \
      unsigned int p0 = f2bf(w1r[a][nt][0]) | ((unsigned int)f2bf(w1r[a][nt][1]) << 16); \
      unsigned int p1 = f2bf(w1r[a][nt][2]) | ((unsigned int)f2bf(w1r[a][nt][3]) << 16); \
      *(unsigned int*)&lds[O_W1BT + n * 264 + m0i]     = p0; \
      *(unsigned int*)&lds[O_W1BT + n * 264 + m0i + 2] = p1; \
    } } } while(0)

#define WRITE_W2BF() do { \
  int mB = w * 16 + qd * 4; \
  _Pragma("unroll") for (int nt = 0; nt < 16; nt++){ \
    int n = nt * 16 + lm; \
    _Pragma("unroll") for (int rr = 0; rr < 4; rr++) \
      lds[O_W2K + (mB + rr) * 264 + n] = f2bf(w2r[nt][rr]); \
    unsigned int p0 = f2bf(w2r[nt][0]) | ((unsigned int)f2bf(w2r[nt][1]) << 16); \
    unsigned int p1 = f2bf(w2r[nt][2]) | ((unsigned int)f2bf(w2r[nt][3]) << 16); \
    *(unsigned int*)&lds[O_W2N + n * 72 + mB]     = p0; \
    *(unsigned int*)&lds[O_W2N + n * 72 + mB + 2] = p1; \
  } } while(0)

  WRITE_W1BF();
  WRITE_W2BF();
  __syncthreads();

  const size_t hb = (size_t)h * 400 * 256;

  for (int nch = 0; nch < 40; nch++){
    // 1. load xk chunk + tgt = xv - xk
    {
      const float* kp = kg + hb + (size_t)nch * 10 * 256;
      const float* vp = vg + hb + (size_t)nch * 10 * 256;
#pragma unroll
      for (int r2 = 0; r2 < 10; r2++){
        float kv = kp[r2 * 256 + tid];
        float vv = vp[r2 * 256 + tid];
        lds[O_XKQ + r2 * 264 + tid] = f2bf(kv);
        lds[O_TGT + r2 * 256 + tid] = f2bf(vv - kv);
      }
    }
    __syncthreads();

    // 2. Z1 slice = xk @ W1s  (+b1 later). wave w -> n-tile w
    f32x4 z1a; z1a[0]=0.f; z1a[1]=0.f; z1a[2]=0.f; z1a[3]=0.f;
#pragma unroll
    for (int ks = 0; ks < 8; ks++){
      bf16x8 av = *(const bf16x8*)&lds[O_XKQ + lm * 264 + ks * 32 + qd * 8];
      bf16x8 bv = *(const bf16x8*)&lds[O_W1BT + (w * 16 + lm) * 264 + ks * 32 + qd * 8];
      z1a = __builtin_amdgcn_mfma_f32_16x16x32_bf16(av, bv, z1a, 0, 0, 0);
    }
    float z1v[4];
    {
      float b1n = ldsf[w * 16 + lm];
#pragma unroll
      for (int rr = 0; rr < 4; rr++){
        z1v[rr] = z1a[rr] + b1n;
        int mr = qd * 4 + rr;
        if (mr < 10){
          float a1 = gelu_f(z1v[rr]);
          unsigned short ab = f2bf(a1);
          lds[O_A1 + mr * 72 + w * 16 + lm] = ab;
          lds[O_A1T + (w * 16 + lm) * 40 + mr] = ab;
        }
      }
    }
    __syncthreads();

    // 4. Z2 partial = A1s @ W2s  -> global fp32 partials
#pragma unroll
    for (int nt4 = 0; nt4 < 4; nt4++){
      int nt = 4 * w + nt4;
      f32x4 p; p[0]=0.f; p[1]=0.f; p[2]=0.f; p[3]=0.f;
#pragma unroll
      for (int ks = 0; ks < 2; ks++){
        bf16x8 av = *(const bf16x8*)&lds[O_A1 + lm * 72 + ks * 32 + qd * 8];
        bf16x8 bv = *(const bf16x8*)&lds[O_W2N + (nt * 16 + lm) * 72 + ks * 32 + qd * 8];
        p = __builtin_amdgcn_mfma_f32_16x16x32_bf16(av, bv, p, 0, 0, 0);
      }
#pragma unroll
      for (int rr = 0; rr < 4; rr++){
        int mr = qd * 4 + rr;
        if (mr < 10)
          pz2f[((size_t)(h * 16 + sl) * 10 + mr) * 256 + nt * 16 + lm] = p[rr];
      }
    }

    // 5. per-head barrier (release: this chunk's Z2 partials + prev chunk's Z2q partials)
    __threadfence();
    __syncthreads();
    if (tid == 0){
      atomicAdd(bar + h, 1u);
      unsigned int target = 16u * (unsigned int)(nch + 1);
      unsigned int spins = 0;
      while (__hip_atomic_load(bar + h, __ATOMIC_ACQUIRE, __HIP_MEMORY_SCOPE_AGENT) < target
             && spins < 4000000u){ spins++; __builtin_amdgcn_s_sleep(2); }
    }
    __syncthreads();
    __threadfence();   // acquire side: invalidate caches before reading partials

    // 6. reduce previous chunk's Z2q partials (off recurrence) -> z2qs (+b2 current)
    if (nch > 0 && tid < 160){
      int r2 = tid >> 4, c = sl * 16 + (tid & 15);
      float sum = 0.f;
      for (int g = 0; g < 16; g++)
        sum += pqf[((size_t)(h * 16 + g) * 10 + r2) * 256 + c];
      z2qs[((size_t)(h * 40 + nch - 1) * 10 + r2) * 256 + c] = sum + ldsf[64 + c];
    }

    // 7. gZ2 (fused LN-L2 backward), redundantly per WG. wave w -> rows w, w+4, w+8
    for (int r2 = w; r2 < 10; r2 += 4){
      int c0 = l * 4;
      float zz[4] = {0.f, 0.f, 0.f, 0.f};
      for (int g = 0; g < 16; g++){
        float4 u = *(const float4*)&pz2f[((size_t)(h * 16 + g) * 10 + r2) * 256 + c0];
        zz[0] += u.x; zz[1] += u.y; zz[2] += u.z; zz[3] += u.w;
      }
      float s1 = 0.f, s2 = 0.f;
#pragma unroll
      for (int i = 0; i < 4; i++){ zz[i] += ldsf[64 + c0 + i]; s1 += zz[i]; s2 += zz[i] * zz[i]; }
#pragma unroll
      for (int off = 32; off >= 1; off >>= 1){ s1 += __shfl_xor(s1, off, 64); s2 += __shfl_xor(s2, off, 64); }
      float mu = s1 * (1.f / 256.f);
      float var = s2 * (1.f / 256.f) - mu * mu;
      float rstd = rsqrtf(var + 1e-6f);
      float xh[4], gx[4];
      float t1 = 0.f, t2 = 0.f;
#pragma unroll
      for (int i = 0; i < 4; i++){
        xh[i] = (zz[i] - mu) * rstd;
        float gwv = ldsf[320 + c0 + i], gbv = ldsf[576 + c0 + i];
        float tg = bf2f(lds[O_TGT + r2 * 256 + c0 + i]);
        float go = gwv * xh[i] + gbv - tg;
        gx[i] = go * gwv;
        t1 += gx[i]; t2 += gx[i] * xh[i];
      }
#pragma unroll
      for (int off = 32; off >= 1; off >>= 1){ t1 += __shfl_xor(t1, off, 64); t2 += __shfl_xor(t2, off, 64); }
      float m1 = t1 * (1.f / 256.f), m2 = t2 * (1.f / 256.f);
      float g0 = (gx[0] - m1 - xh[0] * m2) * rstd;
      float g1 = (gx[1] - m1 - xh[1] * m2) * rstd;
      float g2 = (gx[2] - m1 - xh[2] * m2) * rstd;
      float g3 = (gx[3] - m1 - xh[3] * m2) * rstd;
      unsigned int p0 = f2bf(g0) | ((unsigned int)f2bf(g1) << 16);
      unsigned int p1 = f2bf(g2) | ((unsigned int)f2bf(g3) << 16);
      *(unsigned int*)&lds[O_GZ2 + r2 * 264 + c0]     = p0;
      *(unsigned int*)&lds[O_GZ2 + r2 * 264 + c0 + 2] = p1;
    }
    __syncthreads();

    // 9a. b2 -= eta * sum_rows(gZ2)
    {
      float sum = 0.f;
#pragma unroll
      for (int r2 = 0; r2 < 10; r2++) sum += bf2f(lds[O_GZ2 + r2 * 264 + tid]);
      ldsf[64 + tid] -= ETA * sum;
    }
    // 9b. gZ1 slice = (gZ2 @ W2s^T) * gelu'(Z1)
    {
      f32x4 g1a; g1a[0]=0.f; g1a[1]=0.f; g1a[2]=0.f; g1a[3]=0.f;
#pragma unroll
      for (int ks = 0; ks < 8; ks++){
        bf16x8 av = *(const bf16x8*)&lds[O_GZ2 + lm * 264 + ks * 32 + qd * 8];
        bf16x8 bv = *(const bf16x8*)&lds[O_W2K + (w * 16 + lm) * 264 + ks * 32 + qd * 8];
        g1a = __builtin_amdgcn_mfma_f32_16x16x32_bf16(av, bv, g1a, 0, 0, 0);
      }
#pragma unroll
      for (int rr = 0; rr < 4; rr++){
        int mr = qd * 4 + rr;
        if (mr < 10){
          float gz1 = g1a[rr] * gelu_bwd_f(z1v[rr]);
          lds[O_GZ1 + (w * 16 + lm) * 40 + mr] = f2bf(gz1);
        }
      }
    }
    __syncthreads();

    // 11a. b1 -= eta * colsum(gZ1)
    if (tid < 64){
      float sum = 0.f;
#pragma unroll
      for (int kx = 0; kx < 10; kx++) sum += bf2f(lds[O_GZ1 + tid * 40 + kx]);
      ldsf[tid] -= ETA * sum;
    }
    // 11b. W1 update: dW1 = xk^T @ gZ1  (A from XKQ scalar reads; B = GZ1 n-major)
#pragma unroll
    for (int a = 0; a < 4; a++){
      int mt = 4 * w + a;
      Frag afr;
#pragma unroll
      for (int j8 = 0; j8 < 8; j8++)
        afr.u[j8] = lds[O_XKQ + (qd * 8 + j8) * 264 + mt * 16 + lm];  // k>=10 * zero-B
#pragma unroll
      for (int nt = 0; nt < 4; nt++){
        bf16x8 bv = *(const bf16x8*)&lds[O_GZ1 + (nt * 16 + lm) * 40 + qd * 8];
        f32x4 d; d[0]=0.f; d[1]=0.f; d[2]=0.f; d[3]=0.f;
        d = __builtin_amdgcn_mfma_f32_16x16x32_bf16(afr.v, bv, d, 0, 0, 0);
#pragma unroll
        for (int rr = 0; rr < 4; rr++) w1r[a][nt][rr] -= ETA * d[rr];
      }
    }
    // 11c. W2 update: dW2 = A1^T @ gZ2  (A = A1T b128; B = GZ2 scalar reads)
    {
      bf16x8 av2 = *(const bf16x8*)&lds[O_A1T + (w * 16 + lm) * 40 + qd * 8];  // cols>=10 zero
#pragma unroll
      for (int nt = 0; nt < 16; nt++){
        Frag bfr;
#pragma unroll
        for (int j8 = 0; j8 < 8; j8++)
          bfr.u[j8] = lds[O_GZ2 + (qd * 8 + j8) * 264 + nt * 16 + lm]; // rows>=16 -> ZPAD
        f32x4 d; d[0]=0.f; d[1]=0.f; d[2]=0.f; d[3]=0.f;
        d = __builtin_amdgcn_mfma_f32_16x16x32_bf16(av2, bfr.v, d, 0, 0, 0);
#pragma unroll
        for (int rr = 0; rr < 4; rr++) w2r[nt][rr] -= ETA * d[rr];
      }
    }
    WRITE_W1BF();
    WRITE_W2BF();
    __syncthreads();

    // 13. load xq into XKQ
    {
      const float* qp = qg + hb + (size_t)nch * 10 * 256;
#pragma unroll
      for (int r2 = 0; r2 < 10; r2++)
        lds[O_XKQ + r2 * 264 + tid] = f2bf(qp[r2 * 256 + tid]);
    }
    __syncthreads();

    // 15. Z1q = xq @ W1_new + b1_new -> A1q
    {
      f32x4 zq; zq[0]=0.f; zq[1]=0.f; zq[2]=0.f; zq[3]=0.f;
#pragma unroll
      for (int ks = 0; ks < 8; ks++){
        bf16x8 av = *(const bf16x8*)&lds[O_XKQ + lm * 264 + ks * 32 + qd * 8];
        bf16x8 bv = *(const bf16x8*)&lds[O_W1BT + (w * 16 + lm) * 264 + ks * 32 + qd * 8];
        zq = __builtin_amdgcn_mfma_f32_16x16x32_bf16(av, bv, zq, 0, 0, 0);
      }
      float b1n = ldsf[w * 16 + lm];
#pragma unroll
      for (int rr = 0; rr < 4; rr++){
        int mr = qd * 4 + rr;
        if (mr < 10)
          lds[O_A1 + mr * 72 + w * 16 + lm] = f2bf(gelu_f(zq[rr] + b1n));
      }
    }
    __syncthreads();

    // 17. Z2q partial = A1q @ W2_new -> global (reduced next chunk / after loop)
#pragma unroll
    for (int nt4 = 0; nt4 < 4; nt4++){
      int nt = 4 * w + nt4;
      f32x4 p; p[0]=0.f; p[1]=0.f; p[2]=0.f; p[3]=0.f;
#pragma unroll
      for (int ks = 0; ks < 2; ks++){
        bf16x8 av = *(const bf16x8*)&lds[O_A1 + lm * 72 + ks * 32 + qd * 8];
        bf16x8 bv = *(const bf16x8*)&lds[O_W2N + (nt * 16 + lm) * 72 + ks * 32 + qd * 8];
        p = __builtin_amdgcn_mfma_f32_16x16x32_bf16(av, bv, p, 0, 0, 0);
      }
#pragma unroll
      for (int rr = 0; rr < 4; rr++){
        int mr = qd * 4 + rr;
        if (mr < 10)
          pqf[((size_t)(h * 16 + sl) * 10 + mr) * 256 + nt * 16 + lm] = p[rr];
      }
    }
    __syncthreads();
  }

  // final barrier + reduce last chunk's Z2q
  __threadfence();
  __syncthreads();
  if (tid == 0){
    atomicAdd(bar + h, 1u);
    unsigned int spins = 0;
    while (__hip_atomic_load(bar + h, __ATOMIC_ACQUIRE, __HIP_MEMORY_SCOPE_AGENT) < 16u * 41u
           && spins < 4000000u){ spins++; __builtin_amdgcn_s_sleep(2); }
  }
  __syncthreads();
  __threadfence();
  if (tid < 160){
    int r2 = tid >> 4, c = sl * 16 + (tid & 15);
    float sum = 0.f;
    for (int g = 0; g < 16; g++)
      sum += pqf[((size_t)(h * 16 + g) * 10 + r2) * 256 + c];
    z2qs[((size_t)(h * 40 + 39) * 10 + r2) * 256 + c] = sum + ldsf[64 + c];
  }
}

// ---------------------------------------------------------------------------
// LN forward + residual: o[b*400+t][hh*256+d] = xq + gw*xhat(Z2q) + gb  (bf16)
// one wave per (head,t) row; 1600 blocks x 256 threads
// ---------------------------------------------------------------------------
__global__ __launch_bounds__(256) void k_lnout(
    const float* __restrict__ z2qs, const float* __restrict__ qg,
    const float* __restrict__ gwg, const float* __restrict__ gbg,
    unsigned short* __restrict__ obf)
{
  int w = threadIdx.x >> 6, l = threadIdx.x & 63;
  int gr = blockIdx.x * 4 + w;       // 0..6399
  int h = gr / 400, t = gr % 400, hh = h & 7, b = h >> 3;
  int c0 = l * 4;
  const float* zp = &z2qs[((size_t)h * 400 + t) * 256];
  float z[4]; float s1 = 0.f, s2 = 0.f;
#pragma unroll
  for (int i = 0; i < 4; i++){ z[i] = zp[c0 + i]; s1 += z[i]; s2 += z[i] * z[i]; }
#pragma unroll
  for (int off = 32; off >= 1; off >>= 1){ s1 += __shfl_xor(s1, off, 64); s2 += __shfl_xor(s2, off, 64); }
  float mu = s1 * (1.f / 256.f);
  float var = s2 * (1.f / 256.f) - mu * mu;
  float rstd = rsqrtf(var + 1e-6f);
  const float* qp = &qg[((size_t)h * 400 + t) * 256];
  unsigned short* op = &obf[((size_t)(b * 400 + t)) * 2048 + hh * 256];
#pragma unroll
  for (int i = 0; i < 4; i++){
    float xh = (z[i] - mu) * rstd;
    float o = qp[c0 + i] + gwg[hh * 256 + c0 + i] * xh + gbg[hh * 256 + c0 + i];
    op[c0 + i] = f2bf(o);
  }
}

// ---------------------------------------------------------------------------
// launch
// ---------------------------------------------------------------------------
// ws layout (bytes)
#define WS_WEFF   0u          // bf16 [2048][7744]
#define WS_P      31719424u   // bf16 [800][7744]
#define WS_WQKV   44109824u   // bf16 [6144][2048]
#define WS_WO     69275648u   // bf16 [2048][2048]
#define WS_XB     77664256u   // bf16 [800][2048]
#define WS_Q      80941056u   // f32 [16][400][256]
#define WS_K      87494656u
#define WS_V      94048256u
#define WS_PZ2    100601856u  // f32 [16][16][10][256]
#define WS_PQ     103223296u
#define WS_Z2QS   105844736u  // f32 [16][400][256]
#define WS_OBF    112398336u  // bf16 [800][2048]
#define WS_BSUM   115675136u  // f32 [2048]
#define WS_BAR    115683328u  // u32 [16] (+pad)

extern "C" void kernel_launch(void* const* d_in, const int* in_sizes, int n_in,
                              void* d_out, int out_size, void* d_ws, size_t ws_size,
                              hipStream_t stream)
{
  (void)in_sizes; (void)n_in; (void)out_size; (void)ws_size;
  const float* x  = (const float*)d_in[0];
  const float* cw[6]; const float* cb[6];
  for (int i = 0; i < 6; i++){ cw[i] = (const float*)d_in[2 + 2 * i]; cb[i] = (const float*)d_in[3 + 2 * i]; }
  const float* wq  = (const float*)d_in[14];
  const float* wk  = (const float*)d_in[15];
  const float* wv  = (const float*)d_in[16];
  const float* wo  = (const float*)d_in[17];
  const float* W1  = (const float*)d_in[18];
  const float* b1  = (const float*)d_in[19];
  const float* W2  = (const float*)d_in[20];
  const float* b2  = (const float*)d_in[21];
  const float* lnw = (const float*)d_in[22];
  const float* lnb = (const float*)d_in[23];
  float* outf = (float*)d_out;

  char* wsb = (char*)d_ws;
  unsigned short* weff = (unsigned short*)(wsb + WS_WEFF);
  unsigned short* P    = (unsigned short*)(wsb + WS_P);
  unsigned short* wqkv = (unsigned short*)(wsb + WS_WQKV);
  unsigned short* wob  = (unsigned short*)(wsb + WS_WO);
  unsigned short* xb   = (unsigned short*)(wsb + WS_XB);
  float* qb   = (float*)(wsb + WS_Q);
  float* kb   = (float*)(wsb + WS_K);
  float* vb   = (float*)(wsb + WS_V);
  float* pz2  = (float*)(wsb + WS_PZ2);
  float* pq   = (float*)(wsb + WS_PQ);
  float* z2qs = (float*)(wsb + WS_Z2QS);
  unsigned short* obf = (unsigned short*)(wsb + WS_OBF);
  float* bsum = (float*)(wsb + WS_BSUM);
  unsigned int* bar = (unsigned int*)(wsb + WS_BAR);

  hipMemsetAsync(bar, 0, 256, stream);
  hipFuncSetAttribute(reinterpret_cast<const void*>(k_ttt),
                      hipFuncAttributeMaxDynamicSharedMemorySize, TTT_LDS_BYTES);

  k_weff<<<(2048 * 7744 + 255) / 256, 256, 0, stream>>>(cw[0], cw[1], cw[2], cw[3], cw[4], cw[5], weff);
  k_im2col<<<(800 * 7744 + 255) / 256, 256, 0, stream>>>(x, P);
  k_wqkv<<<(6144 * 2048 + 255) / 256, 256, 0, stream>>>(wq, wk, wv, wqkv);
  k_f2bf_copy<<<(2048 * 2048 + 255) / 256, 256, 0, stream>>>(wo, wob, 2048 * 2048);
  k_bsum<<<8, 256, 0, stream>>>(cb[0], cb[1], cb[2], cb[3], cb[4], cb[5], bsum);

  // conv-as-GEMM: [2048]x[800] over K=7744, epilogue mean/6 + silu -> xb bf16
  k_gemm<0><<<dim3(16, 7), 256, 0, stream>>>(weff, P, 2048, 800, 7744,
                                             bsum, xb, nullptr, nullptr, nullptr, nullptr);
  // QKV: [6144]x[800] over K=2048 -> q/k/v fp32 per-head
  k_gemm<1><<<dim3(48, 7), 256, 0, stream>>>(wqkv, xb, 6144, 800, 2048,
                                             nullptr, nullptr, qb, kb, vb, nullptr);
  // TTT scan (persistent, 256 WGs, per-head barriers)
  k_ttt<<<256, 256, TTT_LDS_BYTES, stream>>>(qb, kb, vb, W1, b1, W2, b2, lnw, lnb,
                                             pz2, pq, z2qs, bar);
  // LN fwd + residual -> o bf16
  k_lnout<<<1600, 256, 0, stream>>>(z2qs, qb, lnw, lnb, obf);
  // output projection: [2048]x[800] over K=2048 -> d_out fp32
  k_gemm<2><<<dim3(16, 7), 256, 0, stream>>>(wob, obf, 2048, 800, 2048,
                                             nullptr, nullptr, nullptr, nullptr, nullptr, outf);
}

// Round 2
// 1846.605 us; speedup vs baseline: 1.7653x; 1.7653x over previous
//
#include <hip/hip_runtime.h>

// ---------------------------------------------------------------------------
// Branch_62989990363328: TimesBlock conv ensemble -> TTT-MLP -> out proj
// B=2 T=400 C=64 OUT=2048 NH=8 HD=256 INNER=1024 MB=10 NC=40
// R1: k_ttt cross-WG exchange via agent-scope RELAXED atomics (sc0/sc1 path,
//     MALL-coherent) instead of __threadfence() (wbl2+inv full-L2 flushes)
//     and ACQUIRE spin polls (inv per poll). No cache maintenance ops remain.
// ---------------------------------------------------------------------------

typedef __bf16 bf16x8 __attribute__((ext_vector_type(8)));
typedef float  f32x4  __attribute__((ext_vector_type(4)));

__device__ __forceinline__ unsigned short f2bf(float f){
  unsigned int u = __builtin_bit_cast(unsigned int, f);
  u += 0x7fffu + ((u >> 16) & 1u);
  return (unsigned short)(u >> 16);
}
__device__ __forceinline__ float bf2f(unsigned short b){
  unsigned int u = ((unsigned int)b) << 16;
  return __builtin_bit_cast(float, u);
}
__device__ __forceinline__ float gelu_f(float x){
  return 0.5f * x * (1.0f + erff(x * 0.70710678118654752f));
}
__device__ __forceinline__ float gelu_bwd_f(float x){
  return 0.5f * (1.0f + erff(x * 0.70710678118654752f))
       + x * __expf(-0.5f * x * x) * 0.3989422804014327f;
}

// agent-scope relaxed atomic helpers (coherent at MALL, no wbl2/inv)
__device__ __forceinline__ void astore(float* p, float v){
  __hip_atomic_store(p, v, __ATOMIC_RELAXED, __HIP_MEMORY_SCOPE_AGENT);
}
__device__ __forceinline__ float aload(const float* p){
  return __hip_atomic_load(p, __ATOMIC_RELAXED, __HIP_MEMORY_SCOPE_AGENT);
}
__device__ __forceinline__ float2 aload2(const float* p){
  unsigned long long v = __hip_atomic_load((const unsigned long long*)p,
                                           __ATOMIC_RELAXED, __HIP_MEMORY_SCOPE_AGENT);
  union { unsigned long long u; float2 f; } cv; cv.u = v; return cv.f;
}

union Frag { bf16x8 v; unsigned short u[8]; };

// ---------------------------------------------------------------------------
// Prep kernels
// ---------------------------------------------------------------------------

__global__ __launch_bounds__(256) void k_weff(
    const float* __restrict__ w0, const float* __restrict__ w1,
    const float* __restrict__ w2, const float* __restrict__ w3,
    const float* __restrict__ w4, const float* __restrict__ w5,
    unsigned short* __restrict__ weff)
{
  int idx = blockIdx.x * 256 + threadIdx.x;
  if (idx >= 2048 * 7744) return;
  int o = idx / 7744, k = idx % 7744;
  int c = k / 121, dd = k % 121, di = dd / 11, dj = dd % 11;
  const float* ws6[6] = {w0, w1, w2, w3, w4, w5};
  float s = 0.f;
#pragma unroll
  for (int i = 0; i < 6; i++){
    int kk = 2 * i + 1;
    int a = di - 5 + i, b = dj - 5 + i;
    if (a >= 0 && a < kk && b >= 0 && b < kk)
      s += ws6[i][(((size_t)o * 64 + c) * kk + a) * kk + b];
  }
  weff[idx] = f2bf(s);
}

__global__ __launch_bounds__(256) void k_im2col(
    const float* __restrict__ x, unsigned short* __restrict__ P)
{
  int idx = blockIdx.x * 256 + threadIdx.x;
  if (idx >= 800 * 7744) return;
  int n = idx / 7744, k = idx % 7744;
  int c = k / 121, dd = k % 121, di = dd / 11, dj = dd % 11;
  int b = n / 400, pos = n % 400, i = pos / 20, j = pos % 20;
  int ii = i + di - 5, jj = j + dj - 5;
  float v = 0.f;
  if (ii >= 0 && ii < 20 && jj >= 0 && jj < 20)
    v = x[((size_t)b * 400 + ii * 20 + jj) * 64 + c];
  P[idx] = f2bf(v);
}

__global__ __launch_bounds__(256) void k_wqkv(
    const float* __restrict__ wq, const float* __restrict__ wk,
    const float* __restrict__ wv, unsigned short* __restrict__ dst)
{
  int idx = blockIdx.x * 256 + threadIdx.x;
  if (idx >= 6144 * 2048) return;
  int m = idx >> 11, kk = idx & 2047;
  const float* src = (m < 2048) ? wq : ((m < 4096) ? wk : wv);
  dst[idx] = f2bf(src[(size_t)(m & 2047) * 2048 + kk]);
}

__global__ __launch_bounds__(256) void k_f2bf_copy(
    const float* __restrict__ src, unsigned short* __restrict__ dst, int n)
{
  int idx = blockIdx.x * 256 + threadIdx.x;
  if (idx < n) dst[idx] = f2bf(src[idx]);
}

__global__ __launch_bounds__(256) void k_bsum(
    const float* __restrict__ b0, const float* __restrict__ b1,
    const float* __restrict__ b2, const float* __restrict__ b3,
    const float* __restrict__ b4, const float* __restrict__ b5,
    float* __restrict__ bsum)
{
  int idx = blockIdx.x * 256 + threadIdx.x;
  if (idx < 2048)
    bsum[idx] = b0[idx] + b1[idx] + b2[idx] + b3[idx] + b4[idx] + b5[idx];
}

// ---------------------------------------------------------------------------
// Generic bf16 MFMA GEMM: C[M][N] = A[M][K] * B[N][K]^T
// ---------------------------------------------------------------------------
template<int MODE>
__global__ __launch_bounds__(256, 1) void k_gemm(
    const unsigned short* __restrict__ A, const unsigned short* __restrict__ B,
    int M, int N, int K,
    const float* __restrict__ bsum, unsigned short* __restrict__ out_bf,
    float* __restrict__ qb, float* __restrict__ kb, float* __restrict__ vb,
    float* __restrict__ outf)
{
  __shared__ unsigned short As[128 * 32];
  __shared__ unsigned short Bs[128 * 32];
  int tid = threadIdx.x, w = tid >> 6, l = tid & 63, qd = l >> 4, lm = l & 15;
  int m0 = blockIdx.x * 128, n0 = blockIdx.y * 128;

  f32x4 acc[4][4];
#pragma unroll
  for (int i = 0; i < 4; i++)
#pragma unroll
    for (int j = 0; j < 4; j++){ acc[i][j][0]=0.f; acc[i][j][1]=0.f; acc[i][j][2]=0.f; acc[i][j][3]=0.f; }

  int nk = K >> 5;
  for (int kt = 0; kt < nk; kt++){
    int k0 = kt << 5;
#pragma unroll
    for (int i = 0; i < 2; i++){
      int cidx = tid + i * 256;
      int row = cidx >> 2, kc = (cidx & 3) << 3;
      *(uint4*)&As[row * 32 + kc] = *(const uint4*)&A[(size_t)(m0 + row) * K + k0 + kc];
      int br = n0 + row; if (br >= N) br = N - 1;
      *(uint4*)&Bs[row * 32 + kc] = *(const uint4*)&B[(size_t)br * K + k0 + kc];
    }
    __syncthreads();
    bf16x8 af[4], bfv[4];
#pragma unroll
    for (int i = 0; i < 4; i++)
      af[i] = *(const bf16x8*)&As[((w >> 1) * 64 + i * 16 + lm) * 32 + qd * 8];
#pragma unroll
    for (int j = 0; j < 4; j++)
      bfv[j] = *(const bf16x8*)&Bs[((w & 1) * 64 + j * 16 + lm) * 32 + qd * 8];
#pragma unroll
    for (int i = 0; i < 4; i++)
#pragma unroll
      for (int j = 0; j < 4; j++)
        acc[i][j] = __builtin_amdgcn_mfma_f32_16x16x32_bf16(af[i], bfv[j], acc[i][j], 0, 0, 0);
    __syncthreads();
  }

#pragma unroll
  for (int i = 0; i < 4; i++){
    int mBase = m0 + (w >> 1) * 64 + i * 16 + qd * 4;
#pragma unroll
    for (int j = 0; j < 4; j++){
      int n = n0 + (w & 1) * 64 + j * 16 + lm;
      if (n < N){
#pragma unroll
        for (int rr = 0; rr < 4; rr++){
          float val = acc[i][j][rr];
          int mm = mBase + rr;
          if (MODE == 0){
            float t = (val + bsum[mm]) * (1.0f / 6.0f);
            float sv = t / (1.0f + __expf(-t));
            out_bf[(size_t)n * 2048 + mm] = f2bf(sv);
          } else if (MODE == 1){
            int proj = mm >> 11, o = mm & 2047, hh = o >> 8, d = o & 255;
            int bh = (n / 400) * 8 + hh, tt = n % 400;
            float* dst = (proj == 0) ? qb : ((proj == 1) ? kb : vb);
            dst[((size_t)bh * 400 + tt) * 256 + d] = val;
          } else {
            outf[(size_t)n * 2048 + mm] = val;
          }
        }
      }
    }
  }
}

// ---------------------------------------------------------------------------
// TTT persistent kernel. 256 WGs: 16 heads x 16 INNER-slices (64 wide).
// Cross-WG exchange exclusively via agent-scope relaxed atomics.
// ---------------------------------------------------------------------------
#define O_W1BT 0
#define O_W2K  16896
#define O_W2N  33792
#define O_XKQ  52224
#define O_TGT  56448
#define O_A1   59008
#define O_A1T  60160
#define O_GZ2  62720
#define O_ZPAD 66944
#define O_GZ1  71168
#define US_TOTAL 73728
#define O_F32  73728
#define TTT_LDS_BYTES (73728 * 2 + 832 * 4)   // 150784 <= 163840

#define ETA 0.01f

__global__ __launch_bounds__(256, 1) void k_ttt(
    const float* __restrict__ qg, const float* __restrict__ kg, const float* __restrict__ vg,
    const float* __restrict__ W1g, const float* __restrict__ b1g,
    const float* __restrict__ W2g, const float* __restrict__ b2g,
    const float* __restrict__ gwg, const float* __restrict__ gbg,
    float* __restrict__ pz2f, float* __restrict__ pqf,
    float* __restrict__ z2qs, unsigned int* __restrict__ bar)
{
  extern __shared__ unsigned short lds[];
  float* ldsf = (float*)&lds[O_F32];

  int tid = threadIdx.x, w = tid >> 6, l = tid & 63, qd = l >> 4, lm = l & 15;
  int bid = blockIdx.x;
  int jj = bid >> 3, xx = bid & 7;
  int h  = xx + 8 * (jj >> 4);   // bh = b*8 + head  (0..15)
  int sl = jj & 15;              // INNER slice (0..15)
  int hh = h & 7;

  for (int i = tid; i < US_TOTAL; i += 256) lds[i] = 0;
  for (int i = tid; i < 832; i += 256) ldsf[i] = 0.f;
  __syncthreads();

  float w1r[4][4][4];
#pragma unroll
  for (int a = 0; a < 4; a++)
#pragma unroll
    for (int nt = 0; nt < 4; nt++)
#pragma unroll
      for (int rr = 0; rr < 4; rr++)
        w1r[a][nt][rr] = W1g[((size_t)hh * 256 + (4 * w + a) * 16 + qd * 4 + rr) * 1024
                             + sl * 64 + nt * 16 + lm];
  float w2r[16][4];
#pragma unroll
  for (int nt = 0; nt < 16; nt++)
#pragma unroll
    for (int rr = 0; rr < 4; rr++)
      w2r[nt][rr] = W2g[((size_t)hh * 1024 + sl * 64 + w * 16 + qd * 4 + rr) * 256
                        + nt * 16 + lm];
  if (tid < 64)  ldsf[tid] = b1g[hh * 1024 + sl * 64 + tid];
  if (tid < 256){
    ldsf[64 + tid]  = b2g[hh * 256 + tid];
    ldsf[320 + tid] = gwg[hh * 256 + tid];
    ldsf[576 + tid] = gbg[hh * 256 + tid];
  }

#define WRITE_W1BF() do { \
  _Pragma("unroll") for (int a = 0; a < 4; a++){ \
    int m0i = (4 * w + a) * 16 + qd * 4; \
    _Pragma("unroll") for (int nt = 0; nt < 4; nt++){ \
      int n = nt * 16 + lm; \
      unsigned int p0 = f2bf(w1r[a][nt][0]) | ((unsigned int)f2bf(w1r[a][nt][1]) << 16); \
      unsigned int p1 = f2bf(w1r[a][nt][2]) | ((unsigned int)f2bf(w1r[a][nt][3]) << 16); \
      *(unsigned int*)&lds[O_W1BT + n * 264 + m0i]     = p0; \
      *(unsigned int*)&lds[O_W1BT + n * 264 + m0i + 2] = p1; \
    } } } while(0)

#define WRITE_W2BF() do { \
  int mB = w * 16 + qd * 4; \
  _Pragma("unroll") for (int nt = 0; nt < 16; nt++){ \
    int n = nt * 16 + lm; \
    _Pragma("unroll") for (int rr = 0; rr < 4; rr++) \
      lds[O_W2K + (mB + rr) * 264 + n] = f2bf(w2r[nt][rr]); \
    unsigned int p0 = f2bf(w2r[nt][0]) | ((unsigned int)f2bf(w2r[nt][1]) << 16); \
    unsigned int p1 = f2bf(w2r[nt][2]) | ((unsigned int)f2bf(w2r[nt][3]) << 16); \
    *(unsigned int*)&lds[O_W2N + n * 72 + mB]     = p0; \
    *(unsigned int*)&lds[O_W2N + n * 72 + mB + 2] = p1; \
  } } while(0)

  WRITE_W1BF();
  WRITE_W2BF();
  __syncthreads();

  const size_t hb = (size_t)h * 400 * 256;

  for (int nch = 0; nch < 40; nch++){
    // 1. load xk chunk + tgt = xv - xk
    {
      const float* kp = kg + hb + (size_t)nch * 10 * 256;
      const float* vp = vg + hb + (size_t)nch * 10 * 256;
#pragma unroll
      for (int r2 = 0; r2 < 10; r2++){
        float kv = kp[r2 * 256 + tid];
        float vv = vp[r2 * 256 + tid];
        lds[O_XKQ + r2 * 264 + tid] = f2bf(kv);
        lds[O_TGT + r2 * 256 + tid] = f2bf(vv - kv);
      }
    }
    __syncthreads();

    // 2. Z1 slice = xk @ W1s
    f32x4 z1a; z1a[0]=0.f; z1a[1]=0.f; z1a[2]=0.f; z1a[3]=0.f;
#pragma unroll
    for (int ks = 0; ks < 8; ks++){
      bf16x8 av = *(const bf16x8*)&lds[O_XKQ + lm * 264 + ks * 32 + qd * 8];
      bf16x8 bv = *(const bf16x8*)&lds[O_W1BT + (w * 16 + lm) * 264 + ks * 32 + qd * 8];
      z1a = __builtin_amdgcn_mfma_f32_16x16x32_bf16(av, bv, z1a, 0, 0, 0);
    }
    float z1v[4];
    {
      float b1n = ldsf[w * 16 + lm];
#pragma unroll
      for (int rr = 0; rr < 4; rr++){
        z1v[rr] = z1a[rr] + b1n;
        int mr = qd * 4 + rr;
        if (mr < 10){
          float a1 = gelu_f(z1v[rr]);
          unsigned short ab = f2bf(a1);
          lds[O_A1 + mr * 72 + w * 16 + lm] = ab;
          lds[O_A1T + (w * 16 + lm) * 40 + mr] = ab;
        }
      }
    }
    __syncthreads();

    // 4. Z2 partial = A1s @ W2s -> global fp32 partials (agent atomics)
#pragma unroll
    for (int nt4 = 0; nt4 < 4; nt4++){
      int nt = 4 * w + nt4;
      f32x4 p; p[0]=0.f; p[1]=0.f; p[2]=0.f; p[3]=0.f;
#pragma unroll
      for (int ks = 0; ks < 2; ks++){
        bf16x8 av = *(const bf16x8*)&lds[O_A1 + lm * 72 + ks * 32 + qd * 8];
        bf16x8 bv = *(const bf16x8*)&lds[O_W2N + (nt * 16 + lm) * 72 + ks * 32 + qd * 8];
        p = __builtin_amdgcn_mfma_f32_16x16x32_bf16(av, bv, p, 0, 0, 0);
      }
#pragma unroll
      for (int rr = 0; rr < 4; rr++){
        int mr = qd * 4 + rr;
        if (mr < 10)
          astore(&pz2f[((size_t)(h * 16 + sl) * 10 + mr) * 256 + nt * 16 + lm], p[rr]);
      }
    }

    // 5. per-head barrier. __syncthreads() drains vmcnt(0) per wave (release);
    //    exchanged data is MALL-coherent (sc1 atomics) so no cache maintenance.
    __syncthreads();
    if (tid == 0){
      __hip_atomic_fetch_add(bar + h, 1u, __ATOMIC_RELAXED, __HIP_MEMORY_SCOPE_AGENT);
      unsigned int target = 16u * (unsigned int)(nch + 1);
      unsigned int spins = 0;
      while (__hip_atomic_load(bar + h, __ATOMIC_RELAXED, __HIP_MEMORY_SCOPE_AGENT) < target
             && spins < 8000000u){ spins++; __builtin_amdgcn_s_sleep(2); }
    }
    __syncthreads();

    // 6. reduce previous chunk's Z2q partials -> z2qs (+b2 current)
    if (nch > 0 && tid < 160){
      int r2 = tid >> 4, c = sl * 16 + (tid & 15);
      float sum = 0.f;
#pragma unroll
      for (int g = 0; g < 16; g++)
        sum += aload(&pqf[((size_t)(h * 16 + g) * 10 + r2) * 256 + c]);
      z2qs[((size_t)(h * 40 + nch - 1) * 10 + r2) * 256 + c] = sum + ldsf[64 + c];
    }

    // 7. gZ2 (fused LN-L2 backward), redundantly per WG
    for (int r2 = w; r2 < 10; r2 += 4){
      int c0 = l * 4;
      float zz[4] = {0.f, 0.f, 0.f, 0.f};
#pragma unroll
      for (int g = 0; g < 16; g++){
        const float* bp = &pz2f[((size_t)(h * 16 + g) * 10 + r2) * 256 + c0];
        float2 u01 = aload2(bp);
        float2 u23 = aload2(bp + 2);
        zz[0] += u01.x; zz[1] += u01.y; zz[2] += u23.x; zz[3] += u23.y;
      }
      float s1 = 0.f, s2 = 0.f;
#pragma unroll
      for (int i = 0; i < 4; i++){ zz[i] += ldsf[64 + c0 + i]; s1 += zz[i]; s2 += zz[i] * zz[i]; }
#pragma unroll
      for (int off = 32; off >= 1; off >>= 1){ s1 += __shfl_xor(s1, off, 64); s2 += __shfl_xor(s2, off, 64); }
      float mu = s1 * (1.f / 256.f);
      float var = s2 * (1.f / 256.f) - mu * mu;
      float rstd = rsqrtf(var + 1e-6f);
      float xh[4], gx[4];
      float t1 = 0.f, t2 = 0.f;
#pragma unroll
      for (int i = 0; i < 4; i++){
        xh[i] = (zz[i] - mu) * rstd;
        float gwv = ldsf[320 + c0 + i], gbv = ldsf[576 + c0 + i];
        float tg = bf2f(lds[O_TGT + r2 * 256 + c0 + i]);
        float go = gwv * xh[i] + gbv - tg;
        gx[i] = go * gwv;
        t1 += gx[i]; t2 += gx[i] * xh[i];
      }
#pragma unroll
      for (int off = 32; off >= 1; off >>= 1){ t1 += __shfl_xor(t1, off, 64); t2 += __shfl_xor(t2, off, 64); }
      float m1 = t1 * (1.f / 256.f), m2 = t2 * (1.f / 256.f);
      float g0 = (gx[0] - m1 - xh[0] * m2) * rstd;
      float g1 = (gx[1] - m1 - xh[1] * m2) * rstd;
      float g2 = (gx[2] - m1 - xh[2] * m2) * rstd;
      float g3 = (gx[3] - m1 - xh[3] * m2) * rstd;
      unsigned int p0 = f2bf(g0) | ((unsigned int)f2bf(g1) << 16);
      unsigned int p1 = f2bf(g2) | ((unsigned int)f2bf(g3) << 16);
      *(unsigned int*)&lds[O_GZ2 + r2 * 264 + c0]     = p0;
      *(unsigned int*)&lds[O_GZ2 + r2 * 264 + c0 + 2] = p1;
    }
    __syncthreads();

    // 9a. b2 -= eta * sum_rows(gZ2)
    {
      float sum = 0.f;
#pragma unroll
      for (int r2 = 0; r2 < 10; r2++) sum += bf2f(lds[O_GZ2 + r2 * 264 + tid]);
      ldsf[64 + tid] -= ETA * sum;
    }
    // 9b. gZ1 slice = (gZ2 @ W2s^T) * gelu'(Z1)
    {
      f32x4 g1a; g1a[0]=0.f; g1a[1]=0.f; g1a[2]=0.f; g1a[3]=0.f;
#pragma unroll
      for (int ks = 0; ks < 8; ks++){
        bf16x8 av = *(const bf16x8*)&lds[O_GZ2 + lm * 264 + ks * 32 + qd * 8];
        bf16x8 bv = *(const bf16x8*)&lds[O_W2K + (w * 16 + lm) * 264 + ks * 32 + qd * 8];
        g1a = __builtin_amdgcn_mfma_f32_16x16x32_bf16(av, bv, g1a, 0, 0, 0);
      }
#pragma unroll
      for (int rr = 0; rr < 4; rr++){
        int mr = qd * 4 + rr;
        if (mr < 10){
          float gz1 = g1a[rr] * gelu_bwd_f(z1v[rr]);
          lds[O_GZ1 + (w * 16 + lm) * 40 + mr] = f2bf(gz1);
        }
      }
    }
    __syncthreads();

    // 11a. b1 -= eta * colsum(gZ1)
    if (tid < 64){
      float sum = 0.f;
#pragma unroll
      for (int kx = 0; kx < 10; kx++) sum += bf2f(lds[O_GZ1 + tid * 40 + kx]);
      ldsf[tid] -= ETA * sum;
    }
    // 11b. W1 update: dW1 = xk^T @ gZ1
#pragma unroll
    for (int a = 0; a < 4; a++){
      int mt = 4 * w + a;
      Frag afr;
#pragma unroll
      for (int j8 = 0; j8 < 8; j8++)
        afr.u[j8] = lds[O_XKQ + (qd * 8 + j8) * 264 + mt * 16 + lm];
#pragma unroll
      for (int nt = 0; nt < 4; nt++){
        bf16x8 bv = *(const bf16x8*)&lds[O_GZ1 + (nt * 16 + lm) * 40 + qd * 8];
        f32x4 d; d[0]=0.f; d[1]=0.f; d[2]=0.f; d[3]=0.f;
        d = __builtin_amdgcn_mfma_f32_16x16x32_bf16(afr.v, bv, d, 0, 0, 0);
#pragma unroll
        for (int rr = 0; rr < 4; rr++) w1r[a][nt][rr] -= ETA * d[rr];
      }
    }
    // 11c. W2 update: dW2 = A1^T @ gZ2
    {
      bf16x8 av2 = *(const bf16x8*)&lds[O_A1T + (w * 16 + lm) * 40 + qd * 8];
#pragma unroll
      for (int nt = 0; nt < 16; nt++){
        Frag bfr;
#pragma unroll
        for (int j8 = 0; j8 < 8; j8++)
          bfr.u[j8] = lds[O_GZ2 + (qd * 8 + j8) * 264 + nt * 16 + lm];
        f32x4 d; d[0]=0.f; d[1]=0.f; d[2]=0.f; d[3]=0.f;
        d = __builtin_amdgcn_mfma_f32_16x16x32_bf16(av2, bfr.v, d, 0, 0, 0);
#pragma unroll
        for (int rr = 0; rr < 4; rr++) w2r[nt][rr] -= ETA * d[rr];
      }
    }
    WRITE_W1BF();
    WRITE_W2BF();
    __syncthreads();

    // 13. load xq into XKQ
    {
      const float* qp = qg + hb + (size_t)nch * 10 * 256;
#pragma unroll
      for (int r2 = 0; r2 < 10; r2++)
        lds[O_XKQ + r2 * 264 + tid] = f2bf(qp[r2 * 256 + tid]);
    }
    __syncthreads();

    // 15. Z1q = xq @ W1_new + b1_new -> A1q
    {
      f32x4 zq; zq[0]=0.f; zq[1]=0.f; zq[2]=0.f; zq[3]=0.f;
#pragma unroll
      for (int ks = 0; ks < 8; ks++){
        bf16x8 av = *(const bf16x8*)&lds[O_XKQ + lm * 264 + ks * 32 + qd * 8];
        bf16x8 bv = *(const bf16x8*)&lds[O_W1BT + (w * 16 + lm) * 264 + ks * 32 + qd * 8];
        zq = __builtin_amdgcn_mfma_f32_16x16x32_bf16(av, bv, zq, 0, 0, 0);
      }
      float b1n = ldsf[w * 16 + lm];
#pragma unroll
      for (int rr = 0; rr < 4; rr++){
        int mr = qd * 4 + rr;
        if (mr < 10)
          lds[O_A1 + mr * 72 + w * 16 + lm] = f2bf(gelu_f(zq[rr] + b1n));
      }
    }
    __syncthreads();

    // 17. Z2q partial = A1q @ W2_new -> global (agent atomics)
#pragma unroll
    for (int nt4 = 0; nt4 < 4; nt4++){
      int nt = 4 * w + nt4;
      f32x4 p; p[0]=0.f; p[1]=0.f; p[2]=0.f; p[3]=0.f;
#pragma unroll
      for (int ks = 0; ks < 2; ks++){
        bf16x8 av = *(const bf16x8*)&lds[O_A1 + lm * 72 + ks * 32 + qd * 8];
        bf16x8 bv = *(const bf16x8*)&lds[O_W2N + (nt * 16 + lm) * 72 + ks * 32 + qd * 8];
        p = __builtin_amdgcn_mfma_f32_16x16x32_bf16(av, bv, p, 0, 0, 0);
      }
#pragma unroll
      for (int rr = 0; rr < 4; rr++){
        int mr = qd * 4 + rr;
        if (mr < 10)
          astore(&pqf[((size_t)(h * 16 + sl) * 10 + mr) * 256 + nt * 16 + lm], p[rr]);
      }
    }
    __syncthreads();
  }

  // final barrier + reduce last chunk's Z2q
  __syncthreads();
  if (tid == 0){
    __hip_atomic_fetch_add(bar + h, 1u, __ATOMIC_RELAXED, __HIP_MEMORY_SCOPE_AGENT);
    unsigned int spins = 0;
    while (__hip_atomic_load(bar + h, __ATOMIC_RELAXED, __HIP_MEMORY_SCOPE_AGENT) < 16u * 41u
           && spins < 8000000u){ spins++; __builtin_amdgcn_s_sleep(2); }
  }
  __syncthreads();
  if (tid < 160){
    int r2 = tid >> 4, c = sl * 16 + (tid & 15);
    float sum = 0.f;
#pragma unroll
    for (int g = 0; g < 16; g++)
      sum += aload(&pqf[((size_t)(h * 16 + g) * 10 + r2) * 256 + c]);
    z2qs[((size_t)(h * 40 + 39) * 10 + r2) * 256 + c] = sum + ldsf[64 + c];
  }
}

// ---------------------------------------------------------------------------
// LN forward + residual
// ---------------------------------------------------------------------------
__global__ __launch_bounds__(256) void k_lnout(
    const float* __restrict__ z2qs, const float* __restrict__ qg,
    const float* __restrict__ gwg, const float* __restrict__ gbg,
    unsigned short* __restrict__ obf)
{
  int w = threadIdx.x >> 6, l = threadIdx.x & 63;
  int gr = blockIdx.x * 4 + w;
  int h = gr / 400, t = gr % 400, hh = h & 7, b = h >> 3;
  int c0 = l * 4;
  const float* zp = &z2qs[((size_t)h * 400 + t) * 256];
  float z[4]; float s1 = 0.f, s2 = 0.f;
#pragma unroll
  for (int i = 0; i < 4; i++){ z[i] = zp[c0 + i]; s1 += z[i]; s2 += z[i] * z[i]; }
#pragma unroll
  for (int off = 32; off >= 1; off >>= 1){ s1 += __shfl_xor(s1, off, 64); s2 += __shfl_xor(s2, off, 64); }
  float mu = s1 * (1.f / 256.f);
  float var = s2 * (1.f / 256.f) - mu * mu;
  float rstd = rsqrtf(var + 1e-6f);
  const float* qp = &qg[((size_t)h * 400 + t) * 256];
  unsigned short* op = &obf[((size_t)(b * 400 + t)) * 2048 + hh * 256];
#pragma unroll
  for (int i = 0; i < 4; i++){
    float xh = (z[i] - mu) * rstd;
    float o = qp[c0 + i] + gwg[hh * 256 + c0 + i] * xh + gbg[hh * 256 + c0 + i];
    op[c0 + i] = f2bf(o);
  }
}

// ---------------------------------------------------------------------------
// launch
// ---------------------------------------------------------------------------
#define WS_WEFF   0u
#define WS_P      31719424u
#define WS_WQKV   44109824u
#define WS_WO     69275648u
#define WS_XB     77664256u
#define WS_Q      80941056u
#define WS_K      87494656u
#define WS_V      94048256u
#define WS_PZ2    100601856u
#define WS_PQ     103223296u
#define WS_Z2QS   105844736u
#define WS_OBF    112398336u
#define WS_BSUM   115675136u
#define WS_BAR    115683328u

extern "C" void kernel_launch(void* const* d_in, const int* in_sizes, int n_in,
                              void* d_out, int out_size, void* d_ws, size_t ws_size,
                              hipStream_t stream)
{
  (void)in_sizes; (void)n_in; (void)out_size; (void)ws_size;
  const float* x  = (const float*)d_in[0];
  const float* cw[6]; const float* cb[6];
  for (int i = 0; i < 6; i++){ cw[i] = (const float*)d_in[2 + 2 * i]; cb[i] = (const float*)d_in[3 + 2 * i]; }
  const float* wq  = (const float*)d_in[14];
  const float* wk  = (const float*)d_in[15];
  const float* wv  = (const float*)d_in[16];
  const float* wo  = (const float*)d_in[17];
  const float* W1  = (const float*)d_in[18];
  const float* b1  = (const float*)d_in[19];
  const float* W2  = (const float*)d_in[20];
  const float* b2  = (const float*)d_in[21];
  const float* lnw = (const float*)d_in[22];
  const float* lnb = (const float*)d_in[23];
  float* outf = (float*)d_out;

  char* wsb = (char*)d_ws;
  unsigned short* weff = (unsigned short*)(wsb + WS_WEFF);
  unsigned short* P    = (unsigned short*)(wsb + WS_P);
  unsigned short* wqkv = (unsigned short*)(wsb + WS_WQKV);
  unsigned short* wob  = (unsigned short*)(wsb + WS_WO);
  unsigned short* xb   = (unsigned short*)(wsb + WS_XB);
  float* qb   = (float*)(wsb + WS_Q);
  float* kb   = (float*)(wsb + WS_K);
  float* vb   = (float*)(wsb + WS_V);
  float* pz2  = (float*)(wsb + WS_PZ2);
  float* pq   = (float*)(wsb + WS_PQ);
  float* z2qs = (float*)(wsb + WS_Z2QS);
  unsigned short* obf = (unsigned short*)(wsb + WS_OBF);
  float* bsum = (float*)(wsb + WS_BSUM);
  unsigned int* bar = (unsigned int*)(wsb + WS_BAR);

  hipMemsetAsync(bar, 0, 256, stream);
  hipFuncSetAttribute(reinterpret_cast<const void*>(k_ttt),
                      hipFuncAttributeMaxDynamicSharedMemorySize, TTT_LDS_BYTES);

  k_weff<<<(2048 * 7744 + 255) / 256, 256, 0, stream>>>(cw[0], cw[1], cw[2], cw[3], cw[4], cw[5], weff);
  k_im2col<<<(800 * 7744 + 255) / 256, 256, 0, stream>>>(x, P);
  k_wqkv<<<(6144 * 2048 + 255) / 256, 256, 0, stream>>>(wq, wk, wv, wqkv);
  k_f2bf_copy<<<(2048 * 2048 + 255) / 256, 256, 0, stream>>>(wo, wob, 2048 * 2048);
  k_bsum<<<8, 256, 0, stream>>>(cb[0], cb[1], cb[2], cb[3], cb[4], cb[5], bsum);

  k_gemm<0><<<dim3(16, 7), 256, 0, stream>>>(weff, P, 2048, 800, 7744,
                                             bsum, xb, nullptr, nullptr, nullptr, nullptr);
  k_gemm<1><<<dim3(48, 7), 256, 0, stream>>>(wqkv, xb, 6144, 800, 2048,
                                             nullptr, nullptr, qb, kb, vb, nullptr);
  k_ttt<<<256, 256, TTT_LDS_BYTES, stream>>>(qb, kb, vb, W1, b1, W2, b2, lnw, lnb,
                                             pz2, pq, z2qs, bar);
  k_lnout<<<1600, 256, 0, stream>>>(z2qs, qb, lnw, lnb, obf);
  k_gemm<2><<<dim3(16, 7), 256, 0, stream>>>(wob, obf, 2048, 800, 2048,
                                             nullptr, nullptr, nullptr, nullptr, nullptr, outf);
}

// Round 3
// 1472.566 us; speedup vs baseline: 2.2137x; 1.2540x over previous
//
#include <hip/hip_runtime.h>

// ---------------------------------------------------------------------------
// Branch_62989990363328: TimesBlock conv ensemble -> TTT-MLP -> out proj
// B=2 T=400 C=64 OUT=2048 NH=8 HD=256 INNER=1024 MB=10 NC=40
// R3: MALL-side reduction. Z2 partials atomicAdd into per-chunk accumulator
//     (16x less read traffic); Z2q partials atomicAdd straight into z2qs
//     (off the barrier entirely). xq prefetch overlaps barrier wait.
// ---------------------------------------------------------------------------

typedef __bf16 bf16x8 __attribute__((ext_vector_type(8)));
typedef float  f32x4  __attribute__((ext_vector_type(4)));

__device__ __forceinline__ unsigned short f2bf(float f){
  unsigned int u = __builtin_bit_cast(unsigned int, f);
  u += 0x7fffu + ((u >> 16) & 1u);
  return (unsigned short)(u >> 16);
}
__device__ __forceinline__ float bf2f(unsigned short b){
  unsigned int u = ((unsigned int)b) << 16;
  return __builtin_bit_cast(float, u);
}
__device__ __forceinline__ float gelu_f(float x){
  return 0.5f * x * (1.0f + erff(x * 0.70710678118654752f));
}
__device__ __forceinline__ float gelu_bwd_f(float x){
  return 0.5f * (1.0f + erff(x * 0.70710678118654752f))
       + x * __expf(-0.5f * x * x) * 0.3989422804014327f;
}

// agent-scope relaxed atomic helpers (MALL-coherent, bypass L1/L2)
__device__ __forceinline__ float2 aload2(const float* p){
  unsigned long long v = __hip_atomic_load((const unsigned long long*)p,
                                           __ATOMIC_RELAXED, __HIP_MEMORY_SCOPE_AGENT);
  union { unsigned long long u; float2 f; } cv; cv.u = v; return cv.f;
}
__device__ __forceinline__ void aadd(float* p, float v){
  __hip_atomic_fetch_add(p, v, __ATOMIC_RELAXED, __HIP_MEMORY_SCOPE_AGENT);
}

union Frag { bf16x8 v; unsigned short u[8]; };

// ---------------------------------------------------------------------------
// Prep kernels
// ---------------------------------------------------------------------------

__global__ __launch_bounds__(256) void k_weff(
    const float* __restrict__ w0, const float* __restrict__ w1,
    const float* __restrict__ w2, const float* __restrict__ w3,
    const float* __restrict__ w4, const float* __restrict__ w5,
    unsigned short* __restrict__ weff)
{
  int idx = blockIdx.x * 256 + threadIdx.x;
  if (idx >= 2048 * 7744) return;
  int o = idx / 7744, k = idx % 7744;
  int c = k / 121, dd = k % 121, di = dd / 11, dj = dd % 11;
  const float* ws6[6] = {w0, w1, w2, w3, w4, w5};
  float s = 0.f;
#pragma unroll
  for (int i = 0; i < 6; i++){
    int kk = 2 * i + 1;
    int a = di - 5 + i, b = dj - 5 + i;
    if (a >= 0 && a < kk && b >= 0 && b < kk)
      s += ws6[i][(((size_t)o * 64 + c) * kk + a) * kk + b];
  }
  weff[idx] = f2bf(s);
}

__global__ __launch_bounds__(256) void k_im2col(
    const float* __restrict__ x, unsigned short* __restrict__ P)
{
  int idx = blockIdx.x * 256 + threadIdx.x;
  if (idx >= 800 * 7744) return;
  int n = idx / 7744, k = idx % 7744;
  int c = k / 121, dd = k % 121, di = dd / 11, dj = dd % 11;
  int b = n / 400, pos = n % 400, i = pos / 20, j = pos % 20;
  int ii = i + di - 5, jj = j + dj - 5;
  float v = 0.f;
  if (ii >= 0 && ii < 20 && jj >= 0 && jj < 20)
    v = x[((size_t)b * 400 + ii * 20 + jj) * 64 + c];
  P[idx] = f2bf(v);
}

__global__ __launch_bounds__(256) void k_wqkv(
    const float* __restrict__ wq, const float* __restrict__ wk,
    const float* __restrict__ wv, unsigned short* __restrict__ dst)
{
  int idx = blockIdx.x * 256 + threadIdx.x;
  if (idx >= 6144 * 2048) return;
  int m = idx >> 11, kk = idx & 2047;
  const float* src = (m < 2048) ? wq : ((m < 4096) ? wk : wv);
  dst[idx] = f2bf(src[(size_t)(m & 2047) * 2048 + kk]);
}

__global__ __launch_bounds__(256) void k_f2bf_copy(
    const float* __restrict__ src, unsigned short* __restrict__ dst, int n)
{
  int idx = blockIdx.x * 256 + threadIdx.x;
  if (idx < n) dst[idx] = f2bf(src[idx]);
}

__global__ __launch_bounds__(256) void k_bsum(
    const float* __restrict__ b0, const float* __restrict__ b1,
    const float* __restrict__ b2, const float* __restrict__ b3,
    const float* __restrict__ b4, const float* __restrict__ b5,
    float* __restrict__ bsum)
{
  int idx = blockIdx.x * 256 + threadIdx.x;
  if (idx < 2048)
    bsum[idx] = b0[idx] + b1[idx] + b2[idx] + b3[idx] + b4[idx] + b5[idx];
}

// ---------------------------------------------------------------------------
// Generic bf16 MFMA GEMM: C[M][N] = A[M][K] * B[N][K]^T
// ---------------------------------------------------------------------------
template<int MODE>
__global__ __launch_bounds__(256, 1) void k_gemm(
    const unsigned short* __restrict__ A, const unsigned short* __restrict__ B,
    int M, int N, int K,
    const float* __restrict__ bsum, unsigned short* __restrict__ out_bf,
    float* __restrict__ qb, float* __restrict__ kb, float* __restrict__ vb,
    float* __restrict__ outf)
{
  __shared__ unsigned short As[128 * 32];
  __shared__ unsigned short Bs[128 * 32];
  int tid = threadIdx.x, w = tid >> 6, l = tid & 63, qd = l >> 4, lm = l & 15;
  int m0 = blockIdx.x * 128, n0 = blockIdx.y * 128;

  f32x4 acc[4][4];
#pragma unroll
  for (int i = 0; i < 4; i++)
#pragma unroll
    for (int j = 0; j < 4; j++){ acc[i][j][0]=0.f; acc[i][j][1]=0.f; acc[i][j][2]=0.f; acc[i][j][3]=0.f; }

  int nk = K >> 5;
  for (int kt = 0; kt < nk; kt++){
    int k0 = kt << 5;
#pragma unroll
    for (int i = 0; i < 2; i++){
      int cidx = tid + i * 256;
      int row = cidx >> 2, kc = (cidx & 3) << 3;
      *(uint4*)&As[row * 32 + kc] = *(const uint4*)&A[(size_t)(m0 + row) * K + k0 + kc];
      int br = n0 + row; if (br >= N) br = N - 1;
      *(uint4*)&Bs[row * 32 + kc] = *(const uint4*)&B[(size_t)br * K + k0 + kc];
    }
    __syncthreads();
    bf16x8 af[4], bfv[4];
#pragma unroll
    for (int i = 0; i < 4; i++)
      af[i] = *(const bf16x8*)&As[((w >> 1) * 64 + i * 16 + lm) * 32 + qd * 8];
#pragma unroll
    for (int j = 0; j < 4; j++)
      bfv[j] = *(const bf16x8*)&Bs[((w & 1) * 64 + j * 16 + lm) * 32 + qd * 8];
#pragma unroll
    for (int i = 0; i < 4; i++)
#pragma unroll
      for (int j = 0; j < 4; j++)
        acc[i][j] = __builtin_amdgcn_mfma_f32_16x16x32_bf16(af[i], bfv[j], acc[i][j], 0, 0, 0);
    __syncthreads();
  }

#pragma unroll
  for (int i = 0; i < 4; i++){
    int mBase = m0 + (w >> 1) * 64 + i * 16 + qd * 4;
#pragma unroll
    for (int j = 0; j < 4; j++){
      int n = n0 + (w & 1) * 64 + j * 16 + lm;
      if (n < N){
#pragma unroll
        for (int rr = 0; rr < 4; rr++){
          float val = acc[i][j][rr];
          int mm = mBase + rr;
          if (MODE == 0){
            float t = (val + bsum[mm]) * (1.0f / 6.0f);
            float sv = t / (1.0f + __expf(-t));
            out_bf[(size_t)n * 2048 + mm] = f2bf(sv);
          } else if (MODE == 1){
            int proj = mm >> 11, o = mm & 2047, hh = o >> 8, d = o & 255;
            int bh = (n / 400) * 8 + hh, tt = n % 400;
            float* dst = (proj == 0) ? qb : ((proj == 1) ? kb : vb);
            dst[((size_t)bh * 400 + tt) * 256 + d] = val;
          } else {
            outf[(size_t)n * 2048 + mm] = val;
          }
        }
      }
    }
  }
}

// ---------------------------------------------------------------------------
// TTT persistent kernel. 256 WGs: 16 heads x 16 INNER-slices (64 wide).
// Z2 reduced via MALL atomicAdd into per-chunk accumulator; one barrier/chunk.
// ---------------------------------------------------------------------------
#define O_W1BT 0
#define O_W2K  16896
#define O_W2N  33792
#define O_XKQ  52224
#define O_TGT  56448
#define O_A1   59008
#define O_A1T  60160
#define O_GZ2  62720
#define O_ZPAD 66944
#define O_GZ1  71168
#define O_XQ2  73728      // [16][264] xq bf16 (rows 10..15 zero)
#define US_TOTAL 77952
#define O_F32  77952
#define TTT_LDS_BYTES (77952 * 2 + 832 * 4)   // 159232 <= 163840

#define ETA 0.01f

__global__ __launch_bounds__(256, 1) void k_ttt(
    const float* __restrict__ qg, const float* __restrict__ kg, const float* __restrict__ vg,
    const float* __restrict__ W1g, const float* __restrict__ b1g,
    const float* __restrict__ W2g, const float* __restrict__ b2g,
    const float* __restrict__ gwg, const float* __restrict__ gbg,
    float* __restrict__ z2acc, float* __restrict__ z2qs,
    unsigned int* __restrict__ bar)
{
  extern __shared__ unsigned short lds[];
  float* ldsf = (float*)&lds[O_F32];

  int tid = threadIdx.x, w = tid >> 6, l = tid & 63, qd = l >> 4, lm = l & 15;
  int bid = blockIdx.x;
  int jj = bid >> 3, xx = bid & 7;
  int h  = xx + 8 * (jj >> 4);   // bh = b*8 + head  (0..15)
  int sl = jj & 15;              // INNER slice (0..15)
  int hh = h & 7;

  for (int i = tid; i < US_TOTAL; i += 256) lds[i] = 0;
  for (int i = tid; i < 832; i += 256) ldsf[i] = 0.f;
  __syncthreads();

  float w1r[4][4][4];
#pragma unroll
  for (int a = 0; a < 4; a++)
#pragma unroll
    for (int nt = 0; nt < 4; nt++)
#pragma unroll
      for (int rr = 0; rr < 4; rr++)
        w1r[a][nt][rr] = W1g[((size_t)hh * 256 + (4 * w + a) * 16 + qd * 4 + rr) * 1024
                             + sl * 64 + nt * 16 + lm];
  float w2r[16][4];
#pragma unroll
  for (int nt = 0; nt < 16; nt++)
#pragma unroll
    for (int rr = 0; rr < 4; rr++)
      w2r[nt][rr] = W2g[((size_t)hh * 1024 + sl * 64 + w * 16 + qd * 4 + rr) * 256
                        + nt * 16 + lm];
  if (tid < 64)  ldsf[tid] = b1g[hh * 1024 + sl * 64 + tid];
  if (tid < 256){
    ldsf[64 + tid]  = b2g[hh * 256 + tid];
    ldsf[320 + tid] = gwg[hh * 256 + tid];
    ldsf[576 + tid] = gbg[hh * 256 + tid];
  }

#define WRITE_W1BF() do { \
  _Pragma("unroll") for (int a = 0; a < 4; a++){ \
    int m0i = (4 * w + a) * 16 + qd * 4; \
    _Pragma("unroll") for (int nt = 0; nt < 4; nt++){ \
      int n = nt * 16 + lm; \
      unsigned int p0 = f2bf(w1r[a][nt][0]) | ((unsigned int)f2bf(w1r[a][nt][1]) << 16); \
      unsigned int p1 = f2bf(w1r[a][nt][2]) | ((unsigned int)f2bf(w1r[a][nt][3]) << 16); \
      *(unsigned int*)&lds[O_W1BT + n * 264 + m0i]     = p0; \
      *(unsigned int*)&lds[O_W1BT + n * 264 + m0i + 2] = p1; \
    } } } while(0)

#define WRITE_W2BF() do { \
  int mB = w * 16 + qd * 4; \
  _Pragma("unroll") for (int nt = 0; nt < 16; nt++){ \
    int n = nt * 16 + lm; \
    _Pragma("unroll") for (int rr = 0; rr < 4; rr++) \
      lds[O_W2K + (mB + rr) * 264 + n] = f2bf(w2r[nt][rr]); \
    unsigned int p0 = f2bf(w2r[nt][0]) | ((unsigned int)f2bf(w2r[nt][1]) << 16); \
    unsigned int p1 = f2bf(w2r[nt][2]) | ((unsigned int)f2bf(w2r[nt][3]) << 16); \
    *(unsigned int*)&lds[O_W2N + n * 72 + mB]     = p0; \
    *(unsigned int*)&lds[O_W2N + n * 72 + mB + 2] = p1; \
  } } while(0)

  WRITE_W1BF();
  WRITE_W2BF();
  __syncthreads();

  const size_t hb = (size_t)h * 400 * 256;

  for (int nch = 0; nch < 40; nch++){
    const size_t chunkBase = (size_t)(h * 40 + nch) * 10 * 256;

    // 1. load xk chunk + tgt = xv - xk
    {
      const float* kp = kg + hb + (size_t)nch * 10 * 256;
      const float* vp = vg + hb + (size_t)nch * 10 * 256;
#pragma unroll
      for (int r2 = 0; r2 < 10; r2++){
        float kv = kp[r2 * 256 + tid];
        float vv = vp[r2 * 256 + tid];
        lds[O_XKQ + r2 * 264 + tid] = f2bf(kv);
        lds[O_TGT + r2 * 256 + tid] = f2bf(vv - kv);
      }
    }
    __syncthreads();

    // 2. Z1 slice = xk @ W1s
    f32x4 z1a; z1a[0]=0.f; z1a[1]=0.f; z1a[2]=0.f; z1a[3]=0.f;
#pragma unroll
    for (int ks = 0; ks < 8; ks++){
      bf16x8 av = *(const bf16x8*)&lds[O_XKQ + lm * 264 + ks * 32 + qd * 8];
      bf16x8 bv = *(const bf16x8*)&lds[O_W1BT + (w * 16 + lm) * 264 + ks * 32 + qd * 8];
      z1a = __builtin_amdgcn_mfma_f32_16x16x32_bf16(av, bv, z1a, 0, 0, 0);
    }
    float z1v[4];
    {
      float b1n = ldsf[w * 16 + lm];
#pragma unroll
      for (int rr = 0; rr < 4; rr++){
        z1v[rr] = z1a[rr] + b1n;
        int mr = qd * 4 + rr;
        if (mr < 10){
          float a1 = gelu_f(z1v[rr]);
          unsigned short ab = f2bf(a1);
          lds[O_A1 + mr * 72 + w * 16 + lm] = ab;
          lds[O_A1T + (w * 16 + lm) * 40 + mr] = ab;
        }
      }
    }
    __syncthreads();

    // 4. Z2 partial = A1s @ W2s -> atomicAdd into per-chunk accumulator
#pragma unroll
    for (int nt4 = 0; nt4 < 4; nt4++){
      int nt = 4 * w + nt4;
      f32x4 p; p[0]=0.f; p[1]=0.f; p[2]=0.f; p[3]=0.f;
#pragma unroll
      for (int ks = 0; ks < 2; ks++){
        bf16x8 av = *(const bf16x8*)&lds[O_A1 + lm * 72 + ks * 32 + qd * 8];
        bf16x8 bv = *(const bf16x8*)&lds[O_W2N + (nt * 16 + lm) * 72 + ks * 32 + qd * 8];
        p = __builtin_amdgcn_mfma_f32_16x16x32_bf16(av, bv, p, 0, 0, 0);
      }
#pragma unroll
      for (int rr = 0; rr < 4; rr++){
        int mr = qd * 4 + rr;
        if (mr < 10)
          aadd(&z2acc[chunkBase + (size_t)mr * 256 + nt * 16 + lm], p[rr]);
      }
    }

    // 4b. prefetch xq into XQ2 (overlaps barrier wait; XKQ keeps xk)
    {
      const float* qp = qg + hb + (size_t)nch * 10 * 256;
#pragma unroll
      for (int r2 = 0; r2 < 10; r2++)
        lds[O_XQ2 + r2 * 264 + tid] = f2bf(qp[r2 * 256 + tid]);
    }

    // 5. per-head barrier (syncthreads drains vmcnt(0) per wave = release)
    __syncthreads();
    if (tid == 0){
      __hip_atomic_fetch_add(bar + h, 1u, __ATOMIC_RELAXED, __HIP_MEMORY_SCOPE_AGENT);
      unsigned int target = 16u * (unsigned int)(nch + 1);
      unsigned int spins = 0;
      while (__hip_atomic_load(bar + h, __ATOMIC_RELAXED, __HIP_MEMORY_SCOPE_AGENT) < target
             && spins < 8000000u){ spins++; __builtin_amdgcn_s_sleep(1); }
    }
    __syncthreads();

    // 7. gZ2 (fused LN-L2 backward) from reduced Z2, redundantly per WG
    for (int r2 = w; r2 < 10; r2 += 4){
      int c0 = l * 4;
      const float* bp = &z2acc[chunkBase + (size_t)r2 * 256 + c0];
      float2 u01 = aload2(bp);
      float2 u23 = aload2(bp + 2);
      float zz[4] = {u01.x, u01.y, u23.x, u23.y};
      float s1 = 0.f, s2 = 0.f;
#pragma unroll
      for (int i = 0; i < 4; i++){ zz[i] += ldsf[64 + c0 + i]; s1 += zz[i]; s2 += zz[i] * zz[i]; }
#pragma unroll
      for (int off = 32; off >= 1; off >>= 1){ s1 += __shfl_xor(s1, off, 64); s2 += __shfl_xor(s2, off, 64); }
      float mu = s1 * (1.f / 256.f);
      float var = s2 * (1.f / 256.f) - mu * mu;
      float rstd = rsqrtf(var + 1e-6f);
      float xh[4], gx[4];
      float t1 = 0.f, t2 = 0.f;
#pragma unroll
      for (int i = 0; i < 4; i++){
        xh[i] = (zz[i] - mu) * rstd;
        float gwv = ldsf[320 + c0 + i], gbv = ldsf[576 + c0 + i];
        float tg = bf2f(lds[O_TGT + r2 * 256 + c0 + i]);
        float go = gwv * xh[i] + gbv - tg;
        gx[i] = go * gwv;
        t1 += gx[i]; t2 += gx[i] * xh[i];
      }
#pragma unroll
      for (int off = 32; off >= 1; off >>= 1){ t1 += __shfl_xor(t1, off, 64); t2 += __shfl_xor(t2, off, 64); }
      float m1 = t1 * (1.f / 256.f), m2 = t2 * (1.f / 256.f);
      float g0 = (gx[0] - m1 - xh[0] * m2) * rstd;
      float g1 = (gx[1] - m1 - xh[1] * m2) * rstd;
      float g2 = (gx[2] - m1 - xh[2] * m2) * rstd;
      float g3 = (gx[3] - m1 - xh[3] * m2) * rstd;
      unsigned int p0 = f2bf(g0) | ((unsigned int)f2bf(g1) << 16);
      unsigned int p1 = f2bf(g2) | ((unsigned int)f2bf(g3) << 16);
      *(unsigned int*)&lds[O_GZ2 + r2 * 264 + c0]     = p0;
      *(unsigned int*)&lds[O_GZ2 + r2 * 264 + c0 + 2] = p1;
    }
    __syncthreads();

    // 9a. b2 -= eta * sum_rows(gZ2)
    {
      float sum = 0.f;
#pragma unroll
      for (int r2 = 0; r2 < 10; r2++) sum += bf2f(lds[O_GZ2 + r2 * 264 + tid]);
      ldsf[64 + tid] -= ETA * sum;
    }
    // 9b. gZ1 slice = (gZ2 @ W2s^T) * gelu'(Z1)
    {
      f32x4 g1a; g1a[0]=0.f; g1a[1]=0.f; g1a[2]=0.f; g1a[3]=0.f;
#pragma unroll
      for (int ks = 0; ks < 8; ks++){
        bf16x8 av = *(const bf16x8*)&lds[O_GZ2 + lm * 264 + ks * 32 + qd * 8];
        bf16x8 bv = *(const bf16x8*)&lds[O_W2K + (w * 16 + lm) * 264 + ks * 32 + qd * 8];
        g1a = __builtin_amdgcn_mfma_f32_16x16x32_bf16(av, bv, g1a, 0, 0, 0);
      }
#pragma unroll
      for (int rr = 0; rr < 4; rr++){
        int mr = qd * 4 + rr;
        if (mr < 10){
          float gz1 = g1a[rr] * gelu_bwd_f(z1v[rr]);
          lds[O_GZ1 + (w * 16 + lm) * 40 + mr] = f2bf(gz1);
        }
      }
    }
    __syncthreads();

    // 11a. b1 -= eta * colsum(gZ1)
    if (tid < 64){
      float sum = 0.f;
#pragma unroll
      for (int kx = 0; kx < 10; kx++) sum += bf2f(lds[O_GZ1 + tid * 40 + kx]);
      ldsf[tid] -= ETA * sum;
    }
    // 11b. W1 update: dW1 = xk^T @ gZ1
#pragma unroll
    for (int a = 0; a < 4; a++){
      int mt = 4 * w + a;
      Frag afr;
#pragma unroll
      for (int j8 = 0; j8 < 8; j8++)
        afr.u[j8] = lds[O_XKQ + (qd * 8 + j8) * 264 + mt * 16 + lm];
#pragma unroll
      for (int nt = 0; nt < 4; nt++){
        bf16x8 bv = *(const bf16x8*)&lds[O_GZ1 + (nt * 16 + lm) * 40 + qd * 8];
        f32x4 d; d[0]=0.f; d[1]=0.f; d[2]=0.f; d[3]=0.f;
        d = __builtin_amdgcn_mfma_f32_16x16x32_bf16(afr.v, bv, d, 0, 0, 0);
#pragma unroll
        for (int rr = 0; rr < 4; rr++) w1r[a][nt][rr] -= ETA * d[rr];
      }
    }
    // 11c. W2 update: dW2 = A1^T @ gZ2
    {
      bf16x8 av2 = *(const bf16x8*)&lds[O_A1T + (w * 16 + lm) * 40 + qd * 8];
#pragma unroll
      for (int nt = 0; nt < 16; nt++){
        Frag bfr;
#pragma unroll
        for (int j8 = 0; j8 < 8; j8++)
          bfr.u[j8] = lds[O_GZ2 + (qd * 8 + j8) * 264 + nt * 16 + lm];
        f32x4 d; d[0]=0.f; d[1]=0.f; d[2]=0.f; d[3]=0.f;
        d = __builtin_amdgcn_mfma_f32_16x16x32_bf16(av2, bfr.v, d, 0, 0, 0);
#pragma unroll
        for (int rr = 0; rr < 4; rr++) w2r[nt][rr] -= ETA * d[rr];
      }
    }
    WRITE_W1BF();
    WRITE_W2BF();
    __syncthreads();

    // 15. Z1q = xq @ W1_new + b1_new -> A1q
    {
      f32x4 zq; zq[0]=0.f; zq[1]=0.f; zq[2]=0.f; zq[3]=0.f;
#pragma unroll
      for (int ks = 0; ks < 8; ks++){
        bf16x8 av = *(const bf16x8*)&lds[O_XQ2 + lm * 264 + ks * 32 + qd * 8];
        bf16x8 bv = *(const bf16x8*)&lds[O_W1BT + (w * 16 + lm) * 264 + ks * 32 + qd * 8];
        zq = __builtin_amdgcn_mfma_f32_16x16x32_bf16(av, bv, zq, 0, 0, 0);
      }
      float b1n = ldsf[w * 16 + lm];
#pragma unroll
      for (int rr = 0; rr < 4; rr++){
        int mr = qd * 4 + rr;
        if (mr < 10)
          lds[O_A1 + mr * 72 + w * 16 + lm] = f2bf(gelu_f(zq[rr] + b1n));
      }
    }
    __syncthreads();

    // 17. Z2q partial = A1q @ W2_new -> atomicAdd into z2qs (off-barrier)
#pragma unroll
    for (int nt4 = 0; nt4 < 4; nt4++){
      int nt = 4 * w + nt4;
      f32x4 p; p[0]=0.f; p[1]=0.f; p[2]=0.f; p[3]=0.f;
#pragma unroll
      for (int ks = 0; ks < 2; ks++){
        bf16x8 av = *(const bf16x8*)&lds[O_A1 + lm * 72 + ks * 32 + qd * 8];
        bf16x8 bv = *(const bf16x8*)&lds[O_W2N + (nt * 16 + lm) * 72 + ks * 32 + qd * 8];
        p = __builtin_amdgcn_mfma_f32_16x16x32_bf16(av, bv, p, 0, 0, 0);
      }
#pragma unroll
      for (int rr = 0; rr < 4; rr++){
        int mr = qd * 4 + rr;
        if (mr < 10)
          aadd(&z2qs[chunkBase + (size_t)mr * 256 + nt * 16 + lm], p[rr]);
      }
    }
    // slice 0 also adds current (post-update) b2 into z2qs rows
    if (sl == 0){
#pragma unroll
      for (int r2 = 0; r2 < 10; r2++)
        aadd(&z2qs[chunkBase + (size_t)r2 * 256 + tid], ldsf[64 + tid]);
    }
    __syncthreads();
  }
}

// ---------------------------------------------------------------------------
// LN forward + residual (z2qs read via MALL atomics — bypass stale L2)
// ---------------------------------------------------------------------------
__global__ __launch_bounds__(256) void k_lnout(
    const float* __restrict__ z2qs, const float* __restrict__ qg,
    const float* __restrict__ gwg, const float* __restrict__ gbg,
    unsigned short* __restrict__ obf)
{
  int w = threadIdx.x >> 6, l = threadIdx.x & 63;
  int gr = blockIdx.x * 4 + w;
  int h = gr / 400, t = gr % 400, hh = h & 7, b = h >> 3;
  int c0 = l * 4;
  const float* zp = &z2qs[((size_t)h * 400 + t) * 256];
  float2 a01 = aload2(zp + c0);
  float2 a23 = aload2(zp + c0 + 2);
  float z[4] = {a01.x, a01.y, a23.x, a23.y};
  float s1 = 0.f, s2 = 0.f;
#pragma unroll
  for (int i = 0; i < 4; i++){ s1 += z[i]; s2 += z[i] * z[i]; }
#pragma unroll
  for (int off = 32; off >= 1; off >>= 1){ s1 += __shfl_xor(s1, off, 64); s2 += __shfl_xor(s2, off, 64); }
  float mu = s1 * (1.f / 256.f);
  float var = s2 * (1.f / 256.f) - mu * mu;
  float rstd = rsqrtf(var + 1e-6f);
  const float* qp = &qg[((size_t)h * 400 + t) * 256];
  unsigned short* op = &obf[((size_t)(b * 400 + t)) * 2048 + hh * 256];
#pragma unroll
  for (int i = 0; i < 4; i++){
    float xh = (z[i] - mu) * rstd;
    float o = qp[c0 + i] + gwg[hh * 256 + c0 + i] * xh + gbg[hh * 256 + c0 + i];
    op[c0 + i] = f2bf(o);
  }
}

// ---------------------------------------------------------------------------
// launch
// ---------------------------------------------------------------------------
#define WS_WEFF   0u          // bf16 [2048][7744] (dead after gemm0; z2acc aliases here)
#define WS_P      31719424u
#define WS_WQKV   44109824u
#define WS_WO     69275648u
#define WS_XB     77664256u
#define WS_Q      80941056u
#define WS_K      87494656u
#define WS_V      94048256u
#define WS_Z2QS   105844736u  // f32 [16][40][10][256]
#define WS_OBF    112398336u
#define WS_BSUM   115675136u
#define WS_BAR    115683328u

extern "C" void kernel_launch(void* const* d_in, const int* in_sizes, int n_in,
                              void* d_out, int out_size, void* d_ws, size_t ws_size,
                              hipStream_t stream)
{
  (void)in_sizes; (void)n_in; (void)out_size; (void)ws_size;
  const float* x  = (const float*)d_in[0];
  const float* cw[6]; const float* cb[6];
  for (int i = 0; i < 6; i++){ cw[i] = (const float*)d_in[2 + 2 * i]; cb[i] = (const float*)d_in[3 + 2 * i]; }
  const float* wq  = (const float*)d_in[14];
  const float* wk  = (const float*)d_in[15];
  const float* wv  = (const float*)d_in[16];
  const float* wo  = (const float*)d_in[17];
  const float* W1  = (const float*)d_in[18];
  const float* b1  = (const float*)d_in[19];
  const float* W2  = (const float*)d_in[20];
  const float* b2  = (const float*)d_in[21];
  const float* lnw = (const float*)d_in[22];
  const float* lnb = (const float*)d_in[23];
  float* outf = (float*)d_out;

  char* wsb = (char*)d_ws;
  unsigned short* weff = (unsigned short*)(wsb + WS_WEFF);
  unsigned short* P    = (unsigned short*)(wsb + WS_P);
  unsigned short* wqkv = (unsigned short*)(wsb + WS_WQKV);
  unsigned short* wob  = (unsigned short*)(wsb + WS_WO);
  unsigned short* xb   = (unsigned short*)(wsb + WS_XB);
  float* qb   = (float*)(wsb + WS_Q);
  float* kb   = (float*)(wsb + WS_K);
  float* vb   = (float*)(wsb + WS_V);
  float* z2acc = (float*)(wsb + WS_WEFF);   // aliases weff (dead after gemm0)
  float* z2qs = (float*)(wsb + WS_Z2QS);
  unsigned short* obf = (unsigned short*)(wsb + WS_OBF);
  float* bsum = (float*)(wsb + WS_BSUM);
  unsigned int* bar = (unsigned int*)(wsb + WS_BAR);

  hipMemsetAsync(bar, 0, 256, stream);
  hipFuncSetAttribute(reinterpret_cast<const void*>(k_ttt),
                      hipFuncAttributeMaxDynamicSharedMemorySize, TTT_LDS_BYTES);

  k_weff<<<(2048 * 7744 + 255) / 256, 256, 0, stream>>>(cw[0], cw[1], cw[2], cw[3], cw[4], cw[5], weff);
  k_im2col<<<(800 * 7744 + 255) / 256, 256, 0, stream>>>(x, P);
  k_wqkv<<<(6144 * 2048 + 255) / 256, 256, 0, stream>>>(wq, wk, wv, wqkv);
  k_f2bf_copy<<<(2048 * 2048 + 255) / 256, 256, 0, stream>>>(wo, wob, 2048 * 2048);
  k_bsum<<<8, 256, 0, stream>>>(cb[0], cb[1], cb[2], cb[3], cb[4], cb[5], bsum);

  k_gemm<0><<<dim3(16, 7), 256, 0, stream>>>(weff, P, 2048, 800, 7744,
                                             bsum, xb, nullptr, nullptr, nullptr, nullptr);
  k_gemm<1><<<dim3(48, 7), 256, 0, stream>>>(wqkv, xb, 6144, 800, 2048,
                                             nullptr, nullptr, qb, kb, vb, nullptr);

  // zero the atomic accumulators (z2acc aliases weff -> after gemm0)
  hipMemsetAsync(z2acc, 0, 16 * 40 * 10 * 256 * 4, stream);
  hipMemsetAsync(z2qs, 0, 16 * 40 * 10 * 256 * 4, stream);

  k_ttt<<<256, 256, TTT_LDS_BYTES, stream>>>(qb, kb, vb, W1, b1, W2, b2, lnw, lnb,
                                             z2acc, z2qs, bar);
  k_lnout<<<1600, 256, 0, stream>>>(z2qs, qb, lnw, lnb, obf);
  k_gemm<2><<<dim3(16, 7), 256, 0, stream>>>(wob, obf, 2048, 800, 2048,
                                             nullptr, nullptr, nullptr, nullptr, nullptr, outf);
}

// Round 4
// 1435.528 us; speedup vs baseline: 2.2709x; 1.0258x over previous
//
#include <hip/hip_runtime.h>

// ---------------------------------------------------------------------------
// Branch_62989990363328: TimesBlock conv ensemble -> TTT-MLP -> out proj
// B=2 T=400 C=64 OUT=2048 NH=8 HD=256 INNER=1024 MB=10 NC=40
// R4: z2q partials -> plain bf16 stores per slice (cross-kernel reduce in
//     k_lnout); only z2acc keeps MALL fetch_add (26M ops). K-split x2 for the
//     two 112-WG GEMMs via gridDim.z + combine kernels.
// ---------------------------------------------------------------------------

typedef __bf16 bf16x8 __attribute__((ext_vector_type(8)));
typedef float  f32x4  __attribute__((ext_vector_type(4)));

__device__ __forceinline__ unsigned short f2bf(float f){
  unsigned int u = __builtin_bit_cast(unsigned int, f);
  u += 0x7fffu + ((u >> 16) & 1u);
  return (unsigned short)(u >> 16);
}
__device__ __forceinline__ float bf2f(unsigned short b){
  unsigned int u = ((unsigned int)b) << 16;
  return __builtin_bit_cast(float, u);
}
__device__ __forceinline__ float gelu_f(float x){
  return 0.5f * x * (1.0f + erff(x * 0.70710678118654752f));
}
__device__ __forceinline__ float gelu_bwd_f(float x){
  return 0.5f * (1.0f + erff(x * 0.70710678118654752f))
       + x * __expf(-0.5f * x * x) * 0.3989422804014327f;
}

// agent-scope relaxed atomic helpers (MALL-coherent, bypass L1/L2)
__device__ __forceinline__ float2 aload2(const float* p){
  unsigned long long v = __hip_atomic_load((const unsigned long long*)p,
                                           __ATOMIC_RELAXED, __HIP_MEMORY_SCOPE_AGENT);
  union { unsigned long long u; float2 f; } cv; cv.u = v; return cv.f;
}
__device__ __forceinline__ void aadd(float* p, float v){
  __hip_atomic_fetch_add(p, v, __ATOMIC_RELAXED, __HIP_MEMORY_SCOPE_AGENT);
}

union Frag { bf16x8 v; unsigned short u[8]; };

// ---------------------------------------------------------------------------
// Prep kernels
// ---------------------------------------------------------------------------

__global__ __launch_bounds__(256) void k_weff(
    const float* __restrict__ w0, const float* __restrict__ w1,
    const float* __restrict__ w2, const float* __restrict__ w3,
    const float* __restrict__ w4, const float* __restrict__ w5,
    unsigned short* __restrict__ weff)
{
  int idx = blockIdx.x * 256 + threadIdx.x;
  if (idx >= 2048 * 7744) return;
  int o = idx / 7744, k = idx % 7744;
  int c = k / 121, dd = k % 121, di = dd / 11, dj = dd % 11;
  const float* ws6[6] = {w0, w1, w2, w3, w4, w5};
  float s = 0.f;
#pragma unroll
  for (int i = 0; i < 6; i++){
    int kk = 2 * i + 1;
    int a = di - 5 + i, b = dj - 5 + i;
    if (a >= 0 && a < kk && b >= 0 && b < kk)
      s += ws6[i][(((size_t)o * 64 + c) * kk + a) * kk + b];
  }
  weff[idx] = f2bf(s);
}

__global__ __launch_bounds__(256) void k_im2col(
    const float* __restrict__ x, unsigned short* __restrict__ P)
{
  int idx = blockIdx.x * 256 + threadIdx.x;
  if (idx >= 800 * 7744) return;
  int n = idx / 7744, k = idx % 7744;
  int c = k / 121, dd = k % 121, di = dd / 11, dj = dd % 11;
  int b = n / 400, pos = n % 400, i = pos / 20, j = pos % 20;
  int ii = i + di - 5, jj = j + dj - 5;
  float v = 0.f;
  if (ii >= 0 && ii < 20 && jj >= 0 && jj < 20)
    v = x[((size_t)b * 400 + ii * 20 + jj) * 64 + c];
  P[idx] = f2bf(v);
}

__global__ __launch_bounds__(256) void k_wqkv(
    const float* __restrict__ wq, const float* __restrict__ wk,
    const float* __restrict__ wv, unsigned short* __restrict__ dst)
{
  int idx = blockIdx.x * 256 + threadIdx.x;
  if (idx >= 6144 * 2048) return;
  int m = idx >> 11, kk = idx & 2047;
  const float* src = (m < 2048) ? wq : ((m < 4096) ? wk : wv);
  dst[idx] = f2bf(src[(size_t)(m & 2047) * 2048 + kk]);
}

__global__ __launch_bounds__(256) void k_f2bf_copy(
    const float* __restrict__ src, unsigned short* __restrict__ dst, int n)
{
  int idx = blockIdx.x * 256 + threadIdx.x;
  if (idx < n) dst[idx] = f2bf(src[idx]);
}

__global__ __launch_bounds__(256) void k_bsum(
    const float* __restrict__ b0, const float* __restrict__ b1,
    const float* __restrict__ b2, const float* __restrict__ b3,
    const float* __restrict__ b4, const float* __restrict__ b5,
    float* __restrict__ bsum)
{
  int idx = blockIdx.x * 256 + threadIdx.x;
  if (idx < 2048)
    bsum[idx] = b0[idx] + b1[idx] + b2[idx] + b3[idx] + b4[idx] + b5[idx];
}

// combine kernels for K-split GEMMs (4 elems/thread, 1600 blocks)
__global__ __launch_bounds__(256) void k_comb_silu(
    const float* __restrict__ p0, const float* __restrict__ p1,
    const float* __restrict__ bsum, unsigned short* __restrict__ xb)
{
  int i4 = (blockIdx.x * 256 + threadIdx.x) * 4;
  float4 a = *(const float4*)&p0[i4];
  float4 b = *(const float4*)&p1[i4];
  int mm = i4 & 2047;
  float4 bs = *(const float4*)&bsum[mm];
  float v[4] = {a.x + b.x + bs.x, a.y + b.y + bs.y, a.z + b.z + bs.z, a.w + b.w + bs.w};
  ushort4 o;
#pragma unroll
  for (int i = 0; i < 4; i++){
    float t = v[i] * (1.0f / 6.0f);
    float sv = t / (1.0f + __expf(-t));
    ((unsigned short*)&o)[i] = f2bf(sv);
  }
  *(ushort4*)&xb[i4] = o;
}

__global__ __launch_bounds__(256) void k_comb_add(
    const float* __restrict__ p0, const float* __restrict__ p1,
    float* __restrict__ out)
{
  int i4 = (blockIdx.x * 256 + threadIdx.x) * 4;
  float4 a = *(const float4*)&p0[i4];
  float4 b = *(const float4*)&p1[i4];
  float4 o = {a.x + b.x, a.y + b.y, a.z + b.z, a.w + b.w};
  *(float4*)&out[i4] = o;
}

// ---------------------------------------------------------------------------
// Generic bf16 MFMA GEMM: C[M][N] (+)= A[M][K] * B[N][K]^T, K-split via z.
// MODE 1: qkv scatter epilogue; MODE 2: fp32 store to outf[z][n][M].
// ---------------------------------------------------------------------------
template<int MODE>
__global__ __launch_bounds__(256, 1) void k_gemm(
    const unsigned short* __restrict__ A, const unsigned short* __restrict__ B,
    int M, int N, int lda, int ldb, int kLen,
    float* __restrict__ qb, float* __restrict__ kb, float* __restrict__ vb,
    float* __restrict__ outf)
{
  __shared__ unsigned short As[128 * 32];
  __shared__ unsigned short Bs[128 * 32];
  int tid = threadIdx.x, w = tid >> 6, l = tid & 63, qd = l >> 4, lm = l & 15;
  int m0 = blockIdx.x * 128, n0 = blockIdx.y * 128;
  int kBase = blockIdx.z * kLen;

  f32x4 acc[4][4];
#pragma unroll
  for (int i = 0; i < 4; i++)
#pragma unroll
    for (int j = 0; j < 4; j++){ acc[i][j][0]=0.f; acc[i][j][1]=0.f; acc[i][j][2]=0.f; acc[i][j][3]=0.f; }

  int nk = kLen >> 5;
  for (int kt = 0; kt < nk; kt++){
    int k0 = kBase + (kt << 5);
#pragma unroll
    for (int i = 0; i < 2; i++){
      int cidx = tid + i * 256;
      int row = cidx >> 2, kc = (cidx & 3) << 3;
      *(uint4*)&As[row * 32 + kc] = *(const uint4*)&A[(size_t)(m0 + row) * lda + k0 + kc];
      int br = n0 + row; if (br >= N) br = N - 1;
      *(uint4*)&Bs[row * 32 + kc] = *(const uint4*)&B[(size_t)br * ldb + k0 + kc];
    }
    __syncthreads();
    bf16x8 af[4], bfv[4];
#pragma unroll
    for (int i = 0; i < 4; i++)
      af[i] = *(const bf16x8*)&As[((w >> 1) * 64 + i * 16 + lm) * 32 + qd * 8];
#pragma unroll
    for (int j = 0; j < 4; j++)
      bfv[j] = *(const bf16x8*)&Bs[((w & 1) * 64 + j * 16 + lm) * 32 + qd * 8];
#pragma unroll
    for (int i = 0; i < 4; i++)
#pragma unroll
      for (int j = 0; j < 4; j++)
        acc[i][j] = __builtin_amdgcn_mfma_f32_16x16x32_bf16(af[i], bfv[j], acc[i][j], 0, 0, 0);
    __syncthreads();
  }

#pragma unroll
  for (int i = 0; i < 4; i++){
    int mBase = m0 + (w >> 1) * 64 + i * 16 + qd * 4;
#pragma unroll
    for (int j = 0; j < 4; j++){
      int n = n0 + (w & 1) * 64 + j * 16 + lm;
      if (n < N){
#pragma unroll
        for (int rr = 0; rr < 4; rr++){
          float val = acc[i][j][rr];
          int mm = mBase + rr;
          if (MODE == 1){
            int proj = mm >> 11, o = mm & 2047, hh = o >> 8, d = o & 255;
            int bh = (n / 400) * 8 + hh, tt = n % 400;
            float* dst = (proj == 0) ? qb : ((proj == 1) ? kb : vb);
            dst[((size_t)bh * 400 + tt) * 256 + d] = val;
          } else {
            outf[(size_t)blockIdx.z * M * N + (size_t)n * M + mm] = val;
          }
        }
      }
    }
  }
}

// ---------------------------------------------------------------------------
// TTT persistent kernel. 256 WGs: 16 heads x 16 INNER-slices (64 wide).
// Z2 reduced via MALL atomicAdd; Z2q via plain bf16 per-slice partial stores.
// ---------------------------------------------------------------------------
#define O_W1BT 0
#define O_W2K  16896
#define O_W2N  33792
#define O_XKQ  52224
#define O_TGT  56448
#define O_A1   59008
#define O_A1T  60160
#define O_GZ2  62720
#define O_ZPAD 66944
#define O_GZ1  71168
#define O_XQ2  73728      // [16][264] xq bf16 (rows 10..15 zero)
#define US_TOTAL 77952
#define O_F32  77952
#define TTT_LDS_BYTES (77952 * 2 + 832 * 4)   // 159232 <= 163840

#define ETA 0.01f

__global__ __launch_bounds__(256, 1) void k_ttt(
    const float* __restrict__ qg, const float* __restrict__ kg, const float* __restrict__ vg,
    const float* __restrict__ W1g, const float* __restrict__ b1g,
    const float* __restrict__ W2g, const float* __restrict__ b2g,
    const float* __restrict__ gwg, const float* __restrict__ gbg,
    float* __restrict__ z2acc, unsigned short* __restrict__ zqp,
    unsigned int* __restrict__ bar)
{
  extern __shared__ unsigned short lds[];
  float* ldsf = (float*)&lds[O_F32];

  int tid = threadIdx.x, w = tid >> 6, l = tid & 63, qd = l >> 4, lm = l & 15;
  int bid = blockIdx.x;
  int jj = bid >> 3, xx = bid & 7;
  int h  = xx + 8 * (jj >> 4);   // bh = b*8 + head  (0..15)
  int sl = jj & 15;              // INNER slice (0..15)
  int hh = h & 7;

  for (int i = tid; i < US_TOTAL; i += 256) lds[i] = 0;
  for (int i = tid; i < 832; i += 256) ldsf[i] = 0.f;
  __syncthreads();

  float w1r[4][4][4];
#pragma unroll
  for (int a = 0; a < 4; a++)
#pragma unroll
    for (int nt = 0; nt < 4; nt++)
#pragma unroll
      for (int rr = 0; rr < 4; rr++)
        w1r[a][nt][rr] = W1g[((size_t)hh * 256 + (4 * w + a) * 16 + qd * 4 + rr) * 1024
                             + sl * 64 + nt * 16 + lm];
  float w2r[16][4];
#pragma unroll
  for (int nt = 0; nt < 16; nt++)
#pragma unroll
    for (int rr = 0; rr < 4; rr++)
      w2r[nt][rr] = W2g[((size_t)hh * 1024 + sl * 64 + w * 16 + qd * 4 + rr) * 256
                        + nt * 16 + lm];
  if (tid < 64)  ldsf[tid] = b1g[hh * 1024 + sl * 64 + tid];
  if (tid < 256){
    ldsf[64 + tid]  = b2g[hh * 256 + tid];
    ldsf[320 + tid] = gwg[hh * 256 + tid];
    ldsf[576 + tid] = gbg[hh * 256 + tid];
  }

#define WRITE_W1BF() do { \
  _Pragma("unroll") for (int a = 0; a < 4; a++){ \
    int m0i = (4 * w + a) * 16 + qd * 4; \
    _Pragma("unroll") for (int nt = 0; nt < 4; nt++){ \
      int n = nt * 16 + lm; \
      unsigned int p0 = f2bf(w1r[a][nt][0]) | ((unsigned int)f2bf(w1r[a][nt][1]) << 16); \
      unsigned int p1 = f2bf(w1r[a][nt][2]) | ((unsigned int)f2bf(w1r[a][nt][3]) << 16); \
      *(unsigned int*)&lds[O_W1BT + n * 264 + m0i]     = p0; \
      *(unsigned int*)&lds[O_W1BT + n * 264 + m0i + 2] = p1; \
    } } } while(0)

#define WRITE_W2BF() do { \
  int mB = w * 16 + qd * 4; \
  _Pragma("unroll") for (int nt = 0; nt < 16; nt++){ \
    int n = nt * 16 + lm; \
    _Pragma("unroll") for (int rr = 0; rr < 4; rr++) \
      lds[O_W2K + (mB + rr) * 264 + n] = f2bf(w2r[nt][rr]); \
    unsigned int p0 = f2bf(w2r[nt][0]) | ((unsigned int)f2bf(w2r[nt][1]) << 16); \
    unsigned int p1 = f2bf(w2r[nt][2]) | ((unsigned int)f2bf(w2r[nt][3]) << 16); \
    *(unsigned int*)&lds[O_W2N + n * 72 + mB]     = p0; \
    *(unsigned int*)&lds[O_W2N + n * 72 + mB + 2] = p1; \
  } } while(0)

  WRITE_W1BF();
  WRITE_W2BF();
  __syncthreads();

  const size_t hb = (size_t)h * 400 * 256;

  for (int nch = 0; nch < 40; nch++){
    const size_t chunkBase = (size_t)(h * 40 + nch) * 10 * 256;

    // 1. load xk chunk + tgt = xv - xk
    {
      const float* kp = kg + hb + (size_t)nch * 10 * 256;
      const float* vp = vg + hb + (size_t)nch * 10 * 256;
#pragma unroll
      for (int r2 = 0; r2 < 10; r2++){
        float kv = kp[r2 * 256 + tid];
        float vv = vp[r2 * 256 + tid];
        lds[O_XKQ + r2 * 264 + tid] = f2bf(kv);
        lds[O_TGT + r2 * 256 + tid] = f2bf(vv - kv);
      }
    }
    __syncthreads();

    // 2. Z1 slice = xk @ W1s
    f32x4 z1a; z1a[0]=0.f; z1a[1]=0.f; z1a[2]=0.f; z1a[3]=0.f;
#pragma unroll
    for (int ks = 0; ks < 8; ks++){
      bf16x8 av = *(const bf16x8*)&lds[O_XKQ + lm * 264 + ks * 32 + qd * 8];
      bf16x8 bv = *(const bf16x8*)&lds[O_W1BT + (w * 16 + lm) * 264 + ks * 32 + qd * 8];
      z1a = __builtin_amdgcn_mfma_f32_16x16x32_bf16(av, bv, z1a, 0, 0, 0);
    }
    float z1v[4];
    {
      float b1n = ldsf[w * 16 + lm];
#pragma unroll
      for (int rr = 0; rr < 4; rr++){
        z1v[rr] = z1a[rr] + b1n;
        int mr = qd * 4 + rr;
        if (mr < 10){
          float a1 = gelu_f(z1v[rr]);
          unsigned short ab = f2bf(a1);
          lds[O_A1 + mr * 72 + w * 16 + lm] = ab;
          lds[O_A1T + (w * 16 + lm) * 40 + mr] = ab;
        }
      }
    }
    __syncthreads();

    // 4. Z2 partial = A1s @ W2s -> atomicAdd into per-chunk accumulator
#pragma unroll
    for (int nt4 = 0; nt4 < 4; nt4++){
      int nt = 4 * w + nt4;
      f32x4 p; p[0]=0.f; p[1]=0.f; p[2]=0.f; p[3]=0.f;
#pragma unroll
      for (int ks = 0; ks < 2; ks++){
        bf16x8 av = *(const bf16x8*)&lds[O_A1 + lm * 72 + ks * 32 + qd * 8];
        bf16x8 bv = *(const bf16x8*)&lds[O_W2N + (nt * 16 + lm) * 72 + ks * 32 + qd * 8];
        p = __builtin_amdgcn_mfma_f32_16x16x32_bf16(av, bv, p, 0, 0, 0);
      }
#pragma unroll
      for (int rr = 0; rr < 4; rr++){
        int mr = qd * 4 + rr;
        if (mr < 10)
          aadd(&z2acc[chunkBase + (size_t)mr * 256 + nt * 16 + lm], p[rr]);
      }
    }

    // 4b. prefetch xq into XQ2 (overlaps barrier wait)
    {
      const float* qp = qg + hb + (size_t)nch * 10 * 256;
#pragma unroll
      for (int r2 = 0; r2 < 10; r2++)
        lds[O_XQ2 + r2 * 264 + tid] = f2bf(qp[r2 * 256 + tid]);
    }

    // 5. per-head barrier
    __syncthreads();
    if (tid == 0){
      __hip_atomic_fetch_add(bar + h, 1u, __ATOMIC_RELAXED, __HIP_MEMORY_SCOPE_AGENT);
      unsigned int target = 16u * (unsigned int)(nch + 1);
      unsigned int spins = 0;
      while (__hip_atomic_load(bar + h, __ATOMIC_RELAXED, __HIP_MEMORY_SCOPE_AGENT) < target
             && spins < 8000000u){ spins++; __builtin_amdgcn_s_sleep(1); }
    }
    __syncthreads();

    // 7. gZ2 (fused LN-L2 backward) from reduced Z2, redundantly per WG
    for (int r2 = w; r2 < 10; r2 += 4){
      int c0 = l * 4;
      const float* bp = &z2acc[chunkBase + (size_t)r2 * 256 + c0];
      float2 u01 = aload2(bp);
      float2 u23 = aload2(bp + 2);
      float zz[4] = {u01.x, u01.y, u23.x, u23.y};
      float s1 = 0.f, s2 = 0.f;
#pragma unroll
      for (int i = 0; i < 4; i++){ zz[i] += ldsf[64 + c0 + i]; s1 += zz[i]; s2 += zz[i] * zz[i]; }
#pragma unroll
      for (int off = 32; off >= 1; off >>= 1){ s1 += __shfl_xor(s1, off, 64); s2 += __shfl_xor(s2, off, 64); }
      float mu = s1 * (1.f / 256.f);
      float var = s2 * (1.f / 256.f) - mu * mu;
      float rstd = rsqrtf(var + 1e-6f);
      float xh[4], gx[4];
      float t1 = 0.f, t2 = 0.f;
#pragma unroll
      for (int i = 0; i < 4; i++){
        xh[i] = (zz[i] - mu) * rstd;
        float gwv = ldsf[320 + c0 + i], gbv = ldsf[576 + c0 + i];
        float tg = bf2f(lds[O_TGT + r2 * 256 + c0 + i]);
        float go = gwv * xh[i] + gbv - tg;
        gx[i] = go * gwv;
        t1 += gx[i]; t2 += gx[i] * xh[i];
      }
#pragma unroll
      for (int off = 32; off >= 1; off >>= 1){ t1 += __shfl_xor(t1, off, 64); t2 += __shfl_xor(t2, off, 64); }
      float m1 = t1 * (1.f / 256.f), m2 = t2 * (1.f / 256.f);
      float g0 = (gx[0] - m1 - xh[0] * m2) * rstd;
      float g1 = (gx[1] - m1 - xh[1] * m2) * rstd;
      float g2 = (gx[2] - m1 - xh[2] * m2) * rstd;
      float g3 = (gx[3] - m1 - xh[3] * m2) * rstd;
      unsigned int p0 = f2bf(g0) | ((unsigned int)f2bf(g1) << 16);
      unsigned int p1 = f2bf(g2) | ((unsigned int)f2bf(g3) << 16);
      *(unsigned int*)&lds[O_GZ2 + r2 * 264 + c0]     = p0;
      *(unsigned int*)&lds[O_GZ2 + r2 * 264 + c0 + 2] = p1;
    }
    __syncthreads();

    // 9a. b2 -= eta * sum_rows(gZ2)
    {
      float sum = 0.f;
#pragma unroll
      for (int r2 = 0; r2 < 10; r2++) sum += bf2f(lds[O_GZ2 + r2 * 264 + tid]);
      ldsf[64 + tid] -= ETA * sum;
    }
    // 9b. gZ1 slice = (gZ2 @ W2s^T) * gelu'(Z1)
    {
      f32x4 g1a; g1a[0]=0.f; g1a[1]=0.f; g1a[2]=0.f; g1a[3]=0.f;
#pragma unroll
      for (int ks = 0; ks < 8; ks++){
        bf16x8 av = *(const bf16x8*)&lds[O_GZ2 + lm * 264 + ks * 32 + qd * 8];
        bf16x8 bv = *(const bf16x8*)&lds[O_W2K + (w * 16 + lm) * 264 + ks * 32 + qd * 8];
        g1a = __builtin_amdgcn_mfma_f32_16x16x32_bf16(av, bv, g1a, 0, 0, 0);
      }
#pragma unroll
      for (int rr = 0; rr < 4; rr++){
        int mr = qd * 4 + rr;
        if (mr < 10){
          float gz1 = g1a[rr] * gelu_bwd_f(z1v[rr]);
          lds[O_GZ1 + (w * 16 + lm) * 40 + mr] = f2bf(gz1);
        }
      }
    }
    __syncthreads();

    // 11a. b1 -= eta * colsum(gZ1)
    if (tid < 64){
      float sum = 0.f;
#pragma unroll
      for (int kx = 0; kx < 10; kx++) sum += bf2f(lds[O_GZ1 + tid * 40 + kx]);
      ldsf[tid] -= ETA * sum;
    }
    // 11b. W1 update: dW1 = xk^T @ gZ1
#pragma unroll
    for (int a = 0; a < 4; a++){
      int mt = 4 * w + a;
      Frag afr;
#pragma unroll
      for (int j8 = 0; j8 < 8; j8++)
        afr.u[j8] = lds[O_XKQ + (qd * 8 + j8) * 264 + mt * 16 + lm];
#pragma unroll
      for (int nt = 0; nt < 4; nt++){
        bf16x8 bv = *(const bf16x8*)&lds[O_GZ1 + (nt * 16 + lm) * 40 + qd * 8];
        f32x4 d; d[0]=0.f; d[1]=0.f; d[2]=0.f; d[3]=0.f;
        d = __builtin_amdgcn_mfma_f32_16x16x32_bf16(afr.v, bv, d, 0, 0, 0);
#pragma unroll
        for (int rr = 0; rr < 4; rr++) w1r[a][nt][rr] -= ETA * d[rr];
      }
    }
    // 11c. W2 update: dW2 = A1^T @ gZ2
    {
      bf16x8 av2 = *(const bf16x8*)&lds[O_A1T + (w * 16 + lm) * 40 + qd * 8];
#pragma unroll
      for (int nt = 0; nt < 16; nt++){
        Frag bfr;
#pragma unroll
        for (int j8 = 0; j8 < 8; j8++)
          bfr.u[j8] = lds[O_GZ2 + (qd * 8 + j8) * 264 + nt * 16 + lm];
        f32x4 d; d[0]=0.f; d[1]=0.f; d[2]=0.f; d[3]=0.f;
        d = __builtin_amdgcn_mfma_f32_16x16x32_bf16(av2, bfr.v, d, 0, 0, 0);
#pragma unroll
        for (int rr = 0; rr < 4; rr++) w2r[nt][rr] -= ETA * d[rr];
      }
    }
    WRITE_W1BF();
    WRITE_W2BF();
    __syncthreads();

    // 15. Z1q = xq @ W1_new + b1_new -> A1q
    {
      f32x4 zq; zq[0]=0.f; zq[1]=0.f; zq[2]=0.f; zq[3]=0.f;
#pragma unroll
      for (int ks = 0; ks < 8; ks++){
        bf16x8 av = *(const bf16x8*)&lds[O_XQ2 + lm * 264 + ks * 32 + qd * 8];
        bf16x8 bv = *(const bf16x8*)&lds[O_W1BT + (w * 16 + lm) * 264 + ks * 32 + qd * 8];
        zq = __builtin_amdgcn_mfma_f32_16x16x32_bf16(av, bv, zq, 0, 0, 0);
      }
      float b1n = ldsf[w * 16 + lm];
#pragma unroll
      for (int rr = 0; rr < 4; rr++){
        int mr = qd * 4 + rr;
        if (mr < 10)
          lds[O_A1 + mr * 72 + w * 16 + lm] = f2bf(gelu_f(zq[rr] + b1n));
      }
    }
    __syncthreads();

    // 17. Z2q partial = A1q @ W2_new -> plain bf16 stores to own slice buffer
    //     (consumed by k_lnout after kernel end; sl==0 folds post-update b2)
    {
      unsigned short* zq_out = zqp + ((size_t)(h * 16 + sl) * 40 + nch) * 2560;
#pragma unroll
      for (int nt4 = 0; nt4 < 4; nt4++){
        int nt = 4 * w + nt4;
        f32x4 p; p[0]=0.f; p[1]=0.f; p[2]=0.f; p[3]=0.f;
#pragma unroll
        for (int ks = 0; ks < 2; ks++){
          bf16x8 av = *(const bf16x8*)&lds[O_A1 + lm * 72 + ks * 32 + qd * 8];
          bf16x8 bv = *(const bf16x8*)&lds[O_W2N + (nt * 16 + lm) * 72 + ks * 32 + qd * 8];
          p = __builtin_amdgcn_mfma_f32_16x16x32_bf16(av, bv, p, 0, 0, 0);
        }
        float bb = (sl == 0) ? ldsf[64 + nt * 16 + lm] : 0.f;
#pragma unroll
        for (int rr = 0; rr < 4; rr++){
          int mr = qd * 4 + rr;
          if (mr < 10)
            zq_out[mr * 256 + nt * 16 + lm] = f2bf(p[rr] + bb);
        }
      }
    }
    __syncthreads();
  }
}

// ---------------------------------------------------------------------------
// LN forward + residual; sums 16 bf16 slice partials of Z2q in fp32.
// ---------------------------------------------------------------------------
__global__ __launch_bounds__(256) void k_lnout(
    const unsigned short* __restrict__ zqp, const float* __restrict__ qg,
    const float* __restrict__ gwg, const float* __restrict__ gbg,
    unsigned short* __restrict__ obf)
{
  int w = threadIdx.x >> 6, l = threadIdx.x & 63;
  int gr = blockIdx.x * 4 + w;
  int h = gr / 400, t = gr % 400, hh = h & 7, b = h >> 3;
  int nch = t / 10, mr = t % 10;
  int c0 = l * 4;
  float z[4] = {0.f, 0.f, 0.f, 0.f};
#pragma unroll
  for (int sl = 0; sl < 16; sl++){
    const unsigned short* zp = zqp + (((size_t)(h * 16 + sl) * 40 + nch) * 10 + mr) * 256 + c0;
    ushort4 u = *(const ushort4*)zp;
    z[0] += bf2f(u.x); z[1] += bf2f(u.y); z[2] += bf2f(u.z); z[3] += bf2f(u.w);
  }
  float s1 = 0.f, s2 = 0.f;
#pragma unroll
  for (int i = 0; i < 4; i++){ s1 += z[i]; s2 += z[i] * z[i]; }
#pragma unroll
  for (int off = 32; off >= 1; off >>= 1){ s1 += __shfl_xor(s1, off, 64); s2 += __shfl_xor(s2, off, 64); }
  float mu = s1 * (1.f / 256.f);
  float var = s2 * (1.f / 256.f) - mu * mu;
  float rstd = rsqrtf(var + 1e-6f);
  const float* qp = &qg[((size_t)h * 400 + t) * 256];
  unsigned short* op = &obf[((size_t)(b * 400 + t)) * 2048 + hh * 256];
#pragma unroll
  for (int i = 0; i < 4; i++){
    float xh = (z[i] - mu) * rstd;
    float o = qp[c0 + i] + gwg[hh * 256 + c0 + i] * xh + gbg[hh * 256 + c0 + i];
    op[c0 + i] = f2bf(o);
  }
}

// ---------------------------------------------------------------------------
// launch — workspace map (bytes), total 95.5 MB
//   0         weff bf16 [2048][7744]  (dead after gemm0)   | zqp bf16 52,428,800 (from k_ttt)
//   31719424  P bf16 [800][7744]      (dead after gemm0)
//   44109824  wqkv bf16 [6144][2048]  (dead after gemm1)
//     52428800  wob bf16 [2048][2048] (written after gemm1, read by gemm2)
//     62722048  z2acc f32 6,553,600   (memset+used after gemm1)
//   69275648  xb bf16 [800][2048]
//   72552448  qb f32 [16][400][256]   | gemm0 partials (2x6.55MB, before gemm1)
//   79106048  kb                      | gemm2 partials (2x6.55MB, after lnout)
//   85659648  vb
//   92213248  obf bf16 [800][2048]
//   95490048  bsum f32[2048]
//   95498240  bar u32[16]
// ---------------------------------------------------------------------------
#define WS_WEFF   0u
#define WS_P      31719424u
#define WS_WQKV   44109824u
#define WS_WOB    52428800u
#define WS_Z2ACC  62722048u
#define WS_XB     69275648u
#define WS_Q      72552448u
#define WS_K      79106048u
#define WS_V      85659648u
#define WS_OBF    92213248u
#define WS_BSUM   95490048u
#define WS_BAR    95498240u

extern "C" void kernel_launch(void* const* d_in, const int* in_sizes, int n_in,
                              void* d_out, int out_size, void* d_ws, size_t ws_size,
                              hipStream_t stream)
{
  (void)in_sizes; (void)n_in; (void)out_size; (void)ws_size;
  const float* x  = (const float*)d_in[0];
  const float* cw[6]; const float* cb[6];
  for (int i = 0; i < 6; i++){ cw[i] = (const float*)d_in[2 + 2 * i]; cb[i] = (const float*)d_in[3 + 2 * i]; }
  const float* wq  = (const float*)d_in[14];
  const float* wk  = (const float*)d_in[15];
  const float* wv  = (const float*)d_in[16];
  const float* wo  = (const float*)d_in[17];
  const float* W1  = (const float*)d_in[18];
  const float* b1  = (const float*)d_in[19];
  const float* W2  = (const float*)d_in[20];
  const float* b2  = (const float*)d_in[21];
  const float* lnw = (const float*)d_in[22];
  const float* lnb = (const float*)d_in[23];
  float* outf = (float*)d_out;

  char* wsb = (char*)d_ws;
  unsigned short* weff = (unsigned short*)(wsb + WS_WEFF);
  unsigned short* P    = (unsigned short*)(wsb + WS_P);
  unsigned short* wqkv = (unsigned short*)(wsb + WS_WQKV);
  unsigned short* wob  = (unsigned short*)(wsb + WS_WOB);
  unsigned short* xb   = (unsigned short*)(wsb + WS_XB);
  float* qb   = (float*)(wsb + WS_Q);
  float* kb   = (float*)(wsb + WS_K);
  float* vb   = (float*)(wsb + WS_V);
  float* z2acc = (float*)(wsb + WS_Z2ACC);
  unsigned short* zqp = (unsigned short*)(wsb + WS_WEFF);   // 52.4 MB alias
  unsigned short* obf = (unsigned short*)(wsb + WS_OBF);
  float* bsum = (float*)(wsb + WS_BSUM);
  unsigned int* bar = (unsigned int*)(wsb + WS_BAR);
  float* g0part = (float*)(wsb + WS_Q);     // 13.1 MB, alias qb+kb (pre-gemm1)
  float* g2part = (float*)(wsb + WS_K);     // 13.1 MB, alias kb+vb (post-lnout)

  hipMemsetAsync(bar, 0, 256, stream);
  hipFuncSetAttribute(reinterpret_cast<const void*>(k_ttt),
                      hipFuncAttributeMaxDynamicSharedMemorySize, TTT_LDS_BYTES);

  k_weff<<<(2048 * 7744 + 255) / 256, 256, 0, stream>>>(cw[0], cw[1], cw[2], cw[3], cw[4], cw[5], weff);
  k_im2col<<<(800 * 7744 + 255) / 256, 256, 0, stream>>>(x, P);
  k_wqkv<<<(6144 * 2048 + 255) / 256, 256, 0, stream>>>(wq, wk, wv, wqkv);
  k_bsum<<<8, 256, 0, stream>>>(cb[0], cb[1], cb[2], cb[3], cb[4], cb[5], bsum);

  // conv-as-GEMM, K-split x2 (3872 each) -> fp32 partials -> silu combine
  k_gemm<2><<<dim3(16, 7, 2), 256, 0, stream>>>(weff, P, 2048, 800, 7744, 7744, 3872,
                                                nullptr, nullptr, nullptr, g0part);
  k_comb_silu<<<1600, 256, 0, stream>>>(g0part, g0part + 1638400, bsum, xb);

  // QKV projection
  k_gemm<1><<<dim3(48, 7, 1), 256, 0, stream>>>(wqkv, xb, 6144, 800, 2048, 2048, 2048,
                                                qb, kb, vb, nullptr);

  // wob (aliases dead wqkv region) + z2acc zero — both after gemm1
  k_f2bf_copy<<<(2048 * 2048 + 255) / 256, 256, 0, stream>>>(wo, wob, 2048 * 2048);
  hipMemsetAsync(z2acc, 0, 16 * 40 * 10 * 256 * 4, stream);

  // TTT scan
  k_ttt<<<256, 256, TTT_LDS_BYTES, stream>>>(qb, kb, vb, W1, b1, W2, b2, lnw, lnb,
                                             z2acc, zqp, bar);
  // LN fwd + residual (16-way Z2q partial sum inside)
  k_lnout<<<1600, 256, 0, stream>>>(zqp, qb, lnw, lnb, obf);

  // output projection, K-split x2 (1024 each) -> combine into d_out
  k_gemm<2><<<dim3(16, 7, 2), 256, 0, stream>>>(wob, obf, 2048, 800, 2048, 2048, 1024,
                                                nullptr, nullptr, nullptr, g2part);
  k_comb_add<<<1600, 256, 0, stream>>>(g2part, g2part + 1638400, outf);
}

// Round 5
// 1389.544 us; speedup vs baseline: 2.3460x; 1.0331x over previous
//
#include <hip/hip_runtime.h>

// ---------------------------------------------------------------------------
// Branch_62989990363328: TimesBlock conv ensemble -> TTT-MLP -> out proj
// B=2 T=400 C=64 OUT=2048 NH=8 HD=256 INNER=1024 MB=10 NC=40
// R5: barrier counters padded to 128B/head (kill MALL line contention);
//     next-chunk xk/tgt prefetch overlaps Z1q/Z2q phase.
// ---------------------------------------------------------------------------

typedef __bf16 bf16x8 __attribute__((ext_vector_type(8)));
typedef float  f32x4  __attribute__((ext_vector_type(4)));

__device__ __forceinline__ unsigned short f2bf(float f){
  unsigned int u = __builtin_bit_cast(unsigned int, f);
  u += 0x7fffu + ((u >> 16) & 1u);
  return (unsigned short)(u >> 16);
}
__device__ __forceinline__ float bf2f(unsigned short b){
  unsigned int u = ((unsigned int)b) << 16;
  return __builtin_bit_cast(float, u);
}
__device__ __forceinline__ float gelu_f(float x){
  return 0.5f * x * (1.0f + erff(x * 0.70710678118654752f));
}
__device__ __forceinline__ float gelu_bwd_f(float x){
  return 0.5f * (1.0f + erff(x * 0.70710678118654752f))
       + x * __expf(-0.5f * x * x) * 0.3989422804014327f;
}

// agent-scope relaxed atomic helpers (MALL-coherent, bypass L1/L2)
__device__ __forceinline__ float2 aload2(const float* p){
  unsigned long long v = __hip_atomic_load((const unsigned long long*)p,
                                           __ATOMIC_RELAXED, __HIP_MEMORY_SCOPE_AGENT);
  union { unsigned long long u; float2 f; } cv; cv.u = v; return cv.f;
}
__device__ __forceinline__ void aadd(float* p, float v){
  __hip_atomic_fetch_add(p, v, __ATOMIC_RELAXED, __HIP_MEMORY_SCOPE_AGENT);
}

union Frag { bf16x8 v; unsigned short u[8]; };

// ---------------------------------------------------------------------------
// Prep kernels
// ---------------------------------------------------------------------------

__global__ __launch_bounds__(256) void k_weff(
    const float* __restrict__ w0, const float* __restrict__ w1,
    const float* __restrict__ w2, const float* __restrict__ w3,
    const float* __restrict__ w4, const float* __restrict__ w5,
    unsigned short* __restrict__ weff)
{
  int idx = blockIdx.x * 256 + threadIdx.x;
  if (idx >= 2048 * 7744) return;
  int o = idx / 7744, k = idx % 7744;
  int c = k / 121, dd = k % 121, di = dd / 11, dj = dd % 11;
  const float* ws6[6] = {w0, w1, w2, w3, w4, w5};
  float s = 0.f;
#pragma unroll
  for (int i = 0; i < 6; i++){
    int kk = 2 * i + 1;
    int a = di - 5 + i, b = dj - 5 + i;
    if (a >= 0 && a < kk && b >= 0 && b < kk)
      s += ws6[i][(((size_t)o * 64 + c) * kk + a) * kk + b];
  }
  weff[idx] = f2bf(s);
}

__global__ __launch_bounds__(256) void k_im2col(
    const float* __restrict__ x, unsigned short* __restrict__ P)
{
  int idx = blockIdx.x * 256 + threadIdx.x;
  if (idx >= 800 * 7744) return;
  int n = idx / 7744, k = idx % 7744;
  int c = k / 121, dd = k % 121, di = dd / 11, dj = dd % 11;
  int b = n / 400, pos = n % 400, i = pos / 20, j = pos % 20;
  int ii = i + di - 5, jj = j + dj - 5;
  float v = 0.f;
  if (ii >= 0 && ii < 20 && jj >= 0 && jj < 20)
    v = x[((size_t)b * 400 + ii * 20 + jj) * 64 + c];
  P[idx] = f2bf(v);
}

__global__ __launch_bounds__(256) void k_wqkv(
    const float* __restrict__ wq, const float* __restrict__ wk,
    const float* __restrict__ wv, unsigned short* __restrict__ dst)
{
  int idx = blockIdx.x * 256 + threadIdx.x;
  if (idx >= 6144 * 2048) return;
  int m = idx >> 11, kk = idx & 2047;
  const float* src = (m < 2048) ? wq : ((m < 4096) ? wk : wv);
  dst[idx] = f2bf(src[(size_t)(m & 2047) * 2048 + kk]);
}

__global__ __launch_bounds__(256) void k_f2bf_copy(
    const float* __restrict__ src, unsigned short* __restrict__ dst, int n)
{
  int idx = blockIdx.x * 256 + threadIdx.x;
  if (idx < n) dst[idx] = f2bf(src[idx]);
}

__global__ __launch_bounds__(256) void k_bsum(
    const float* __restrict__ b0, const float* __restrict__ b1,
    const float* __restrict__ b2, const float* __restrict__ b3,
    const float* __restrict__ b4, const float* __restrict__ b5,
    float* __restrict__ bsum)
{
  int idx = blockIdx.x * 256 + threadIdx.x;
  if (idx < 2048)
    bsum[idx] = b0[idx] + b1[idx] + b2[idx] + b3[idx] + b4[idx] + b5[idx];
}

// combine kernels for K-split GEMMs (4 elems/thread, 1600 blocks)
__global__ __launch_bounds__(256) void k_comb_silu(
    const float* __restrict__ p0, const float* __restrict__ p1,
    const float* __restrict__ bsum, unsigned short* __restrict__ xb)
{
  int i4 = (blockIdx.x * 256 + threadIdx.x) * 4;
  float4 a = *(const float4*)&p0[i4];
  float4 b = *(const float4*)&p1[i4];
  int mm = i4 & 2047;
  float4 bs = *(const float4*)&bsum[mm];
  float v[4] = {a.x + b.x + bs.x, a.y + b.y + bs.y, a.z + b.z + bs.z, a.w + b.w + bs.w};
  ushort4 o;
#pragma unroll
  for (int i = 0; i < 4; i++){
    float t = v[i] * (1.0f / 6.0f);
    float sv = t / (1.0f + __expf(-t));
    ((unsigned short*)&o)[i] = f2bf(sv);
  }
  *(ushort4*)&xb[i4] = o;
}

__global__ __launch_bounds__(256) void k_comb_add(
    const float* __restrict__ p0, const float* __restrict__ p1,
    float* __restrict__ out)
{
  int i4 = (blockIdx.x * 256 + threadIdx.x) * 4;
  float4 a = *(const float4*)&p0[i4];
  float4 b = *(const float4*)&p1[i4];
  float4 o = {a.x + b.x, a.y + b.y, a.z + b.z, a.w + b.w};
  *(float4*)&out[i4] = o;
}

// ---------------------------------------------------------------------------
// Generic bf16 MFMA GEMM: C[M][N] (+)= A[M][K] * B[N][K]^T, K-split via z.
// ---------------------------------------------------------------------------
template<int MODE>
__global__ __launch_bounds__(256, 1) void k_gemm(
    const unsigned short* __restrict__ A, const unsigned short* __restrict__ B,
    int M, int N, int lda, int ldb, int kLen,
    float* __restrict__ qb, float* __restrict__ kb, float* __restrict__ vb,
    float* __restrict__ outf)
{
  __shared__ unsigned short As[128 * 32];
  __shared__ unsigned short Bs[128 * 32];
  int tid = threadIdx.x, w = tid >> 6, l = tid & 63, qd = l >> 4, lm = l & 15;
  int m0 = blockIdx.x * 128, n0 = blockIdx.y * 128;
  int kBase = blockIdx.z * kLen;

  f32x4 acc[4][4];
#pragma unroll
  for (int i = 0; i < 4; i++)
#pragma unroll
    for (int j = 0; j < 4; j++){ acc[i][j][0]=0.f; acc[i][j][1]=0.f; acc[i][j][2]=0.f; acc[i][j][3]=0.f; }

  int nk = kLen >> 5;
  for (int kt = 0; kt < nk; kt++){
    int k0 = kBase + (kt << 5);
#pragma unroll
    for (int i = 0; i < 2; i++){
      int cidx = tid + i * 256;
      int row = cidx >> 2, kc = (cidx & 3) << 3;
      *(uint4*)&As[row * 32 + kc] = *(const uint4*)&A[(size_t)(m0 + row) * lda + k0 + kc];
      int br = n0 + row; if (br >= N) br = N - 1;
      *(uint4*)&Bs[row * 32 + kc] = *(const uint4*)&B[(size_t)br * ldb + k0 + kc];
    }
    __syncthreads();
    bf16x8 af[4], bfv[4];
#pragma unroll
    for (int i = 0; i < 4; i++)
      af[i] = *(const bf16x8*)&As[((w >> 1) * 64 + i * 16 + lm) * 32 + qd * 8];
#pragma unroll
    for (int j = 0; j < 4; j++)
      bfv[j] = *(const bf16x8*)&Bs[((w & 1) * 64 + j * 16 + lm) * 32 + qd * 8];
#pragma unroll
    for (int i = 0; i < 4; i++)
#pragma unroll
      for (int j = 0; j < 4; j++)
        acc[i][j] = __builtin_amdgcn_mfma_f32_16x16x32_bf16(af[i], bfv[j], acc[i][j], 0, 0, 0);
    __syncthreads();
  }

#pragma unroll
  for (int i = 0; i < 4; i++){
    int mBase = m0 + (w >> 1) * 64 + i * 16 + qd * 4;
#pragma unroll
    for (int j = 0; j < 4; j++){
      int n = n0 + (w & 1) * 64 + j * 16 + lm;
      if (n < N){
#pragma unroll
        for (int rr = 0; rr < 4; rr++){
          float val = acc[i][j][rr];
          int mm = mBase + rr;
          if (MODE == 1){
            int proj = mm >> 11, o = mm & 2047, hh = o >> 8, d = o & 255;
            int bh = (n / 400) * 8 + hh, tt = n % 400;
            float* dst = (proj == 0) ? qb : ((proj == 1) ? kb : vb);
            dst[((size_t)bh * 400 + tt) * 256 + d] = val;
          } else {
            outf[(size_t)blockIdx.z * M * N + (size_t)n * M + mm] = val;
          }
        }
      }
    }
  }
}

// ---------------------------------------------------------------------------
// TTT persistent kernel. 256 WGs: 16 heads x 16 INNER-slices (64 wide).
// ---------------------------------------------------------------------------
#define O_W1BT 0
#define O_W2K  16896
#define O_W2N  33792
#define O_XKQ  52224
#define O_TGT  56448
#define O_A1   59008
#define O_A1T  60160
#define O_GZ2  62720
#define O_ZPAD 66944
#define O_GZ1  71168
#define O_XQ2  73728      // [16][264] xq bf16 (rows 10..15 zero)
#define US_TOTAL 77952
#define O_F32  77952
#define TTT_LDS_BYTES (77952 * 2 + 832 * 4)   // 159232 <= 163840

#define ETA 0.01f
#define BAR_STRIDE 32     // 128B per head counter — one MALL line each

__global__ __launch_bounds__(256, 1) void k_ttt(
    const float* __restrict__ qg, const float* __restrict__ kg, const float* __restrict__ vg,
    const float* __restrict__ W1g, const float* __restrict__ b1g,
    const float* __restrict__ W2g, const float* __restrict__ b2g,
    const float* __restrict__ gwg, const float* __restrict__ gbg,
    float* __restrict__ z2acc, unsigned short* __restrict__ zqp,
    unsigned int* __restrict__ bar)
{
  extern __shared__ unsigned short lds[];
  float* ldsf = (float*)&lds[O_F32];

  int tid = threadIdx.x, w = tid >> 6, l = tid & 63, qd = l >> 4, lm = l & 15;
  int bid = blockIdx.x;
  int jj = bid >> 3, xx = bid & 7;
  int h  = xx + 8 * (jj >> 4);   // bh = b*8 + head  (0..15)
  int sl = jj & 15;              // INNER slice (0..15)
  int hh = h & 7;

  for (int i = tid; i < US_TOTAL; i += 256) lds[i] = 0;
  for (int i = tid; i < 832; i += 256) ldsf[i] = 0.f;
  __syncthreads();

  float w1r[4][4][4];
#pragma unroll
  for (int a = 0; a < 4; a++)
#pragma unroll
    for (int nt = 0; nt < 4; nt++)
#pragma unroll
      for (int rr = 0; rr < 4; rr++)
        w1r[a][nt][rr] = W1g[((size_t)hh * 256 + (4 * w + a) * 16 + qd * 4 + rr) * 1024
                             + sl * 64 + nt * 16 + lm];
  float w2r[16][4];
#pragma unroll
  for (int nt = 0; nt < 16; nt++)
#pragma unroll
    for (int rr = 0; rr < 4; rr++)
      w2r[nt][rr] = W2g[((size_t)hh * 1024 + sl * 64 + w * 16 + qd * 4 + rr) * 256
                        + nt * 16 + lm];
  if (tid < 64)  ldsf[tid] = b1g[hh * 1024 + sl * 64 + tid];
  if (tid < 256){
    ldsf[64 + tid]  = b2g[hh * 256 + tid];
    ldsf[320 + tid] = gwg[hh * 256 + tid];
    ldsf[576 + tid] = gbg[hh * 256 + tid];
  }

#define WRITE_W1BF() do { \
  _Pragma("unroll") for (int a = 0; a < 4; a++){ \
    int m0i = (4 * w + a) * 16 + qd * 4; \
    _Pragma("unroll") for (int nt = 0; nt < 4; nt++){ \
      int n = nt * 16 + lm; \
      unsigned int p0 = f2bf(w1r[a][nt][0]) | ((unsigned int)f2bf(w1r[a][nt][1]) << 16); \
      unsigned int p1 = f2bf(w1r[a][nt][2]) | ((unsigned int)f2bf(w1r[a][nt][3]) << 16); \
      *(unsigned int*)&lds[O_W1BT + n * 264 + m0i]     = p0; \
      *(unsigned int*)&lds[O_W1BT + n * 264 + m0i + 2] = p1; \
    } } } while(0)

#define WRITE_W2BF() do { \
  int mB = w * 16 + qd * 4; \
  _Pragma("unroll") for (int nt = 0; nt < 16; nt++){ \
    int n = nt * 16 + lm; \
    _Pragma("unroll") for (int rr = 0; rr < 4; rr++) \
      lds[O_W2K + (mB + rr) * 264 + n] = f2bf(w2r[nt][rr]); \
    unsigned int p0 = f2bf(w2r[nt][0]) | ((unsigned int)f2bf(w2r[nt][1]) << 16); \
    unsigned int p1 = f2bf(w2r[nt][2]) | ((unsigned int)f2bf(w2r[nt][3]) << 16); \
    *(unsigned int*)&lds[O_W2N + n * 72 + mB]     = p0; \
    *(unsigned int*)&lds[O_W2N + n * 72 + mB + 2] = p1; \
  } } while(0)

#define LOAD_XK_TGT(NCH) do { \
  const float* kp = kg + hb + (size_t)(NCH) * 10 * 256; \
  const float* vp = vg + hb + (size_t)(NCH) * 10 * 256; \
  _Pragma("unroll") for (int r2 = 0; r2 < 10; r2++){ \
    float kv = kp[r2 * 256 + tid]; \
    float vv = vp[r2 * 256 + tid]; \
    lds[O_XKQ + r2 * 264 + tid] = f2bf(kv); \
    lds[O_TGT + r2 * 256 + tid] = f2bf(vv - kv); \
  } } while(0)

  WRITE_W1BF();
  WRITE_W2BF();

  const size_t hb = (size_t)h * 400 * 256;

  // preload chunk 0 xk/tgt
  LOAD_XK_TGT(0);
  __syncthreads();

  for (int nch = 0; nch < 40; nch++){
    const size_t chunkBase = (size_t)(h * 40 + nch) * 10 * 256;

    // 2. Z1 slice = xk @ W1s
    f32x4 z1a; z1a[0]=0.f; z1a[1]=0.f; z1a[2]=0.f; z1a[3]=0.f;
#pragma unroll
    for (int ks = 0; ks < 8; ks++){
      bf16x8 av = *(const bf16x8*)&lds[O_XKQ + lm * 264 + ks * 32 + qd * 8];
      bf16x8 bv = *(const bf16x8*)&lds[O_W1BT + (w * 16 + lm) * 264 + ks * 32 + qd * 8];
      z1a = __builtin_amdgcn_mfma_f32_16x16x32_bf16(av, bv, z1a, 0, 0, 0);
    }
    float z1v[4];
    {
      float b1n = ldsf[w * 16 + lm];
#pragma unroll
      for (int rr = 0; rr < 4; rr++){
        z1v[rr] = z1a[rr] + b1n;
        int mr = qd * 4 + rr;
        if (mr < 10){
          float a1 = gelu_f(z1v[rr]);
          unsigned short ab = f2bf(a1);
          lds[O_A1 + mr * 72 + w * 16 + lm] = ab;
          lds[O_A1T + (w * 16 + lm) * 40 + mr] = ab;
        }
      }
    }
    __syncthreads();

    // 4. Z2 partial = A1s @ W2s -> atomicAdd into per-chunk accumulator
#pragma unroll
    for (int nt4 = 0; nt4 < 4; nt4++){
      int nt = 4 * w + nt4;
      f32x4 p; p[0]=0.f; p[1]=0.f; p[2]=0.f; p[3]=0.f;
#pragma unroll
      for (int ks = 0; ks < 2; ks++){
        bf16x8 av = *(const bf16x8*)&lds[O_A1 + lm * 72 + ks * 32 + qd * 8];
        bf16x8 bv = *(const bf16x8*)&lds[O_W2N + (nt * 16 + lm) * 72 + ks * 32 + qd * 8];
        p = __builtin_amdgcn_mfma_f32_16x16x32_bf16(av, bv, p, 0, 0, 0);
      }
#pragma unroll
      for (int rr = 0; rr < 4; rr++){
        int mr = qd * 4 + rr;
        if (mr < 10)
          aadd(&z2acc[chunkBase + (size_t)mr * 256 + nt * 16 + lm], p[rr]);
      }
    }

    // 4b. prefetch xq into XQ2 (overlaps barrier wait)
    {
      const float* qp = qg + hb + (size_t)nch * 10 * 256;
#pragma unroll
      for (int r2 = 0; r2 < 10; r2++)
        lds[O_XQ2 + r2 * 264 + tid] = f2bf(qp[r2 * 256 + tid]);
    }

    // 5. per-head barrier (padded counter: one line per head)
    __syncthreads();
    if (tid == 0){
      __hip_atomic_fetch_add(bar + h * BAR_STRIDE, 1u, __ATOMIC_RELAXED, __HIP_MEMORY_SCOPE_AGENT);
      unsigned int target = 16u * (unsigned int)(nch + 1);
      unsigned int spins = 0;
      while (__hip_atomic_load(bar + h * BAR_STRIDE, __ATOMIC_RELAXED, __HIP_MEMORY_SCOPE_AGENT) < target
             && spins < 8000000u){ spins++; __builtin_amdgcn_s_sleep(1); }
    }
    __syncthreads();

    // 7. gZ2 (fused LN-L2 backward) from reduced Z2, redundantly per WG
    for (int r2 = w; r2 < 10; r2 += 4){
      int c0 = l * 4;
      const float* bp = &z2acc[chunkBase + (size_t)r2 * 256 + c0];
      float2 u01 = aload2(bp);
      float2 u23 = aload2(bp + 2);
      float zz[4] = {u01.x, u01.y, u23.x, u23.y};
      float s1 = 0.f, s2 = 0.f;
#pragma unroll
      for (int i = 0; i < 4; i++){ zz[i] += ldsf[64 + c0 + i]; s1 += zz[i]; s2 += zz[i] * zz[i]; }
#pragma unroll
      for (int off = 32; off >= 1; off >>= 1){ s1 += __shfl_xor(s1, off, 64); s2 += __shfl_xor(s2, off, 64); }
      float mu = s1 * (1.f / 256.f);
      float var = s2 * (1.f / 256.f) - mu * mu;
      float rstd = rsqrtf(var + 1e-6f);
      float xh[4], gx[4];
      float t1 = 0.f, t2 = 0.f;
#pragma unroll
      for (int i = 0; i < 4; i++){
        xh[i] = (zz[i] - mu) * rstd;
        float gwv = ldsf[320 + c0 + i], gbv = ldsf[576 + c0 + i];
        float tg = bf2f(lds[O_TGT + r2 * 256 + c0 + i]);
        float go = gwv * xh[i] + gbv - tg;
        gx[i] = go * gwv;
        t1 += gx[i]; t2 += gx[i] * xh[i];
      }
#pragma unroll
      for (int off = 32; off >= 1; off >>= 1){ t1 += __shfl_xor(t1, off, 64); t2 += __shfl_xor(t2, off, 64); }
      float m1 = t1 * (1.f / 256.f), m2 = t2 * (1.f / 256.f);
      float g0 = (gx[0] - m1 - xh[0] * m2) * rstd;
      float g1 = (gx[1] - m1 - xh[1] * m2) * rstd;
      float g2 = (gx[2] - m1 - xh[2] * m2) * rstd;
      float g3 = (gx[3] - m1 - xh[3] * m2) * rstd;
      unsigned int p0 = f2bf(g0) | ((unsigned int)f2bf(g1) << 16);
      unsigned int p1 = f2bf(g2) | ((unsigned int)f2bf(g3) << 16);
      *(unsigned int*)&lds[O_GZ2 + r2 * 264 + c0]     = p0;
      *(unsigned int*)&lds[O_GZ2 + r2 * 264 + c0 + 2] = p1;
    }
    __syncthreads();

    // 9a. b2 -= eta * sum_rows(gZ2)
    {
      float sum = 0.f;
#pragma unroll
      for (int r2 = 0; r2 < 10; r2++) sum += bf2f(lds[O_GZ2 + r2 * 264 + tid]);
      ldsf[64 + tid] -= ETA * sum;
    }
    // 9b. gZ1 slice = (gZ2 @ W2s^T) * gelu'(Z1)
    {
      f32x4 g1a; g1a[0]=0.f; g1a[1]=0.f; g1a[2]=0.f; g1a[3]=0.f;
#pragma unroll
      for (int ks = 0; ks < 8; ks++){
        bf16x8 av = *(const bf16x8*)&lds[O_GZ2 + lm * 264 + ks * 32 + qd * 8];
        bf16x8 bv = *(const bf16x8*)&lds[O_W2K + (w * 16 + lm) * 264 + ks * 32 + qd * 8];
        g1a = __builtin_amdgcn_mfma_f32_16x16x32_bf16(av, bv, g1a, 0, 0, 0);
      }
#pragma unroll
      for (int rr = 0; rr < 4; rr++){
        int mr = qd * 4 + rr;
        if (mr < 10){
          float gz1 = g1a[rr] * gelu_bwd_f(z1v[rr]);
          lds[O_GZ1 + (w * 16 + lm) * 40 + mr] = f2bf(gz1);
        }
      }
    }
    __syncthreads();

    // 11a. b1 -= eta * colsum(gZ1)
    if (tid < 64){
      float sum = 0.f;
#pragma unroll
      for (int kx = 0; kx < 10; kx++) sum += bf2f(lds[O_GZ1 + tid * 40 + kx]);
      ldsf[tid] -= ETA * sum;
    }
    // 11b. W1 update: dW1 = xk^T @ gZ1
#pragma unroll
    for (int a = 0; a < 4; a++){
      int mt = 4 * w + a;
      Frag afr;
#pragma unroll
      for (int j8 = 0; j8 < 8; j8++)
        afr.u[j8] = lds[O_XKQ + (qd * 8 + j8) * 264 + mt * 16 + lm];
#pragma unroll
      for (int nt = 0; nt < 4; nt++){
        bf16x8 bv = *(const bf16x8*)&lds[O_GZ1 + (nt * 16 + lm) * 40 + qd * 8];
        f32x4 d; d[0]=0.f; d[1]=0.f; d[2]=0.f; d[3]=0.f;
        d = __builtin_amdgcn_mfma_f32_16x16x32_bf16(afr.v, bv, d, 0, 0, 0);
#pragma unroll
        for (int rr = 0; rr < 4; rr++) w1r[a][nt][rr] -= ETA * d[rr];
      }
    }
    // 11c. W2 update: dW2 = A1^T @ gZ2
    {
      bf16x8 av2 = *(const bf16x8*)&lds[O_A1T + (w * 16 + lm) * 40 + qd * 8];
#pragma unroll
      for (int nt = 0; nt < 16; nt++){
        Frag bfr;
#pragma unroll
        for (int j8 = 0; j8 < 8; j8++)
          bfr.u[j8] = lds[O_GZ2 + (qd * 8 + j8) * 264 + nt * 16 + lm];
        f32x4 d; d[0]=0.f; d[1]=0.f; d[2]=0.f; d[3]=0.f;
        d = __builtin_amdgcn_mfma_f32_16x16x32_bf16(av2, bfr.v, d, 0, 0, 0);
#pragma unroll
        for (int rr = 0; rr < 4; rr++) w2r[nt][rr] -= ETA * d[rr];
      }
    }
    WRITE_W1BF();
    WRITE_W2BF();
    __syncthreads();

    // prefetch next chunk's xk/tgt (XKQ/TGT dead until next iteration)
    if (nch + 1 < 40) LOAD_XK_TGT(nch + 1);

    // 15. Z1q = xq @ W1_new + b1_new -> A1q
    {
      f32x4 zq; zq[0]=0.f; zq[1]=0.f; zq[2]=0.f; zq[3]=0.f;
#pragma unroll
      for (int ks = 0; ks < 8; ks++){
        bf16x8 av = *(const bf16x8*)&lds[O_XQ2 + lm * 264 + ks * 32 + qd * 8];
        bf16x8 bv = *(const bf16x8*)&lds[O_W1BT + (w * 16 + lm) * 264 + ks * 32 + qd * 8];
        zq = __builtin_amdgcn_mfma_f32_16x16x32_bf16(av, bv, zq, 0, 0, 0);
      }
      float b1n = ldsf[w * 16 + lm];
#pragma unroll
      for (int rr = 0; rr < 4; rr++){
        int mr = qd * 4 + rr;
        if (mr < 10)
          lds[O_A1 + mr * 72 + w * 16 + lm] = f2bf(gelu_f(zq[rr] + b1n));
      }
    }
    __syncthreads();

    // 17. Z2q partial = A1q @ W2_new -> plain bf16 stores to own slice buffer
    {
      unsigned short* zq_out = zqp + ((size_t)(h * 16 + sl) * 40 + nch) * 2560;
#pragma unroll
      for (int nt4 = 0; nt4 < 4; nt4++){
        int nt = 4 * w + nt4;
        f32x4 p; p[0]=0.f; p[1]=0.f; p[2]=0.f; p[3]=0.f;
#pragma unroll
        for (int ks = 0; ks < 2; ks++){
          bf16x8 av = *(const bf16x8*)&lds[O_A1 + lm * 72 + ks * 32 + qd * 8];
          bf16x8 bv = *(const bf16x8*)&lds[O_W2N + (nt * 16 + lm) * 72 + ks * 32 + qd * 8];
          p = __builtin_amdgcn_mfma_f32_16x16x32_bf16(av, bv, p, 0, 0, 0);
        }
        float bb = (sl == 0) ? ldsf[64 + nt * 16 + lm] : 0.f;
#pragma unroll
        for (int rr = 0; rr < 4; rr++){
          int mr = qd * 4 + rr;
          if (mr < 10)
            zq_out[mr * 256 + nt * 16 + lm] = f2bf(p[rr] + bb);
        }
      }
    }
    __syncthreads();
  }
}

// ---------------------------------------------------------------------------
// LN forward + residual; sums 16 bf16 slice partials of Z2q in fp32.
// ---------------------------------------------------------------------------
__global__ __launch_bounds__(256) void k_lnout(
    const unsigned short* __restrict__ zqp, const float* __restrict__ qg,
    const float* __restrict__ gwg, const float* __restrict__ gbg,
    unsigned short* __restrict__ obf)
{
  int w = threadIdx.x >> 6, l = threadIdx.x & 63;
  int gr = blockIdx.x * 4 + w;
  int h = gr / 400, t = gr % 400, hh = h & 7, b = h >> 3;
  int nch = t / 10, mr = t % 10;
  int c0 = l * 4;
  float z[4] = {0.f, 0.f, 0.f, 0.f};
#pragma unroll
  for (int sl = 0; sl < 16; sl++){
    const unsigned short* zp = zqp + (((size_t)(h * 16 + sl) * 40 + nch) * 10 + mr) * 256 + c0;
    ushort4 u = *(const ushort4*)zp;
    z[0] += bf2f(u.x); z[1] += bf2f(u.y); z[2] += bf2f(u.z); z[3] += bf2f(u.w);
  }
  float s1 = 0.f, s2 = 0.f;
#pragma unroll
  for (int i = 0; i < 4; i++){ s1 += z[i]; s2 += z[i] * z[i]; }
#pragma unroll
  for (int off = 32; off >= 1; off >>= 1){ s1 += __shfl_xor(s1, off, 64); s2 += __shfl_xor(s2, off, 64); }
  float mu = s1 * (1.f / 256.f);
  float var = s2 * (1.f / 256.f) - mu * mu;
  float rstd = rsqrtf(var + 1e-6f);
  const float* qp = &qg[((size_t)h * 400 + t) * 256];
  unsigned short* op = &obf[((size_t)(b * 400 + t)) * 2048 + hh * 256];
#pragma unroll
  for (int i = 0; i < 4; i++){
    float xh = (z[i] - mu) * rstd;
    float o = qp[c0 + i] + gwg[hh * 256 + c0 + i] * xh + gbg[hh * 256 + c0 + i];
    op[c0 + i] = f2bf(o);
  }
}

// ---------------------------------------------------------------------------
// launch
// ---------------------------------------------------------------------------
#define WS_WEFF   0u
#define WS_P      31719424u
#define WS_WQKV   44109824u
#define WS_WOB    52428800u
#define WS_Z2ACC  62722048u
#define WS_XB     69275648u
#define WS_Q      72552448u
#define WS_K      79106048u
#define WS_V      85659648u
#define WS_OBF    92213248u
#define WS_BSUM   95490048u
#define WS_BAR    95498240u

extern "C" void kernel_launch(void* const* d_in, const int* in_sizes, int n_in,
                              void* d_out, int out_size, void* d_ws, size_t ws_size,
                              hipStream_t stream)
{
  (void)in_sizes; (void)n_in; (void)out_size; (void)ws_size;
  const float* x  = (const float*)d_in[0];
  const float* cw[6]; const float* cb[6];
  for (int i = 0; i < 6; i++){ cw[i] = (const float*)d_in[2 + 2 * i]; cb[i] = (const float*)d_in[3 + 2 * i]; }
  const float* wq  = (const float*)d_in[14];
  const float* wk  = (const float*)d_in[15];
  const float* wv  = (const float*)d_in[16];
  const float* wo  = (const float*)d_in[17];
  const float* W1  = (const float*)d_in[18];
  const float* b1  = (const float*)d_in[19];
  const float* W2  = (const float*)d_in[20];
  const float* b2  = (const float*)d_in[21];
  const float* lnw = (const float*)d_in[22];
  const float* lnb = (const float*)d_in[23];
  float* outf = (float*)d_out;

  char* wsb = (char*)d_ws;
  unsigned short* weff = (unsigned short*)(wsb + WS_WEFF);
  unsigned short* P    = (unsigned short*)(wsb + WS_P);
  unsigned short* wqkv = (unsigned short*)(wsb + WS_WQKV);
  unsigned short* wob  = (unsigned short*)(wsb + WS_WOB);
  unsigned short* xb   = (unsigned short*)(wsb + WS_XB);
  float* qb   = (float*)(wsb + WS_Q);
  float* kb   = (float*)(wsb + WS_K);
  float* vb   = (float*)(wsb + WS_V);
  float* z2acc = (float*)(wsb + WS_Z2ACC);
  unsigned short* zqp = (unsigned short*)(wsb + WS_WEFF);   // 52.4 MB alias
  unsigned short* obf = (unsigned short*)(wsb + WS_OBF);
  float* bsum = (float*)(wsb + WS_BSUM);
  unsigned int* bar = (unsigned int*)(wsb + WS_BAR);
  float* g0part = (float*)(wsb + WS_Q);     // 13.1 MB, alias qb+kb (pre-gemm1)
  float* g2part = (float*)(wsb + WS_K);     // 13.1 MB, alias kb+vb (post-lnout)

  hipMemsetAsync(bar, 0, 16 * BAR_STRIDE * 4, stream);
  hipFuncSetAttribute(reinterpret_cast<const void*>(k_ttt),
                      hipFuncAttributeMaxDynamicSharedMemorySize, TTT_LDS_BYTES);

  k_weff<<<(2048 * 7744 + 255) / 256, 256, 0, stream>>>(cw[0], cw[1], cw[2], cw[3], cw[4], cw[5], weff);
  k_im2col<<<(800 * 7744 + 255) / 256, 256, 0, stream>>>(x, P);
  k_wqkv<<<(6144 * 2048 + 255) / 256, 256, 0, stream>>>(wq, wk, wv, wqkv);
  k_bsum<<<8, 256, 0, stream>>>(cb[0], cb[1], cb[2], cb[3], cb[4], cb[5], bsum);

  k_gemm<2><<<dim3(16, 7, 2), 256, 0, stream>>>(weff, P, 2048, 800, 7744, 7744, 3872,
                                                nullptr, nullptr, nullptr, g0part);
  k_comb_silu<<<1600, 256, 0, stream>>>(g0part, g0part + 1638400, bsum, xb);

  k_gemm<1><<<dim3(48, 7, 1), 256, 0, stream>>>(wqkv, xb, 6144, 800, 2048, 2048, 2048,
                                                qb, kb, vb, nullptr);

  k_f2bf_copy<<<(2048 * 2048 + 255) / 256, 256, 0, stream>>>(wo, wob, 2048 * 2048);
  hipMemsetAsync(z2acc, 0, 16 * 40 * 10 * 256 * 4, stream);

  k_ttt<<<256, 256, TTT_LDS_BYTES, stream>>>(qb, kb, vb, W1, b1, W2, b2, lnw, lnb,
                                             z2acc, zqp, bar);
  k_lnout<<<1600, 256, 0, stream>>>(zqp, qb, lnw, lnb, obf);

  k_gemm<2><<<dim3(16, 7, 2), 256, 0, stream>>>(wob, obf, 2048, 800, 2048, 2048, 1024,
                                                nullptr, nullptr, nullptr, g2part);
  k_comb_add<<<1600, 256, 0, stream>>>(g2part, g2part + 1638400, outf);
}

// Round 6
// 1130.450 us; speedup vs baseline: 2.8837x; 1.2292x over previous
//
#include <hip/hip_runtime.h>

// ---------------------------------------------------------------------------
// Branch_62989990363328: TimesBlock conv ensemble -> TTT-MLP -> out proj
// B=2 T=400 C=64 OUT=2048 NH=8 HD=256 INNER=1024 MB=10 NC=40
// R6: k_ttt scalar-op purge (XKT/GZ2T transposed copies -> b128 fragment
//     loads), q/k/v in bf16 (coalesced dword loads), LDS-staged k_weff.
// ---------------------------------------------------------------------------

typedef __bf16 bf16x8 __attribute__((ext_vector_type(8)));
typedef float  f32x4  __attribute__((ext_vector_type(4)));

__device__ __forceinline__ unsigned short f2bf(float f){
  unsigned int u = __builtin_bit_cast(unsigned int, f);
  u += 0x7fffu + ((u >> 16) & 1u);
  return (unsigned short)(u >> 16);
}
__device__ __forceinline__ float bf2f(unsigned short b){
  unsigned int u = ((unsigned int)b) << 16;
  return __builtin_bit_cast(float, u);
}
__device__ __forceinline__ float gelu_f(float x){
  return 0.5f * x * (1.0f + erff(x * 0.70710678118654752f));
}
__device__ __forceinline__ float gelu_bwd_f(float x){
  return 0.5f * (1.0f + erff(x * 0.70710678118654752f))
       + x * __expf(-0.5f * x * x) * 0.3989422804014327f;
}

// agent-scope relaxed atomic helpers (MALL-coherent, bypass L1/L2)
__device__ __forceinline__ float2 aload2(const float* p){
  unsigned long long v = __hip_atomic_load((const unsigned long long*)p,
                                           __ATOMIC_RELAXED, __HIP_MEMORY_SCOPE_AGENT);
  union { unsigned long long u; float2 f; } cv; cv.u = v; return cv.f;
}
__device__ __forceinline__ void aadd(float* p, float v){
  __hip_atomic_fetch_add(p, v, __ATOMIC_RELAXED, __HIP_MEMORY_SCOPE_AGENT);
}

// ---------------------------------------------------------------------------
// Prep kernels
// ---------------------------------------------------------------------------

// LDS-staged conv-ensemble combine: one WG per output channel o.
// Stages all 6 kernels' weights for o (18304 floats) via coalesced loads,
// then scatters into the 11x11 effective kernel.
__global__ __launch_bounds__(256) void k_weff(
    const float* __restrict__ w0, const float* __restrict__ w1,
    const float* __restrict__ w2, const float* __restrict__ w3,
    const float* __restrict__ w4, const float* __restrict__ w5,
    unsigned short* __restrict__ weff)
{
  extern __shared__ float sw[];   // 18304 floats = 73216 B
  const int off[6] = {0, 64, 640, 2240, 5376, 10560};
  const float* ws6[6] = {w0, w1, w2, w3, w4, w5};
  int o = blockIdx.x, tid = threadIdx.x;
#pragma unroll
  for (int i = 0; i < 6; i++){
    int kk = 2 * i + 1, sz = 64 * kk * kk;
    const float* src = ws6[i] + (size_t)o * sz;
    for (int idx = tid; idx < sz; idx += 256) sw[off[i] + idx] = src[idx];
  }
  __syncthreads();
  for (int t = tid; t < 7744; t += 256){
    int c = t / 121, dd = t % 121, di = dd / 11, dj = dd % 11;
    float s = 0.f;
#pragma unroll
    for (int i = 0; i < 6; i++){
      int kk = 2 * i + 1;
      int a = di - 5 + i, b = dj - 5 + i;
      if (a >= 0 && a < kk && b >= 0 && b < kk)
        s += sw[off[i] + (c * kk + a) * kk + b];
    }
    weff[(size_t)o * 7744 + t] = f2bf(s);
  }
}

__global__ __launch_bounds__(256) void k_im2col(
    const float* __restrict__ x, unsigned short* __restrict__ P)
{
  int idx = blockIdx.x * 256 + threadIdx.x;
  if (idx >= 800 * 7744) return;
  int n = idx / 7744, k = idx % 7744;
  int c = k / 121, dd = k % 121, di = dd / 11, dj = dd % 11;
  int b = n / 400, pos = n % 400, i = pos / 20, j = pos % 20;
  int ii = i + di - 5, jj = j + dj - 5;
  float v = 0.f;
  if (ii >= 0 && ii < 20 && jj >= 0 && jj < 20)
    v = x[((size_t)b * 400 + ii * 20 + jj) * 64 + c];
  P[idx] = f2bf(v);
}

__global__ __launch_bounds__(256) void k_wqkv(
    const float* __restrict__ wq, const float* __restrict__ wk,
    const float* __restrict__ wv, unsigned short* __restrict__ dst)
{
  int idx = blockIdx.x * 256 + threadIdx.x;
  if (idx >= 6144 * 2048) return;
  int m = idx >> 11, kk = idx & 2047;
  const float* src = (m < 2048) ? wq : ((m < 4096) ? wk : wv);
  dst[idx] = f2bf(src[(size_t)(m & 2047) * 2048 + kk]);
}

__global__ __launch_bounds__(256) void k_f2bf_copy(
    const float* __restrict__ src, unsigned short* __restrict__ dst, int n)
{
  int idx = blockIdx.x * 256 + threadIdx.x;
  if (idx < n) dst[idx] = f2bf(src[idx]);
}

__global__ __launch_bounds__(256) void k_bsum(
    const float* __restrict__ b0, const float* __restrict__ b1,
    const float* __restrict__ b2, const float* __restrict__ b3,
    const float* __restrict__ b4, const float* __restrict__ b5,
    float* __restrict__ bsum)
{
  int idx = blockIdx.x * 256 + threadIdx.x;
  if (idx < 2048)
    bsum[idx] = b0[idx] + b1[idx] + b2[idx] + b3[idx] + b4[idx] + b5[idx];
}

__global__ __launch_bounds__(256) void k_comb_silu(
    const float* __restrict__ p0, const float* __restrict__ p1,
    const float* __restrict__ bsum, unsigned short* __restrict__ xb)
{
  int i4 = (blockIdx.x * 256 + threadIdx.x) * 4;
  float4 a = *(const float4*)&p0[i4];
  float4 b = *(const float4*)&p1[i4];
  int mm = i4 & 2047;
  float4 bs = *(const float4*)&bsum[mm];
  float v[4] = {a.x + b.x + bs.x, a.y + b.y + bs.y, a.z + b.z + bs.z, a.w + b.w + bs.w};
  ushort4 o;
#pragma unroll
  for (int i = 0; i < 4; i++){
    float t = v[i] * (1.0f / 6.0f);
    float sv = t / (1.0f + __expf(-t));
    ((unsigned short*)&o)[i] = f2bf(sv);
  }
  *(ushort4*)&xb[i4] = o;
}

__global__ __launch_bounds__(256) void k_comb_add(
    const float* __restrict__ p0, const float* __restrict__ p1,
    float* __restrict__ out)
{
  int i4 = (blockIdx.x * 256 + threadIdx.x) * 4;
  float4 a = *(const float4*)&p0[i4];
  float4 b = *(const float4*)&p1[i4];
  float4 o = {a.x + b.x, a.y + b.y, a.z + b.z, a.w + b.w};
  *(float4*)&out[i4] = o;
}

// ---------------------------------------------------------------------------
// Generic bf16 MFMA GEMM: C[M][N] = A[M][K] * B[N][K]^T, K-split via z.
// MODE 1: qkv scatter epilogue (bf16); MODE 2: fp32 store to outf[z][n][M].
// ---------------------------------------------------------------------------
template<int MODE>
__global__ __launch_bounds__(256, 1) void k_gemm(
    const unsigned short* __restrict__ A, const unsigned short* __restrict__ B,
    int M, int N, int lda, int ldb, int kLen,
    unsigned short* __restrict__ qb, unsigned short* __restrict__ kb,
    unsigned short* __restrict__ vb, float* __restrict__ outf)
{
  __shared__ unsigned short As[128 * 32];
  __shared__ unsigned short Bs[128 * 32];
  int tid = threadIdx.x, w = tid >> 6, l = tid & 63, qd = l >> 4, lm = l & 15;
  int m0 = blockIdx.x * 128, n0 = blockIdx.y * 128;
  int kBase = blockIdx.z * kLen;

  f32x4 acc[4][4];
#pragma unroll
  for (int i = 0; i < 4; i++)
#pragma unroll
    for (int j = 0; j < 4; j++){ acc[i][j][0]=0.f; acc[i][j][1]=0.f; acc[i][j][2]=0.f; acc[i][j][3]=0.f; }

  int nk = kLen >> 5;
  for (int kt = 0; kt < nk; kt++){
    int k0 = kBase + (kt << 5);
#pragma unroll
    for (int i = 0; i < 2; i++){
      int cidx = tid + i * 256;
      int row = cidx >> 2, kc = (cidx & 3) << 3;
      *(uint4*)&As[row * 32 + kc] = *(const uint4*)&A[(size_t)(m0 + row) * lda + k0 + kc];
      int br = n0 + row; if (br >= N) br = N - 1;
      *(uint4*)&Bs[row * 32 + kc] = *(const uint4*)&B[(size_t)br * ldb + k0 + kc];
    }
    __syncthreads();
    bf16x8 af[4], bfv[4];
#pragma unroll
    for (int i = 0; i < 4; i++)
      af[i] = *(const bf16x8*)&As[((w >> 1) * 64 + i * 16 + lm) * 32 + qd * 8];
#pragma unroll
    for (int j = 0; j < 4; j++)
      bfv[j] = *(const bf16x8*)&Bs[((w & 1) * 64 + j * 16 + lm) * 32 + qd * 8];
#pragma unroll
    for (int i = 0; i < 4; i++)
#pragma unroll
      for (int j = 0; j < 4; j++)
        acc[i][j] = __builtin_amdgcn_mfma_f32_16x16x32_bf16(af[i], bfv[j], acc[i][j], 0, 0, 0);
    __syncthreads();
  }

#pragma unroll
  for (int i = 0; i < 4; i++){
    int mBase = m0 + (w >> 1) * 64 + i * 16 + qd * 4;
#pragma unroll
    for (int j = 0; j < 4; j++){
      int n = n0 + (w & 1) * 64 + j * 16 + lm;
      if (n < N){
#pragma unroll
        for (int rr = 0; rr < 4; rr++){
          float val = acc[i][j][rr];
          int mm = mBase + rr;
          if (MODE == 1){
            int proj = mm >> 11, o = mm & 2047, hh = o >> 8, d = o & 255;
            int bh = (n / 400) * 8 + hh, tt = n % 400;
            unsigned short* dst = (proj == 0) ? qb : ((proj == 1) ? kb : vb);
            dst[((size_t)bh * 400 + tt) * 256 + d] = f2bf(val);
          } else {
            outf[(size_t)blockIdx.z * M * N + (size_t)n * M + mm] = val;
          }
        }
      }
    }
  }
}

// ---------------------------------------------------------------------------
// TTT persistent kernel. 256 WGs: 16 heads x 16 INNER-slices (64 wide).
// LDS layout (ushort offsets; b128-read bases are 8-ushort aligned):
// ---------------------------------------------------------------------------
#define O_W1BT 0        // [64][264]  W1^T bf16 (inner, hd)
#define O_W2K  16896    // [64][264]  W2 bf16   (inner, hd)  - B for gZ1
#define O_W2N  33792    // [256][72]  W2^T bf16 (hd, inner)  - B for Z2
#define O_XKQ  52224    // [10][264]  xk bf16 (A for Z1; rows>=10 spill = junk, C rows discarded)
#define O_TGT  54864    // [10][256]  (xv-xk) bf16
#define O_A1   57424    // [10][72]   A1 bf16
#define O_A1T  58144    // [64][40]   A1^T bf16 (cols>=10 zero - REQUIRED)
#define O_GZ2  60704    // [10][264]  gZ2 bf16
#define O_GZ1  63344    // [64][32]   gZ1 bf16 (cols>=10 zero - REQUIRED)
#define O_XQ2  65392    // [10][264]  xq bf16
#define O_GZ2T 68032    // [256][24]  gZ2^T bf16 (B for dW2; cols>=10 covered by A1T zeros)
#define O_XKT  74176    // [256][24]  xk^T bf16  (A for dW1; cols>=10 covered by GZ1 zeros)
#define O_F32  80320    // floats: b1s[64], b2[256]
#define O_GW   80960    // bf16[256]
#define O_GB   81216    // bf16[256]
#define US_TOTAL 81472
#define TTT_LDS_BYTES (81472 * 2)   // 162944 <= 163840

#define ETA 0.01f
#define BAR_STRIDE 32   // 128B per head counter

__global__ __launch_bounds__(256, 1) void k_ttt(
    const unsigned short* __restrict__ qg, const unsigned short* __restrict__ kg,
    const unsigned short* __restrict__ vg,
    const float* __restrict__ W1g, const float* __restrict__ b1g,
    const float* __restrict__ W2g, const float* __restrict__ b2g,
    const float* __restrict__ gwg, const float* __restrict__ gbg,
    float* __restrict__ z2acc, unsigned short* __restrict__ zqp,
    unsigned int* __restrict__ bar)
{
  extern __shared__ unsigned short lds[];
  float* ldsf = (float*)&lds[O_F32];

  int tid = threadIdx.x, w = tid >> 6, l = tid & 63, qd = l >> 4, lm = l & 15;
  int bid = blockIdx.x;
  int jj = bid >> 3, xx = bid & 7;
  int h  = xx + 8 * (jj >> 4);   // bh = b*8 + head  (0..15)
  int sl = jj & 15;              // INNER slice (0..15)
  int hh = h & 7;

  for (int i = tid; i < US_TOTAL; i += 256) lds[i] = 0;
  __syncthreads();

  float w1r[4][4][4];
#pragma unroll
  for (int a = 0; a < 4; a++)
#pragma unroll
    for (int nt = 0; nt < 4; nt++)
#pragma unroll
      for (int rr = 0; rr < 4; rr++)
        w1r[a][nt][rr] = W1g[((size_t)hh * 256 + (4 * w + a) * 16 + qd * 4 + rr) * 1024
                             + sl * 64 + nt * 16 + lm];
  float w2r[16][4];
#pragma unroll
  for (int nt = 0; nt < 16; nt++)
#pragma unroll
    for (int rr = 0; rr < 4; rr++)
      w2r[nt][rr] = W2g[((size_t)hh * 1024 + sl * 64 + w * 16 + qd * 4 + rr) * 256
                        + nt * 16 + lm];
  if (tid < 64)  ldsf[tid] = b1g[hh * 1024 + sl * 64 + tid];
  if (tid < 256){
    ldsf[64 + tid] = b2g[hh * 256 + tid];
    lds[O_GW + tid] = f2bf(gwg[hh * 256 + tid]);
    lds[O_GB + tid] = f2bf(gbg[hh * 256 + tid]);
  }

#define WRITE_W1BF() do { \
  _Pragma("unroll") for (int a = 0; a < 4; a++){ \
    int m0i = (4 * w + a) * 16 + qd * 4; \
    _Pragma("unroll") for (int nt = 0; nt < 4; nt++){ \
      int n = nt * 16 + lm; \
      unsigned int p0 = f2bf(w1r[a][nt][0]) | ((unsigned int)f2bf(w1r[a][nt][1]) << 16); \
      unsigned int p1 = f2bf(w1r[a][nt][2]) | ((unsigned int)f2bf(w1r[a][nt][3]) << 16); \
      *(unsigned int*)&lds[O_W1BT + n * 264 + m0i]     = p0; \
      *(unsigned int*)&lds[O_W1BT + n * 264 + m0i + 2] = p1; \
    } } } while(0)

#define WRITE_W2BF() do { \
  int mB = w * 16 + qd * 4; \
  _Pragma("unroll") for (int nt = 0; nt < 16; nt++){ \
    int n = nt * 16 + lm; \
    _Pragma("unroll") for (int rr = 0; rr < 4; rr++) \
      lds[O_W2K + (mB + rr) * 264 + n] = f2bf(w2r[nt][rr]); \
    unsigned int p0 = f2bf(w2r[nt][0]) | ((unsigned int)f2bf(w2r[nt][1]) << 16); \
    unsigned int p1 = f2bf(w2r[nt][2]) | ((unsigned int)f2bf(w2r[nt][3]) << 16); \
    *(unsigned int*)&lds[O_W2N + n * 72 + mB]     = p0; \
    *(unsigned int*)&lds[O_W2N + n * 72 + mB + 2] = p1; \
  } } while(0)

  const size_t hb2 = (size_t)h * 400 * 256;

  // coalesced bf16 load of xk + tgt(=xv-xk) + xk^T copy
#define LOAD_XK_TGT(NCH) do { \
  const unsigned int* kp = (const unsigned int*)(kg + hb2 + (size_t)(NCH) * 2560); \
  const unsigned int* vp = (const unsigned int*)(vg + hb2 + (size_t)(NCH) * 2560); \
  _Pragma("unroll") for (int i5 = 0; i5 < 5; i5++){ \
    int f2i = i5 * 256 + tid; \
    unsigned int ku = kp[f2i], vu = vp[f2i]; \
    int row = f2i >> 7, col = (f2i & 127) * 2; \
    *(unsigned int*)&lds[O_XKQ + row * 264 + col] = ku; \
    lds[O_XKT + col * 24 + row]       = (unsigned short)(ku & 0xffffu); \
    lds[O_XKT + (col + 1) * 24 + row] = (unsigned short)(ku >> 16); \
    float kv0 = bf2f((unsigned short)(ku & 0xffffu)), kv1 = bf2f((unsigned short)(ku >> 16)); \
    float vv0 = bf2f((unsigned short)(vu & 0xffffu)), vv1 = bf2f((unsigned short)(vu >> 16)); \
    unsigned int tu = (unsigned int)f2bf(vv0 - kv0) | ((unsigned int)f2bf(vv1 - kv1) << 16); \
    *(unsigned int*)&lds[O_TGT + row * 256 + col] = tu; \
  } } while(0)

  WRITE_W1BF();
  WRITE_W2BF();
  LOAD_XK_TGT(0);
  __syncthreads();

  for (int nch = 0; nch < 40; nch++){
    const size_t chunkBase = (size_t)(h * 40 + nch) * 10 * 256;

    // 2. Z1 slice = xk @ W1s
    f32x4 z1a; z1a[0]=0.f; z1a[1]=0.f; z1a[2]=0.f; z1a[3]=0.f;
#pragma unroll
    for (int ks = 0; ks < 8; ks++){
      bf16x8 av = *(const bf16x8*)&lds[O_XKQ + lm * 264 + ks * 32 + qd * 8];
      bf16x8 bv = *(const bf16x8*)&lds[O_W1BT + (w * 16 + lm) * 264 + ks * 32 + qd * 8];
      z1a = __builtin_amdgcn_mfma_f32_16x16x32_bf16(av, bv, z1a, 0, 0, 0);
    }
    float z1v[4];
    {
      float b1n = ldsf[w * 16 + lm];
#pragma unroll
      for (int rr = 0; rr < 4; rr++){
        z1v[rr] = z1a[rr] + b1n;
        int mr = qd * 4 + rr;
        if (mr < 10){
          float a1 = gelu_f(z1v[rr]);
          unsigned short ab = f2bf(a1);
          lds[O_A1 + mr * 72 + w * 16 + lm] = ab;
          lds[O_A1T + (w * 16 + lm) * 40 + mr] = ab;
        }
      }
    }
    __syncthreads();

    // 4. Z2 partial = A1s @ W2s -> atomicAdd into per-chunk accumulator
#pragma unroll
    for (int nt4 = 0; nt4 < 4; nt4++){
      int nt = 4 * w + nt4;
      f32x4 p; p[0]=0.f; p[1]=0.f; p[2]=0.f; p[3]=0.f;
#pragma unroll
      for (int ks = 0; ks < 2; ks++){
        bf16x8 av = *(const bf16x8*)&lds[O_A1 + lm * 72 + ks * 32 + qd * 8];
        bf16x8 bv = *(const bf16x8*)&lds[O_W2N + (nt * 16 + lm) * 72 + ks * 32 + qd * 8];
        p = __builtin_amdgcn_mfma_f32_16x16x32_bf16(av, bv, p, 0, 0, 0);
      }
#pragma unroll
      for (int rr = 0; rr < 4; rr++){
        int mr = qd * 4 + rr;
        if (mr < 10)
          aadd(&z2acc[chunkBase + (size_t)mr * 256 + nt * 16 + lm], p[rr]);
      }
    }

    // 4b. prefetch xq (overlaps barrier wait)
    {
      const unsigned int* qp = (const unsigned int*)(qg + hb2 + (size_t)nch * 2560);
#pragma unroll
      for (int i5 = 0; i5 < 5; i5++){
        int f2i = i5 * 256 + tid;
        unsigned int qu = qp[f2i];
        int row = f2i >> 7, col = (f2i & 127) * 2;
        *(unsigned int*)&lds[O_XQ2 + row * 264 + col] = qu;
      }
    }

    // 5. per-head barrier
    __syncthreads();
    if (tid == 0){
      __hip_atomic_fetch_add(bar + h * BAR_STRIDE, 1u, __ATOMIC_RELAXED, __HIP_MEMORY_SCOPE_AGENT);
      unsigned int target = 16u * (unsigned int)(nch + 1);
      unsigned int spins = 0;
      while (__hip_atomic_load(bar + h * BAR_STRIDE, __ATOMIC_RELAXED, __HIP_MEMORY_SCOPE_AGENT) < target
             && spins < 8000000u){ spins++; __builtin_amdgcn_s_sleep(1); }
    }
    __syncthreads();

    // 7. gZ2 (fused LN-L2 backward) from reduced Z2, redundantly per WG
    for (int r2 = w; r2 < 10; r2 += 4){
      int c0 = l * 4;
      const float* bp = &z2acc[chunkBase + (size_t)r2 * 256 + c0];
      float2 u01 = aload2(bp);
      float2 u23 = aload2(bp + 2);
      float zz[4] = {u01.x, u01.y, u23.x, u23.y};
      float s1 = 0.f, s2 = 0.f;
#pragma unroll
      for (int i = 0; i < 4; i++){ zz[i] += ldsf[64 + c0 + i]; s1 += zz[i]; s2 += zz[i] * zz[i]; }
#pragma unroll
      for (int off = 32; off >= 1; off >>= 1){ s1 += __shfl_xor(s1, off, 64); s2 += __shfl_xor(s2, off, 64); }
      float mu = s1 * (1.f / 256.f);
      float var = s2 * (1.f / 256.f) - mu * mu;
      float rstd = rsqrtf(var + 1e-6f);
      float xh[4], gx[4];
      float t1 = 0.f, t2 = 0.f;
#pragma unroll
      for (int i = 0; i < 4; i++){
        xh[i] = (zz[i] - mu) * rstd;
        float gwv = bf2f(lds[O_GW + c0 + i]), gbv = bf2f(lds[O_GB + c0 + i]);
        float tg = bf2f(lds[O_TGT + r2 * 256 + c0 + i]);
        float go = gwv * xh[i] + gbv - tg;
        gx[i] = go * gwv;
        t1 += gx[i]; t2 += gx[i] * xh[i];
      }
#pragma unroll
      for (int off = 32; off >= 1; off >>= 1){ t1 += __shfl_xor(t1, off, 64); t2 += __shfl_xor(t2, off, 64); }
      float m1 = t1 * (1.f / 256.f), m2 = t2 * (1.f / 256.f);
      float g0 = (gx[0] - m1 - xh[0] * m2) * rstd;
      float g1 = (gx[1] - m1 - xh[1] * m2) * rstd;
      float g2 = (gx[2] - m1 - xh[2] * m2) * rstd;
      float g3 = (gx[3] - m1 - xh[3] * m2) * rstd;
      unsigned int p0 = f2bf(g0) | ((unsigned int)f2bf(g1) << 16);
      unsigned int p1 = f2bf(g2) | ((unsigned int)f2bf(g3) << 16);
      *(unsigned int*)&lds[O_GZ2 + r2 * 264 + c0]     = p0;
      *(unsigned int*)&lds[O_GZ2 + r2 * 264 + c0 + 2] = p1;
    }
    __syncthreads();

    // 9a. b2 -= eta * sum_rows(gZ2); also build gZ2^T for the dW2 MFMA
    {
      float sum = 0.f;
#pragma unroll
      for (int r2 = 0; r2 < 10; r2++){
        unsigned short g = lds[O_GZ2 + r2 * 264 + tid];
        lds[O_GZ2T + tid * 24 + r2] = g;
        sum += bf2f(g);
      }
      ldsf[64 + tid] -= ETA * sum;
    }
    // 9b. gZ1 slice = (gZ2 @ W2s^T) * gelu'(Z1)
    {
      f32x4 g1a; g1a[0]=0.f; g1a[1]=0.f; g1a[2]=0.f; g1a[3]=0.f;
#pragma unroll
      for (int ks = 0; ks < 8; ks++){
        bf16x8 av = *(const bf16x8*)&lds[O_GZ2 + lm * 264 + ks * 32 + qd * 8];
        bf16x8 bv = *(const bf16x8*)&lds[O_W2K + (w * 16 + lm) * 264 + ks * 32 + qd * 8];
        g1a = __builtin_amdgcn_mfma_f32_16x16x32_bf16(av, bv, g1a, 0, 0, 0);
      }
#pragma unroll
      for (int rr = 0; rr < 4; rr++){
        int mr = qd * 4 + rr;
        if (mr < 10){
          float gz1 = g1a[rr] * gelu_bwd_f(z1v[rr]);
          lds[O_GZ1 + (w * 16 + lm) * 32 + mr] = f2bf(gz1);
        }
      }
    }
    __syncthreads();

    // 11a. b1 -= eta * colsum(gZ1)
    if (tid < 64){
      float sum = 0.f;
#pragma unroll
      for (int kx = 0; kx < 10; kx++) sum += bf2f(lds[O_GZ1 + tid * 32 + kx]);
      ldsf[tid] -= ETA * sum;
    }
    // 11b. W1 update: dW1 = xk^T @ gZ1  (A b128 from XKT; junk k>=16 nulled by GZ1 zeros)
#pragma unroll
    for (int a = 0; a < 4; a++){
      int mt = 4 * w + a;
      bf16x8 av = *(const bf16x8*)&lds[O_XKT + (mt * 16 + lm) * 24 + (qd & 1) * 8];
#pragma unroll
      for (int nt = 0; nt < 4; nt++){
        bf16x8 bv = *(const bf16x8*)&lds[O_GZ1 + (nt * 16 + lm) * 32 + qd * 8];
        f32x4 d; d[0]=0.f; d[1]=0.f; d[2]=0.f; d[3]=0.f;
        d = __builtin_amdgcn_mfma_f32_16x16x32_bf16(av, bv, d, 0, 0, 0);
#pragma unroll
        for (int rr = 0; rr < 4; rr++) w1r[a][nt][rr] -= ETA * d[rr];
      }
    }
    // 11c. W2 update: dW2 = A1^T @ gZ2  (B b128 from GZ2T; junk k>=10 nulled by A1T zeros)
    {
      bf16x8 av2 = *(const bf16x8*)&lds[O_A1T + (w * 16 + lm) * 40 + qd * 8];
#pragma unroll
      for (int nt = 0; nt < 16; nt++){
        bf16x8 bv = *(const bf16x8*)&lds[O_GZ2T + (nt * 16 + lm) * 24 + (qd & 1) * 8];
        f32x4 d; d[0]=0.f; d[1]=0.f; d[2]=0.f; d[3]=0.f;
        d = __builtin_amdgcn_mfma_f32_16x16x32_bf16(av2, bv, d, 0, 0, 0);
#pragma unroll
        for (int rr = 0; rr < 4; rr++) w2r[nt][rr] -= ETA * d[rr];
      }
    }
    WRITE_W1BF();
    WRITE_W2BF();
    __syncthreads();

    // prefetch next chunk's xk/tgt (XKQ/TGT/XKT dead until next iteration)
    if (nch + 1 < 40) LOAD_XK_TGT(nch + 1);

    // 15. Z1q = xq @ W1_new + b1_new -> A1q
    {
      f32x4 zq; zq[0]=0.f; zq[1]=0.f; zq[2]=0.f; zq[3]=0.f;
#pragma unroll
      for (int ks = 0; ks < 8; ks++){
        bf16x8 av = *(const bf16x8*)&lds[O_XQ2 + lm * 264 + ks * 32 + qd * 8];
        bf16x8 bv = *(const bf16x8*)&lds[O_W1BT + (w * 16 + lm) * 264 + ks * 32 + qd * 8];
        zq = __builtin_amdgcn_mfma_f32_16x16x32_bf16(av, bv, zq, 0, 0, 0);
      }
      float b1n = ldsf[w * 16 + lm];
#pragma unroll
      for (int rr = 0; rr < 4; rr++){
        int mr = qd * 4 + rr;
        if (mr < 10)
          lds[O_A1 + mr * 72 + w * 16 + lm] = f2bf(gelu_f(zq[rr] + b1n));
      }
    }
    __syncthreads();

    // 17. Z2q partial = A1q @ W2_new -> plain bf16 stores to own slice buffer
    {
      unsigned short* zq_out = zqp + ((size_t)(h * 16 + sl) * 40 + nch) * 2560;
#pragma unroll
      for (int nt4 = 0; nt4 < 4; nt4++){
        int nt = 4 * w + nt4;
        f32x4 p; p[0]=0.f; p[1]=0.f; p[2]=0.f; p[3]=0.f;
#pragma unroll
        for (int ks = 0; ks < 2; ks++){
          bf16x8 av = *(const bf16x8*)&lds[O_A1 + lm * 72 + ks * 32 + qd * 8];
          bf16x8 bv = *(const bf16x8*)&lds[O_W2N + (nt * 16 + lm) * 72 + ks * 32 + qd * 8];
          p = __builtin_amdgcn_mfma_f32_16x16x32_bf16(av, bv, p, 0, 0, 0);
        }
        float bb = (sl == 0) ? ldsf[64 + nt * 16 + lm] : 0.f;
#pragma unroll
        for (int rr = 0; rr < 4; rr++){
          int mr = qd * 4 + rr;
          if (mr < 10)
            zq_out[mr * 256 + nt * 16 + lm] = f2bf(p[rr] + bb);
        }
      }
    }
    __syncthreads();
  }
}

// ---------------------------------------------------------------------------
// LN forward + residual; sums 16 bf16 slice partials of Z2q in fp32.
// ---------------------------------------------------------------------------
__global__ __launch_bounds__(256) void k_lnout(
    const unsigned short* __restrict__ zqp, const unsigned short* __restrict__ qg,
    const float* __restrict__ gwg, const float* __restrict__ gbg,
    unsigned short* __restrict__ obf)
{
  int w = threadIdx.x >> 6, l = threadIdx.x & 63;
  int gr = blockIdx.x * 4 + w;
  int h = gr / 400, t = gr % 400, hh = h & 7, b = h >> 3;
  int nch = t / 10, mr = t % 10;
  int c0 = l * 4;
  float z[4] = {0.f, 0.f, 0.f, 0.f};
#pragma unroll
  for (int sl = 0; sl < 16; sl++){
    const unsigned short* zp = zqp + (((size_t)(h * 16 + sl) * 40 + nch) * 10 + mr) * 256 + c0;
    ushort4 u = *(const ushort4*)zp;
    z[0] += bf2f(u.x); z[1] += bf2f(u.y); z[2] += bf2f(u.z); z[3] += bf2f(u.w);
  }
  float s1 = 0.f, s2 = 0.f;
#pragma unroll
  for (int i = 0; i < 4; i++){ s1 += z[i]; s2 += z[i] * z[i]; }
#pragma unroll
  for (int off = 32; off >= 1; off >>= 1){ s1 += __shfl_xor(s1, off, 64); s2 += __shfl_xor(s2, off, 64); }
  float mu = s1 * (1.f / 256.f);
  float var = s2 * (1.f / 256.f) - mu * mu;
  float rstd = rsqrtf(var + 1e-6f);
  const unsigned short* qp = &qg[((size_t)h * 400 + t) * 256];
  ushort4 qu = *(const ushort4*)&qp[c0];
  float qv[4] = {bf2f(qu.x), bf2f(qu.y), bf2f(qu.z), bf2f(qu.w)};
  unsigned short* op = &obf[((size_t)(b * 400 + t)) * 2048 + hh * 256];
#pragma unroll
  for (int i = 0; i < 4; i++){
    float xh = (z[i] - mu) * rstd;
    float o = qv[i] + gwg[hh * 256 + c0 + i] * xh + gbg[hh * 256 + c0 + i];
    op[c0 + i] = f2bf(o);
  }
}

// ---------------------------------------------------------------------------
// launch — workspace map (bytes), total 85.7 MB
// ---------------------------------------------------------------------------
#define WS_WEFF   0u          // bf16 [2048][7744] (dead after gemm0) | zqp 52.4MB alias
#define WS_P      31719424u   // bf16 [800][7744]  (dead after gemm0)
#define WS_WQKV   44109824u   // bf16 [6144][2048] (dead after gemm1)
#define WS_WOB    52428800u   // bf16 [2048][2048] (written after gemm1)
#define WS_Z2ACC  62722048u   // f32 6.55MB | g2part 13.1MB (post-lnout, spans xb+q)
#define WS_XB     69275648u   // bf16 [800][2048]
#define WS_Q      72552448u   // bf16 [16][400][256] | g0part 13.1MB (pre-gemm1, spans q..obf)
#define WS_K      75829248u
#define WS_V      79106048u
#define WS_OBF    82382848u   // bf16 [800][2048]
#define WS_BSUM   85659648u
#define WS_BAR    85667840u

extern "C" void kernel_launch(void* const* d_in, const int* in_sizes, int n_in,
                              void* d_out, int out_size, void* d_ws, size_t ws_size,
                              hipStream_t stream)
{
  (void)in_sizes; (void)n_in; (void)out_size; (void)ws_size;
  const float* x  = (const float*)d_in[0];
  const float* cw[6]; const float* cb[6];
  for (int i = 0; i < 6; i++){ cw[i] = (const float*)d_in[2 + 2 * i]; cb[i] = (const float*)d_in[3 + 2 * i]; }
  const float* wq  = (const float*)d_in[14];
  const float* wk  = (const float*)d_in[15];
  const float* wv  = (const float*)d_in[16];
  const float* wo  = (const float*)d_in[17];
  const float* W1  = (const float*)d_in[18];
  const float* b1  = (const float*)d_in[19];
  const float* W2  = (const float*)d_in[20];
  const float* b2  = (const float*)d_in[21];
  const float* lnw = (const float*)d_in[22];
  const float* lnb = (const float*)d_in[23];
  float* outf = (float*)d_out;

  char* wsb = (char*)d_ws;
  unsigned short* weff = (unsigned short*)(wsb + WS_WEFF);
  unsigned short* P    = (unsigned short*)(wsb + WS_P);
  unsigned short* wqkv = (unsigned short*)(wsb + WS_WQKV);
  unsigned short* wob  = (unsigned short*)(wsb + WS_WOB);
  unsigned short* xb   = (unsigned short*)(wsb + WS_XB);
  unsigned short* qb   = (unsigned short*)(wsb + WS_Q);
  unsigned short* kb   = (unsigned short*)(wsb + WS_K);
  unsigned short* vb   = (unsigned short*)(wsb + WS_V);
  float* z2acc = (float*)(wsb + WS_Z2ACC);
  unsigned short* zqp = (unsigned short*)(wsb + WS_WEFF);   // 52.4 MB alias
  unsigned short* obf = (unsigned short*)(wsb + WS_OBF);
  float* bsum = (float*)(wsb + WS_BSUM);
  unsigned int* bar = (unsigned int*)(wsb + WS_BAR);
  float* g0part = (float*)(wsb + WS_Q);
  float* g2part = (float*)(wsb + WS_Z2ACC);

  hipMemsetAsync(bar, 0, 16 * BAR_STRIDE * 4, stream);
  hipFuncSetAttribute(reinterpret_cast<const void*>(k_ttt),
                      hipFuncAttributeMaxDynamicSharedMemorySize, TTT_LDS_BYTES);
  hipFuncSetAttribute(reinterpret_cast<const void*>(k_weff),
                      hipFuncAttributeMaxDynamicSharedMemorySize, 18304 * 4);

  k_weff<<<2048, 256, 18304 * 4, stream>>>(cw[0], cw[1], cw[2], cw[3], cw[4], cw[5], weff);
  k_im2col<<<(800 * 7744 + 255) / 256, 256, 0, stream>>>(x, P);
  k_wqkv<<<(6144 * 2048 + 255) / 256, 256, 0, stream>>>(wq, wk, wv, wqkv);
  k_bsum<<<8, 256, 0, stream>>>(cb[0], cb[1], cb[2], cb[3], cb[4], cb[5], bsum);

  // conv-as-GEMM, K-split x2 -> fp32 partials -> silu combine
  k_gemm<2><<<dim3(16, 7, 2), 256, 0, stream>>>(weff, P, 2048, 800, 7744, 7744, 3872,
                                                nullptr, nullptr, nullptr, g0part);
  k_comb_silu<<<1600, 256, 0, stream>>>(g0part, g0part + 1638400, bsum, xb);

  // QKV projection -> bf16 per-head buffers
  k_gemm<1><<<dim3(48, 7, 1), 256, 0, stream>>>(wqkv, xb, 6144, 800, 2048, 2048, 2048,
                                                qb, kb, vb, nullptr);

  k_f2bf_copy<<<(2048 * 2048 + 255) / 256, 256, 0, stream>>>(wo, wob, 2048 * 2048);
  hipMemsetAsync(z2acc, 0, 16 * 40 * 10 * 256 * 4, stream);

  k_ttt<<<256, 256, TTT_LDS_BYTES, stream>>>(qb, kb, vb, W1, b1, W2, b2, lnw, lnb,
                                             z2acc, zqp, bar);
  k_lnout<<<1600, 256, 0, stream>>>(zqp, qb, lnw, lnb, obf);

  // output projection, K-split x2 -> combine into d_out
  k_gemm<2><<<dim3(16, 7, 2), 256, 0, stream>>>(wob, obf, 2048, 800, 2048, 2048, 1024,
                                                nullptr, nullptr, nullptr, g2part);
  k_comb_add<<<1600, 256, 0, stream>>>(g2part, g2part + 1638400, outf);
}

// Round 7
// 1100.588 us; speedup vs baseline: 2.9619x; 1.0271x over previous
//
#include <hip/hip_runtime.h>

// ---------------------------------------------------------------------------
// Branch_62989990363328: TimesBlock conv ensemble -> TTT-MLP -> out proj
// B=2 T=400 C=64 OUT=2048 NH=8 HD=256 INNER=1024 MB=10 NC=40
// R7: query-output phase deferred one chunk into the barrier-wait slot
//     (add -> fill(Z1q/Z2q of prev chunk, xq reload) -> poll); gemm2 K-split 4.
// ---------------------------------------------------------------------------

typedef __bf16 bf16x8 __attribute__((ext_vector_type(8)));
typedef float  f32x4  __attribute__((ext_vector_type(4)));

__device__ __forceinline__ unsigned short f2bf(float f){
  unsigned int u = __builtin_bit_cast(unsigned int, f);
  u += 0x7fffu + ((u >> 16) & 1u);
  return (unsigned short)(u >> 16);
}
__device__ __forceinline__ float bf2f(unsigned short b){
  unsigned int u = ((unsigned int)b) << 16;
  return __builtin_bit_cast(float, u);
}
__device__ __forceinline__ float gelu_f(float x){
  return 0.5f * x * (1.0f + erff(x * 0.70710678118654752f));
}
__device__ __forceinline__ float gelu_bwd_f(float x){
  return 0.5f * (1.0f + erff(x * 0.70710678118654752f))
       + x * __expf(-0.5f * x * x) * 0.3989422804014327f;
}

// agent-scope relaxed atomic helpers (MALL-coherent, bypass L1/L2)
__device__ __forceinline__ float2 aload2(const float* p){
  unsigned long long v = __hip_atomic_load((const unsigned long long*)p,
                                           __ATOMIC_RELAXED, __HIP_MEMORY_SCOPE_AGENT);
  union { unsigned long long u; float2 f; } cv; cv.u = v; return cv.f;
}
__device__ __forceinline__ void aadd(float* p, float v){
  __hip_atomic_fetch_add(p, v, __ATOMIC_RELAXED, __HIP_MEMORY_SCOPE_AGENT);
}

// ---------------------------------------------------------------------------
// Prep kernels
// ---------------------------------------------------------------------------

__global__ __launch_bounds__(256) void k_weff(
    const float* __restrict__ w0, const float* __restrict__ w1,
    const float* __restrict__ w2, const float* __restrict__ w3,
    const float* __restrict__ w4, const float* __restrict__ w5,
    unsigned short* __restrict__ weff)
{
  extern __shared__ float sw[];   // 18304 floats
  const int off[6] = {0, 64, 640, 2240, 5376, 10560};
  const float* ws6[6] = {w0, w1, w2, w3, w4, w5};
  int o = blockIdx.x, tid = threadIdx.x;
#pragma unroll
  for (int i = 0; i < 6; i++){
    int kk = 2 * i + 1, sz = 64 * kk * kk;
    const float* src = ws6[i] + (size_t)o * sz;
    for (int idx = tid; idx < sz; idx += 256) sw[off[i] + idx] = src[idx];
  }
  __syncthreads();
  for (int t = tid; t < 7744; t += 256){
    int c = t / 121, dd = t % 121, di = dd / 11, dj = dd % 11;
    float s = 0.f;
#pragma unroll
    for (int i = 0; i < 6; i++){
      int kk = 2 * i + 1;
      int a = di - 5 + i, b = dj - 5 + i;
      if (a >= 0 && a < kk && b >= 0 && b < kk)
        s += sw[off[i] + (c * kk + a) * kk + b];
    }
    weff[(size_t)o * 7744 + t] = f2bf(s);
  }
}

__global__ __launch_bounds__(256) void k_im2col(
    const float* __restrict__ x, unsigned short* __restrict__ P)
{
  int idx = blockIdx.x * 256 + threadIdx.x;
  if (idx >= 800 * 7744) return;
  int n = idx / 7744, k = idx % 7744;
  int c = k / 121, dd = k % 121, di = dd / 11, dj = dd % 11;
  int b = n / 400, pos = n % 400, i = pos / 20, j = pos % 20;
  int ii = i + di - 5, jj = j + dj - 5;
  float v = 0.f;
  if (ii >= 0 && ii < 20 && jj >= 0 && jj < 20)
    v = x[((size_t)b * 400 + ii * 20 + jj) * 64 + c];
  P[idx] = f2bf(v);
}

__global__ __launch_bounds__(256) void k_wqkv(
    const float* __restrict__ wq, const float* __restrict__ wk,
    const float* __restrict__ wv, unsigned short* __restrict__ dst)
{
  int idx = blockIdx.x * 256 + threadIdx.x;
  if (idx >= 6144 * 2048) return;
  int m = idx >> 11, kk = idx & 2047;
  const float* src = (m < 2048) ? wq : ((m < 4096) ? wk : wv);
  dst[idx] = f2bf(src[(size_t)(m & 2047) * 2048 + kk]);
}

__global__ __launch_bounds__(256) void k_f2bf_copy(
    const float* __restrict__ src, unsigned short* __restrict__ dst, int n)
{
  int idx = blockIdx.x * 256 + threadIdx.x;
  if (idx < n) dst[idx] = f2bf(src[idx]);
}

__global__ __launch_bounds__(256) void k_bsum(
    const float* __restrict__ b0, const float* __restrict__ b1,
    const float* __restrict__ b2, const float* __restrict__ b3,
    const float* __restrict__ b4, const float* __restrict__ b5,
    float* __restrict__ bsum)
{
  int idx = blockIdx.x * 256 + threadIdx.x;
  if (idx < 2048)
    bsum[idx] = b0[idx] + b1[idx] + b2[idx] + b3[idx] + b4[idx] + b5[idx];
}

__global__ __launch_bounds__(256) void k_comb_silu(
    const float* __restrict__ p0, const float* __restrict__ p1,
    const float* __restrict__ bsum, unsigned short* __restrict__ xb)
{
  int i4 = (blockIdx.x * 256 + threadIdx.x) * 4;
  float4 a = *(const float4*)&p0[i4];
  float4 b = *(const float4*)&p1[i4];
  int mm = i4 & 2047;
  float4 bs = *(const float4*)&bsum[mm];
  float v[4] = {a.x + b.x + bs.x, a.y + b.y + bs.y, a.z + b.z + bs.z, a.w + b.w + bs.w};
  ushort4 o;
#pragma unroll
  for (int i = 0; i < 4; i++){
    float t = v[i] * (1.0f / 6.0f);
    float sv = t / (1.0f + __expf(-t));
    ((unsigned short*)&o)[i] = f2bf(sv);
  }
  *(ushort4*)&xb[i4] = o;
}

__global__ __launch_bounds__(256) void k_comb_add4(
    const float* __restrict__ p, float* __restrict__ out)
{
  int i4 = (blockIdx.x * 256 + threadIdx.x) * 4;
  float4 a = *(const float4*)&p[i4];
  float4 b = *(const float4*)&p[1638400 + i4];
  float4 c = *(const float4*)&p[3276800 + i4];
  float4 d = *(const float4*)&p[4915200 + i4];
  float4 o = {a.x + b.x + c.x + d.x, a.y + b.y + c.y + d.y,
              a.z + b.z + c.z + d.z, a.w + b.w + c.w + d.w};
  *(float4*)&out[i4] = o;
}

// ---------------------------------------------------------------------------
// Generic bf16 MFMA GEMM: C[M][N] = A[M][K] * B[N][K]^T, K-split via z.
// ---------------------------------------------------------------------------
template<int MODE>
__global__ __launch_bounds__(256, 1) void k_gemm(
    const unsigned short* __restrict__ A, const unsigned short* __restrict__ B,
    int M, int N, int lda, int ldb, int kLen,
    unsigned short* __restrict__ qb, unsigned short* __restrict__ kb,
    unsigned short* __restrict__ vb, float* __restrict__ outf)
{
  __shared__ unsigned short As[128 * 32];
  __shared__ unsigned short Bs[128 * 32];
  int tid = threadIdx.x, w = tid >> 6, l = tid & 63, qd = l >> 4, lm = l & 15;
  int m0 = blockIdx.x * 128, n0 = blockIdx.y * 128;
  int kBase = blockIdx.z * kLen;

  f32x4 acc[4][4];
#pragma unroll
  for (int i = 0; i < 4; i++)
#pragma unroll
    for (int j = 0; j < 4; j++){ acc[i][j][0]=0.f; acc[i][j][1]=0.f; acc[i][j][2]=0.f; acc[i][j][3]=0.f; }

  int nk = kLen >> 5;
  for (int kt = 0; kt < nk; kt++){
    int k0 = kBase + (kt << 5);
#pragma unroll
    for (int i = 0; i < 2; i++){
      int cidx = tid + i * 256;
      int row = cidx >> 2, kc = (cidx & 3) << 3;
      *(uint4*)&As[row * 32 + kc] = *(const uint4*)&A[(size_t)(m0 + row) * lda + k0 + kc];
      int br = n0 + row; if (br >= N) br = N - 1;
      *(uint4*)&Bs[row * 32 + kc] = *(const uint4*)&B[(size_t)br * ldb + k0 + kc];
    }
    __syncthreads();
    bf16x8 af[4], bfv[4];
#pragma unroll
    for (int i = 0; i < 4; i++)
      af[i] = *(const bf16x8*)&As[((w >> 1) * 64 + i * 16 + lm) * 32 + qd * 8];
#pragma unroll
    for (int j = 0; j < 4; j++)
      bfv[j] = *(const bf16x8*)&Bs[((w & 1) * 64 + j * 16 + lm) * 32 + qd * 8];
#pragma unroll
    for (int i = 0; i < 4; i++)
#pragma unroll
      for (int j = 0; j < 4; j++)
        acc[i][j] = __builtin_amdgcn_mfma_f32_16x16x32_bf16(af[i], bfv[j], acc[i][j], 0, 0, 0);
    __syncthreads();
  }

#pragma unroll
  for (int i = 0; i < 4; i++){
    int mBase = m0 + (w >> 1) * 64 + i * 16 + qd * 4;
#pragma unroll
    for (int j = 0; j < 4; j++){
      int n = n0 + (w & 1) * 64 + j * 16 + lm;
      if (n < N){
#pragma unroll
        for (int rr = 0; rr < 4; rr++){
          float val = acc[i][j][rr];
          int mm = mBase + rr;
          if (MODE == 1){
            int proj = mm >> 11, o = mm & 2047, hh = o >> 8, d = o & 255;
            int bh = (n / 400) * 8 + hh, tt = n % 400;
            unsigned short* dst = (proj == 0) ? qb : ((proj == 1) ? kb : vb);
            dst[((size_t)bh * 400 + tt) * 256 + d] = f2bf(val);
          } else {
            outf[(size_t)blockIdx.z * M * N + (size_t)n * M + mm] = val;
          }
        }
      }
    }
  }
}

// ---------------------------------------------------------------------------
// TTT persistent kernel. 256 WGs: 16 heads x 16 INNER-slices (64 wide).
// Query-output phase deferred one chunk into the barrier-wait slot.
// LDS layout (ushort offsets; all b128 bases 8-aligned):
// ---------------------------------------------------------------------------
#define O_W1BT 0        // [64][264]  W1^T bf16 (inner, hd)
#define O_W2K  16896    // [64][264]  W2 bf16   (inner, hd)  - B for gZ1
#define O_W2N  33792    // [256][72]  W2^T bf16 (hd, inner)  - B for Z2
#define O_XKQ  52224    // [10][264]  xk bf16
#define O_TGT  54864    // [10][256]  (xv-xk) bf16
#define O_A1   57424    // [10][72]   A1 bf16
#define O_A1T  58144    // [64][32]   A1^T bf16 (cols>=10 zero - REQUIRED)
#define O_GZ2  60192    // [10][264]  gZ2 bf16
#define O_GZ1  62832    // [64][32]   gZ1 bf16 (cols>=10 zero - REQUIRED)
#define O_XQ2  64880    // [10][264]  xq bf16 (prev chunk's xq during fill)
#define O_GZ2T 67520    // [256][24]  gZ2^T bf16 (cols>=10 zero)
#define O_XKT  73664    // [256][24]  xk^T bf16
#define O_A1Q  79808    // [10][72]   A1q bf16 (fill phase)
#define O_F32  80528    // floats: b1s[64], b2[256]
#define O_GW   81168    // bf16[256]
#define O_GB   81424    // bf16[256]
#define US_TOTAL 81680
#define TTT_LDS_BYTES (81680 * 2)   // 163360 <= 163840

#define ETA 0.01f
#define BAR_STRIDE 32   // 128B per head counter

__global__ __launch_bounds__(256, 1) void k_ttt(
    const unsigned short* __restrict__ qg, const unsigned short* __restrict__ kg,
    const unsigned short* __restrict__ vg,
    const float* __restrict__ W1g, const float* __restrict__ b1g,
    const float* __restrict__ W2g, const float* __restrict__ b2g,
    const float* __restrict__ gwg, const float* __restrict__ gbg,
    float* __restrict__ z2acc, unsigned short* __restrict__ zqp,
    unsigned int* __restrict__ bar)
{
  extern __shared__ unsigned short lds[];
  float* ldsf = (float*)&lds[O_F32];

  int tid = threadIdx.x, w = tid >> 6, l = tid & 63, qd = l >> 4, lm = l & 15;
  int bid = blockIdx.x;
  int jj = bid >> 3, xx = bid & 7;
  int h  = xx + 8 * (jj >> 4);   // bh = b*8 + head  (0..15)
  int sl = jj & 15;              // INNER slice (0..15)
  int hh = h & 7;

  for (int i = tid; i < US_TOTAL; i += 256) lds[i] = 0;
  __syncthreads();

  float w1r[4][4][4];
#pragma unroll
  for (int a = 0; a < 4; a++)
#pragma unroll
    for (int nt = 0; nt < 4; nt++)
#pragma unroll
      for (int rr = 0; rr < 4; rr++)
        w1r[a][nt][rr] = W1g[((size_t)hh * 256 + (4 * w + a) * 16 + qd * 4 + rr) * 1024
                             + sl * 64 + nt * 16 + lm];
  float w2r[16][4];
#pragma unroll
  for (int nt = 0; nt < 16; nt++)
#pragma unroll
    for (int rr = 0; rr < 4; rr++)
      w2r[nt][rr] = W2g[((size_t)hh * 1024 + sl * 64 + w * 16 + qd * 4 + rr) * 256
                        + nt * 16 + lm];
  if (tid < 64)  ldsf[tid] = b1g[hh * 1024 + sl * 64 + tid];
  if (tid < 256){
    ldsf[64 + tid] = b2g[hh * 256 + tid];
    lds[O_GW + tid] = f2bf(gwg[hh * 256 + tid]);
    lds[O_GB + tid] = f2bf(gbg[hh * 256 + tid]);
  }

#define WRITE_W1BF() do { \
  _Pragma("unroll") for (int a = 0; a < 4; a++){ \
    int m0i = (4 * w + a) * 16 + qd * 4; \
    _Pragma("unroll") for (int nt = 0; nt < 4; nt++){ \
      int n = nt * 16 + lm; \
      unsigned int p0 = f2bf(w1r[a][nt][0]) | ((unsigned int)f2bf(w1r[a][nt][1]) << 16); \
      unsigned int p1 = f2bf(w1r[a][nt][2]) | ((unsigned int)f2bf(w1r[a][nt][3]) << 16); \
      *(unsigned int*)&lds[O_W1BT + n * 264 + m0i]     = p0; \
      *(unsigned int*)&lds[O_W1BT + n * 264 + m0i + 2] = p1; \
    } } } while(0)

#define WRITE_W2BF() do { \
  int mB = w * 16 + qd * 4; \
  _Pragma("unroll") for (int nt = 0; nt < 16; nt++){ \
    int n = nt * 16 + lm; \
    _Pragma("unroll") for (int rr = 0; rr < 4; rr++) \
      lds[O_W2K + (mB + rr) * 264 + n] = f2bf(w2r[nt][rr]); \
    unsigned int p0 = f2bf(w2r[nt][0]) | ((unsigned int)f2bf(w2r[nt][1]) << 16); \
    unsigned int p1 = f2bf(w2r[nt][2]) | ((unsigned int)f2bf(w2r[nt][3]) << 16); \
    *(unsigned int*)&lds[O_W2N + n * 72 + mB]     = p0; \
    *(unsigned int*)&lds[O_W2N + n * 72 + mB + 2] = p1; \
  } } while(0)

  const size_t hb2 = (size_t)h * 400 * 256;

#define LOAD_XK_TGT(NCH) do { \
  const unsigned int* kp = (const unsigned int*)(kg + hb2 + (size_t)(NCH) * 2560); \
  const unsigned int* vp = (const unsigned int*)(vg + hb2 + (size_t)(NCH) * 2560); \
  _Pragma("unroll") for (int i5 = 0; i5 < 5; i5++){ \
    int f2i = i5 * 256 + tid; \
    unsigned int ku = kp[f2i], vu = vp[f2i]; \
    int row = f2i >> 7, col = (f2i & 127) * 2; \
    *(unsigned int*)&lds[O_XKQ + row * 264 + col] = ku; \
    lds[O_XKT + col * 24 + row]       = (unsigned short)(ku & 0xffffu); \
    lds[O_XKT + (col + 1) * 24 + row] = (unsigned short)(ku >> 16); \
    float kv0 = bf2f((unsigned short)(ku & 0xffffu)), kv1 = bf2f((unsigned short)(ku >> 16)); \
    float vv0 = bf2f((unsigned short)(vu & 0xffffu)), vv1 = bf2f((unsigned short)(vu >> 16)); \
    unsigned int tu = (unsigned int)f2bf(vv0 - kv0) | ((unsigned int)f2bf(vv1 - kv1) << 16); \
    *(unsigned int*)&lds[O_TGT + row * 256 + col] = tu; \
  } } while(0)

#define LOAD_XQ(NCH) do { \
  const unsigned int* qp = (const unsigned int*)(qg + hb2 + (size_t)(NCH) * 2560); \
  _Pragma("unroll") for (int i5 = 0; i5 < 5; i5++){ \
    int f2i = i5 * 256 + tid; \
    unsigned int qu = qp[f2i]; \
    int row = f2i >> 7, col = (f2i & 127) * 2; \
    *(unsigned int*)&lds[O_XQ2 + row * 264 + col] = qu; \
  } } while(0)

  WRITE_W1BF();
  WRITE_W2BF();
  LOAD_XK_TGT(0);
  LOAD_XQ(0);
  __syncthreads();

  for (int nch = 0; nch < 40; nch++){
    const size_t chunkBase = (size_t)(h * 40 + nch) * 10 * 256;

    // 1. Z1 = xk@W1 + b1 -> A1 (uses W_{nch-1})
    f32x4 z1a; z1a[0]=0.f; z1a[1]=0.f; z1a[2]=0.f; z1a[3]=0.f;
#pragma unroll
    for (int ks = 0; ks < 8; ks++){
      bf16x8 av = *(const bf16x8*)&lds[O_XKQ + lm * 264 + ks * 32 + qd * 8];
      bf16x8 bv = *(const bf16x8*)&lds[O_W1BT + (w * 16 + lm) * 264 + ks * 32 + qd * 8];
      z1a = __builtin_amdgcn_mfma_f32_16x16x32_bf16(av, bv, z1a, 0, 0, 0);
    }
    float z1v[4];
    {
      float b1n = ldsf[w * 16 + lm];
#pragma unroll
      for (int rr = 0; rr < 4; rr++){
        z1v[rr] = z1a[rr] + b1n;
        int mr = qd * 4 + rr;
        if (mr < 10){
          float a1 = gelu_f(z1v[rr]);
          unsigned short ab = f2bf(a1);
          lds[O_A1 + mr * 72 + w * 16 + lm] = ab;
          lds[O_A1T + (w * 16 + lm) * 32 + mr] = ab;
        }
      }
    }
    __syncthreads();

    // 3. Z2 partial = A1@W2 -> atomicAdd into per-chunk accumulator
#pragma unroll
    for (int nt4 = 0; nt4 < 4; nt4++){
      int nt = 4 * w + nt4;
      f32x4 p; p[0]=0.f; p[1]=0.f; p[2]=0.f; p[3]=0.f;
#pragma unroll
      for (int ks = 0; ks < 2; ks++){
        bf16x8 av = *(const bf16x8*)&lds[O_A1 + lm * 72 + ks * 32 + qd * 8];
        bf16x8 bv = *(const bf16x8*)&lds[O_W2N + (nt * 16 + lm) * 72 + ks * 32 + qd * 8];
        p = __builtin_amdgcn_mfma_f32_16x16x32_bf16(av, bv, p, 0, 0, 0);
      }
#pragma unroll
      for (int rr = 0; rr < 4; rr++){
        int mr = qd * 4 + rr;
        if (mr < 10)
          aadd(&z2acc[chunkBase + (size_t)mr * 256 + nt * 16 + lm], p[rr]);
      }
    }
    __syncthreads();   // drain atomics (release)

    // 5. barrier add, then FILL the wait slot with prev chunk's query outputs
    if (tid == 0)
      __hip_atomic_fetch_add(bar + h * BAR_STRIDE, 1u, __ATOMIC_RELAXED, __HIP_MEMORY_SCOPE_AGENT);

    if (nch > 0){
      // Z1q_{nch-1} = xq_{nch-1}@W1_{nch-1} + b1_{nch-1} -> A1q  (W1BT = W_{nch-1})
      f32x4 zq; zq[0]=0.f; zq[1]=0.f; zq[2]=0.f; zq[3]=0.f;
#pragma unroll
      for (int ks = 0; ks < 8; ks++){
        bf16x8 av = *(const bf16x8*)&lds[O_XQ2 + lm * 264 + ks * 32 + qd * 8];
        bf16x8 bv = *(const bf16x8*)&lds[O_W1BT + (w * 16 + lm) * 264 + ks * 32 + qd * 8];
        zq = __builtin_amdgcn_mfma_f32_16x16x32_bf16(av, bv, zq, 0, 0, 0);
      }
      float b1n = ldsf[w * 16 + lm];
#pragma unroll
      for (int rr = 0; rr < 4; rr++){
        int mr = qd * 4 + rr;
        if (mr < 10)
          lds[O_A1Q + mr * 72 + w * 16 + lm] = f2bf(gelu_f(zq[rr] + b1n));
      }
    }
    __syncthreads();   // A1Q visible; XQ2 free

    if (nch > 0){
      LOAD_XQ(nch);    // overwrite with current chunk's xq (for next fill)
      // Z2q partial = A1q@W2_{nch-1} -> bf16 store (chunk nch-1)
      unsigned short* zq_out = zqp + ((size_t)(h * 16 + sl) * 40 + (nch - 1)) * 2560;
#pragma unroll
      for (int nt4 = 0; nt4 < 4; nt4++){
        int nt = 4 * w + nt4;
        f32x4 p; p[0]=0.f; p[1]=0.f; p[2]=0.f; p[3]=0.f;
#pragma unroll
        for (int ks = 0; ks < 2; ks++){
          bf16x8 av = *(const bf16x8*)&lds[O_A1Q + lm * 72 + ks * 32 + qd * 8];
          bf16x8 bv = *(const bf16x8*)&lds[O_W2N + (nt * 16 + lm) * 72 + ks * 32 + qd * 8];
          p = __builtin_amdgcn_mfma_f32_16x16x32_bf16(av, bv, p, 0, 0, 0);
        }
        float bb = (sl == 0) ? ldsf[64 + nt * 16 + lm] : 0.f;
#pragma unroll
        for (int rr = 0; rr < 4; rr++){
          int mr = qd * 4 + rr;
          if (mr < 10)
            zq_out[mr * 256 + nt * 16 + lm] = f2bf(p[rr] + bb);
        }
      }
    }

    // 6. poll (after fill — wait time absorbed by the fill work above)
    if (tid == 0){
      unsigned int target = 16u * (unsigned int)(nch + 1);
      unsigned int spins = 0;
      while (__hip_atomic_load(bar + h * BAR_STRIDE, __ATOMIC_RELAXED, __HIP_MEMORY_SCOPE_AGENT) < target
             && spins < 8000000u){ spins++; __builtin_amdgcn_s_sleep(1); }
    }
    __syncthreads();

    // 7. gZ2 (fused LN-L2 backward) from reduced Z2, redundantly per WG
    for (int r2 = w; r2 < 10; r2 += 4){
      int c0 = l * 4;
      const float* bp = &z2acc[chunkBase + (size_t)r2 * 256 + c0];
      float2 u01 = aload2(bp);
      float2 u23 = aload2(bp + 2);
      float zz[4] = {u01.x, u01.y, u23.x, u23.y};
      float s1 = 0.f, s2 = 0.f;
#pragma unroll
      for (int i = 0; i < 4; i++){ zz[i] += ldsf[64 + c0 + i]; s1 += zz[i]; s2 += zz[i] * zz[i]; }
#pragma unroll
      for (int off = 32; off >= 1; off >>= 1){ s1 += __shfl_xor(s1, off, 64); s2 += __shfl_xor(s2, off, 64); }
      float mu = s1 * (1.f / 256.f);
      float var = s2 * (1.f / 256.f) - mu * mu;
      float rstd = rsqrtf(var + 1e-6f);
      float xh[4], gx[4];
      float t1 = 0.f, t2 = 0.f;
#pragma unroll
      for (int i = 0; i < 4; i++){
        xh[i] = (zz[i] - mu) * rstd;
        float gwv = bf2f(lds[O_GW + c0 + i]), gbv = bf2f(lds[O_GB + c0 + i]);
        float tg = bf2f(lds[O_TGT + r2 * 256 + c0 + i]);
        float go = gwv * xh[i] + gbv - tg;
        gx[i] = go * gwv;
        t1 += gx[i]; t2 += gx[i] * xh[i];
      }
#pragma unroll
      for (int off = 32; off >= 1; off >>= 1){ t1 += __shfl_xor(t1, off, 64); t2 += __shfl_xor(t2, off, 64); }
      float m1 = t1 * (1.f / 256.f), m2 = t2 * (1.f / 256.f);
      float g0 = (gx[0] - m1 - xh[0] * m2) * rstd;
      float g1 = (gx[1] - m1 - xh[1] * m2) * rstd;
      float g2 = (gx[2] - m1 - xh[2] * m2) * rstd;
      float g3 = (gx[3] - m1 - xh[3] * m2) * rstd;
      unsigned int p0 = f2bf(g0) | ((unsigned int)f2bf(g1) << 16);
      unsigned int p1 = f2bf(g2) | ((unsigned int)f2bf(g3) << 16);
      *(unsigned int*)&lds[O_GZ2 + r2 * 264 + c0]     = p0;
      *(unsigned int*)&lds[O_GZ2 + r2 * 264 + c0 + 2] = p1;
    }
    __syncthreads();

    // 9a. b2 -= eta * sum_rows(gZ2); build gZ2^T
    {
      float sum = 0.f;
#pragma unroll
      for (int r2 = 0; r2 < 10; r2++){
        unsigned short g = lds[O_GZ2 + r2 * 264 + tid];
        lds[O_GZ2T + tid * 24 + r2] = g;
        sum += bf2f(g);
      }
      ldsf[64 + tid] -= ETA * sum;
    }
    // 9b. gZ1 = (gZ2 @ W2^T) * gelu'(Z1)
    {
      f32x4 g1a; g1a[0]=0.f; g1a[1]=0.f; g1a[2]=0.f; g1a[3]=0.f;
#pragma unroll
      for (int ks = 0; ks < 8; ks++){
        bf16x8 av = *(const bf16x8*)&lds[O_GZ2 + lm * 264 + ks * 32 + qd * 8];
        bf16x8 bv = *(const bf16x8*)&lds[O_W2K + (w * 16 + lm) * 264 + ks * 32 + qd * 8];
        g1a = __builtin_amdgcn_mfma_f32_16x16x32_bf16(av, bv, g1a, 0, 0, 0);
      }
#pragma unroll
      for (int rr = 0; rr < 4; rr++){
        int mr = qd * 4 + rr;
        if (mr < 10){
          float gz1 = g1a[rr] * gelu_bwd_f(z1v[rr]);
          lds[O_GZ1 + (w * 16 + lm) * 32 + mr] = f2bf(gz1);
        }
      }
    }
    __syncthreads();

    // 11a. b1 -= eta * colsum(gZ1)
    if (tid < 64){
      float sum = 0.f;
#pragma unroll
      for (int kx = 0; kx < 10; kx++) sum += bf2f(lds[O_GZ1 + tid * 32 + kx]);
      ldsf[tid] -= ETA * sum;
    }
    // 11b. W1 update: dW1 = xk^T @ gZ1
#pragma unroll
    for (int a = 0; a < 4; a++){
      int mt = 4 * w + a;
      bf16x8 av = *(const bf16x8*)&lds[O_XKT + (mt * 16 + lm) * 24 + (qd & 1) * 8];
#pragma unroll
      for (int nt = 0; nt < 4; nt++){
        bf16x8 bv = *(const bf16x8*)&lds[O_GZ1 + (nt * 16 + lm) * 32 + qd * 8];
        f32x4 d; d[0]=0.f; d[1]=0.f; d[2]=0.f; d[3]=0.f;
        d = __builtin_amdgcn_mfma_f32_16x16x32_bf16(av, bv, d, 0, 0, 0);
#pragma unroll
        for (int rr = 0; rr < 4; rr++) w1r[a][nt][rr] -= ETA * d[rr];
      }
    }
    // 11c. W2 update: dW2 = A1^T @ gZ2
    {
      bf16x8 av2 = *(const bf16x8*)&lds[O_A1T + (w * 16 + lm) * 32 + qd * 8];
#pragma unroll
      for (int nt = 0; nt < 16; nt++){
        bf16x8 bv = *(const bf16x8*)&lds[O_GZ2T + (nt * 16 + lm) * 24 + (qd & 1) * 8];
        f32x4 d; d[0]=0.f; d[1]=0.f; d[2]=0.f; d[3]=0.f;
        d = __builtin_amdgcn_mfma_f32_16x16x32_bf16(av2, bv, d, 0, 0, 0);
#pragma unroll
        for (int rr = 0; rr < 4; rr++) w2r[nt][rr] -= ETA * d[rr];
      }
    }
    WRITE_W1BF();
    WRITE_W2BF();
    __syncthreads();

    // prefetch next chunk's xk/tgt (XKQ/XKT/TGT consumed above)
    if (nch + 1 < 40){
      LOAD_XK_TGT(nch + 1);
    }
    __syncthreads();
  }

  // epilogue: query outputs for chunk 39 (W1BT/W2N = W_39, XQ2 = xq_39)
  {
    f32x4 zq; zq[0]=0.f; zq[1]=0.f; zq[2]=0.f; zq[3]=0.f;
#pragma unroll
    for (int ks = 0; ks < 8; ks++){
      bf16x8 av = *(const bf16x8*)&lds[O_XQ2 + lm * 264 + ks * 32 + qd * 8];
      bf16x8 bv = *(const bf16x8*)&lds[O_W1BT + (w * 16 + lm) * 264 + ks * 32 + qd * 8];
      zq = __builtin_amdgcn_mfma_f32_16x16x32_bf16(av, bv, zq, 0, 0, 0);
    }
    float b1n = ldsf[w * 16 + lm];
#pragma unroll
    for (int rr = 0; rr < 4; rr++){
      int mr = qd * 4 + rr;
      if (mr < 10)
        lds[O_A1Q + mr * 72 + w * 16 + lm] = f2bf(gelu_f(zq[rr] + b1n));
    }
  }
  __syncthreads();
  {
    unsigned short* zq_out = zqp + ((size_t)(h * 16 + sl) * 40 + 39) * 2560;
#pragma unroll
    for (int nt4 = 0; nt4 < 4; nt4++){
      int nt = 4 * w + nt4;
      f32x4 p; p[0]=0.f; p[1]=0.f; p[2]=0.f; p[3]=0.f;
#pragma unroll
      for (int ks = 0; ks < 2; ks++){
        bf16x8 av = *(const bf16x8*)&lds[O_A1Q + lm * 72 + ks * 32 + qd * 8];
        bf16x8 bv = *(const bf16x8*)&lds[O_W2N + (nt * 16 + lm) * 72 + ks * 32 + qd * 8];
        p = __builtin_amdgcn_mfma_f32_16x16x32_bf16(av, bv, p, 0, 0, 0);
      }
      float bb = (sl == 0) ? ldsf[64 + nt * 16 + lm] : 0.f;
#pragma unroll
      for (int rr = 0; rr < 4; rr++){
        int mr = qd * 4 + rr;
        if (mr < 10)
          zq_out[mr * 256 + nt * 16 + lm] = f2bf(p[rr] + bb);
      }
    }
  }
}

// ---------------------------------------------------------------------------
// LN forward + residual; sums 16 bf16 slice partials of Z2q in fp32.
// ---------------------------------------------------------------------------
__global__ __launch_bounds__(256) void k_lnout(
    const unsigned short* __restrict__ zqp, const unsigned short* __restrict__ qg,
    const float* __restrict__ gwg, const float* __restrict__ gbg,
    unsigned short* __restrict__ obf)
{
  int w = threadIdx.x >> 6, l = threadIdx.x & 63;
  int gr = blockIdx.x * 4 + w;
  int h = gr / 400, t = gr % 400, hh = h & 7, b = h >> 3;
  int nch = t / 10, mr = t % 10;
  int c0 = l * 4;
  float z[4] = {0.f, 0.f, 0.f, 0.f};
#pragma unroll
  for (int sl = 0; sl < 16; sl++){
    const unsigned short* zp = zqp + (((size_t)(h * 16 + sl) * 40 + nch) * 10 + mr) * 256 + c0;
    ushort4 u = *(const ushort4*)zp;
    z[0] += bf2f(u.x); z[1] += bf2f(u.y); z[2] += bf2f(u.z); z[3] += bf2f(u.w);
  }
  float s1 = 0.f, s2 = 0.f;
#pragma unroll
  for (int i = 0; i < 4; i++){ s1 += z[i]; s2 += z[i] * z[i]; }
#pragma unroll
  for (int off = 32; off >= 1; off >>= 1){ s1 += __shfl_xor(s1, off, 64); s2 += __shfl_xor(s2, off, 64); }
  float mu = s1 * (1.f / 256.f);
  float var = s2 * (1.f / 256.f) - mu * mu;
  float rstd = rsqrtf(var + 1e-6f);
  const unsigned short* qp = &qg[((size_t)h * 400 + t) * 256];
  ushort4 qu = *(const ushort4*)&qp[c0];
  float qv[4] = {bf2f(qu.x), bf2f(qu.y), bf2f(qu.z), bf2f(qu.w)};
  unsigned short* op = &obf[((size_t)(b * 400 + t)) * 2048 + hh * 256];
#pragma unroll
  for (int i = 0; i < 4; i++){
    float xh = (z[i] - mu) * rstd;
    float o = qv[i] + gwg[hh * 256 + c0 + i] * xh + gbg[hh * 256 + c0 + i];
    op[c0 + i] = f2bf(o);
  }
}

// ---------------------------------------------------------------------------
// launch — workspace map (bytes)
// ---------------------------------------------------------------------------
#define WS_WEFF   0u          // weff (dead after gemm0) | zqp 52.4MB | g2part 26.2MB (post-lnout)
#define WS_P      31719424u
#define WS_WQKV   44109824u
#define WS_WOB    52428800u
#define WS_Z2ACC  62722048u
#define WS_XB     69275648u
#define WS_Q      72552448u   // | g0part 13.1MB (pre-gemm1)
#define WS_K      75829248u
#define WS_V      79106048u
#define WS_OBF    82382848u
#define WS_BSUM   85659648u
#define WS_BAR    85667840u

extern "C" void kernel_launch(void* const* d_in, const int* in_sizes, int n_in,
                              void* d_out, int out_size, void* d_ws, size_t ws_size,
                              hipStream_t stream)
{
  (void)in_sizes; (void)n_in; (void)out_size; (void)ws_size;
  const float* x  = (const float*)d_in[0];
  const float* cw[6]; const float* cb[6];
  for (int i = 0; i < 6; i++){ cw[i] = (const float*)d_in[2 + 2 * i]; cb[i] = (const float*)d_in[3 + 2 * i]; }
  const float* wq  = (const float*)d_in[14];
  const float* wk  = (const float*)d_in[15];
  const float* wv  = (const float*)d_in[16];
  const float* wo  = (const float*)d_in[17];
  const float* W1  = (const float*)d_in[18];
  const float* b1  = (const float*)d_in[19];
  const float* W2  = (const float*)d_in[20];
  const float* b2  = (const float*)d_in[21];
  const float* lnw = (const float*)d_in[22];
  const float* lnb = (const float*)d_in[23];
  float* outf = (float*)d_out;

  char* wsb = (char*)d_ws;
  unsigned short* weff = (unsigned short*)(wsb + WS_WEFF);
  unsigned short* P    = (unsigned short*)(wsb + WS_P);
  unsigned short* wqkv = (unsigned short*)(wsb + WS_WQKV);
  unsigned short* wob  = (unsigned short*)(wsb + WS_WOB);
  unsigned short* xb   = (unsigned short*)(wsb + WS_XB);
  unsigned short* qb   = (unsigned short*)(wsb + WS_Q);
  unsigned short* kb   = (unsigned short*)(wsb + WS_K);
  unsigned short* vb   = (unsigned short*)(wsb + WS_V);
  float* z2acc = (float*)(wsb + WS_Z2ACC);
  unsigned short* zqp = (unsigned short*)(wsb + WS_WEFF);
  unsigned short* obf = (unsigned short*)(wsb + WS_OBF);
  float* bsum = (float*)(wsb + WS_BSUM);
  unsigned int* bar = (unsigned int*)(wsb + WS_BAR);
  float* g0part = (float*)(wsb + WS_Q);      // pre-gemm1
  float* g2part = (float*)(wsb + WS_WEFF);   // post-lnout (zqp dead), 26.2MB

  hipMemsetAsync(bar, 0, 16 * BAR_STRIDE * 4, stream);
  hipFuncSetAttribute(reinterpret_cast<const void*>(k_ttt),
                      hipFuncAttributeMaxDynamicSharedMemorySize, TTT_LDS_BYTES);
  hipFuncSetAttribute(reinterpret_cast<const void*>(k_weff),
                      hipFuncAttributeMaxDynamicSharedMemorySize, 18304 * 4);

  k_weff<<<2048, 256, 18304 * 4, stream>>>(cw[0], cw[1], cw[2], cw[3], cw[4], cw[5], weff);
  k_im2col<<<(800 * 7744 + 255) / 256, 256, 0, stream>>>(x, P);
  k_wqkv<<<(6144 * 2048 + 255) / 256, 256, 0, stream>>>(wq, wk, wv, wqkv);
  k_bsum<<<8, 256, 0, stream>>>(cb[0], cb[1], cb[2], cb[3], cb[4], cb[5], bsum);

  k_gemm<2><<<dim3(16, 7, 2), 256, 0, stream>>>(weff, P, 2048, 800, 7744, 7744, 3872,
                                                nullptr, nullptr, nullptr, g0part);
  k_comb_silu<<<1600, 256, 0, stream>>>(g0part, g0part + 1638400, bsum, xb);

  k_gemm<1><<<dim3(48, 7, 1), 256, 0, stream>>>(wqkv, xb, 6144, 800, 2048, 2048, 2048,
                                                qb, kb, vb, nullptr);

  k_f2bf_copy<<<(2048 * 2048 + 255) / 256, 256, 0, stream>>>(wo, wob, 2048 * 2048);
  hipMemsetAsync(z2acc, 0, 16 * 40 * 10 * 256 * 4, stream);

  k_ttt<<<256, 256, TTT_LDS_BYTES, stream>>>(qb, kb, vb, W1, b1, W2, b2, lnw, lnb,
                                             z2acc, zqp, bar);
  k_lnout<<<1600, 256, 0, stream>>>(zqp, qb, lnw, lnb, obf);

  k_gemm<2><<<dim3(16, 7, 4), 256, 0, stream>>>(wob, obf, 2048, 800, 2048, 2048, 512,
                                                nullptr, nullptr, nullptr, g2part);
  k_comb_add4<<<1600, 256, 0, stream>>>(g2part, outf);
}